// Round 6
// baseline (633.422 us; speedup 1.0000x reference)
//
#include <hip/hip_runtime.h>
#include <math.h>

// Fixed problem dims
constexpr int kB  = 4;
constexpr int kD  = 256;
constexpr int kNQ = 4096;
constexpr int kNK = 4096;
constexpr int kHW = 4096;   // 64*64

typedef __bf16 bf16x8 __attribute__((ext_vector_type(8)));
typedef float  f32x16 __attribute__((ext_vector_type(16)));

__device__ __forceinline__ unsigned short f2bf(float x) {
    unsigned int u = __builtin_bit_cast(unsigned int, x);
    u = (u + 0x7fffu + ((u >> 16) & 1u)) >> 16;
    return (unsigned short)u;
}

// ------------------------------------------------------------- f32 -> bf16
__global__ __launch_bounds__(256) void k_cvt_bf16(const float* __restrict__ in,
                                                  ushort* __restrict__ out) {
    const int i = blockIdx.x * 256 + threadIdx.x;   // one float4 each
    float4 v = ((const float4*)in)[i];
    ushort4 o;
    o.x = f2bf(v.x); o.y = f2bf(v.y); o.z = f2bf(v.z); o.w = f2bf(v.w);
    ((ushort4*)out)[i] = o;
}

// ---------------------------------------------------------------- fold w1 -> bf16
__global__ void k_fold_w1(const float* __restrict__ w1, ushort* __restrict__ w1e) {
    int h = blockIdx.x, d = threadIdx.x;
    w1e[h * 256 + d] = f2bf(w1[h * 512 + d] + w1[h * 512 + 256 + d]);
}

// ------------------------------------------- conv1 weights -> bf16 [9][co][ci]
__global__ void k_repack_w9(const float* __restrict__ cw, ushort* __restrict__ w9) {
    const int ci = threadIdx.x;
    const int co = blockIdx.x & 255;
    const int s  = blockIdx.x >> 8;     // grid 9*256
    w9[((size_t)s * 256 + co) * 256 + ci] = f2bf(cw[((size_t)co * 256 + ci) * 9 + s]);
}

// ----------------------------------------------- generic MFMA GEMM  C = A @ W^T
// A [M,256] bf16, W [256,256] bf16 ([n][k]). Block: 128m x 64n, 4 waves (2x2).
// EPI: 0 = f32 [m][256]; 1 = bf16 [m][256]; 2 = bf16 transposed per-batch [b][n][4096]
template<int EPI, int RELU>
__global__ __launch_bounds__(256, 2) void k_gemm_mfma(
    const ushort* __restrict__ A, const ushort* __restrict__ W,
    const float* __restrict__ bias, void* __restrict__ outp)
{
    const int t = threadIdx.x, w = t >> 6, l = t & 63, lr = l & 31, lh = l >> 5;
    const int m0 = (blockIdx.x >> 2) * 128;
    const int n0 = (blockIdx.x & 3) * 64;
    const int wm = w >> 1, wn = w & 1;
    const ushort* Ar0 = A + (size_t)(m0 + wm * 64 + lr) * 256 + lh * 8;
    const ushort* Ar1 = Ar0 + 32 * 256;
    const ushort* Wr  = W + (size_t)(n0 + wn * 32 + lr) * 256 + lh * 8;
    f32x16 c0{}, c1{};
    #pragma unroll
    for (int ks = 0; ks < 16; ++ks) {
        bf16x8 a0 = *(const bf16x8*)(Ar0 + ks * 16);
        bf16x8 a1 = *(const bf16x8*)(Ar1 + ks * 16);
        bf16x8 wf = *(const bf16x8*)(Wr + ks * 16);
        c0 = __builtin_amdgcn_mfma_f32_32x32x16_bf16(a0, wf, c0, 0, 0, 0);
        c1 = __builtin_amdgcn_mfma_f32_32x32x16_bf16(a1, wf, c1, 0, 0, 0);
    }
    const int n = n0 + wn * 32 + lr;            // C col for both accs
    float bb = bias ? bias[n] : 0.f;
    if constexpr (EPI == 2) {
        __shared__ ushort tr[64][136];          // [n_local][m_local], 16B-aligned rows
        #pragma unroll
        for (int r = 0; r < 16; ++r) {
            const int ml = wm * 64 + (r & 3) + 8 * (r >> 2) + 4 * lh;
            float v0 = c0[r], v1 = c1[r];
            if (RELU) { v0 = fmaxf(v0, 0.f); v1 = fmaxf(v1, 0.f); }
            tr[wn * 32 + lr][ml]      = f2bf(v0);
            tr[wn * 32 + lr][ml + 32] = f2bf(v1);
        }
        __syncthreads();
        ushort* out = (ushort*)outp;
        const int b = m0 >> 12, mm = m0 & 4095;
        const int row = t >> 2, seg = t & 3;    // 64 rows x 4 segs of 32 cols
        uint4 u0 = *(uint4*)&tr[row][seg * 32];
        uint4 u1 = *(uint4*)&tr[row][seg * 32 + 8];
        uint4 u2 = *(uint4*)&tr[row][seg * 32 + 16];
        uint4 u3 = *(uint4*)&tr[row][seg * 32 + 24];
        ushort* ob = out + ((size_t)b * 256 + n0 + row) * 4096 + mm + seg * 32;
        *(uint4*)ob        = u0; *(uint4*)(ob + 8)  = u1;
        *(uint4*)(ob + 16) = u2; *(uint4*)(ob + 24) = u3;
    } else {
        #pragma unroll
        for (int r = 0; r < 16; ++r) {
            const int m = m0 + wm * 64 + (r & 3) + 8 * (r >> 2) + 4 * lh;
            float v0 = c0[r] + bb, v1 = c1[r] + bb;
            if (RELU) { v0 = fmaxf(v0, 0.f); v1 = fmaxf(v1, 0.f); }
            if constexpr (EPI == 0) {
                float* out = (float*)outp;
                out[(size_t)m * 256 + n]      = v0;
                out[(size_t)(m + 32) * 256 + n] = v1;
            } else {
                ushort* out = (ushort*)outp;
                out[(size_t)m * 256 + n]      = f2bf(v0);
                out[(size_t)(m + 32) * 256 + n] = f2bf(v1);
            }
        }
    }
}

// ---------------------------------------------------------------- L2 norm -> bf16
__global__ __launch_bounds__(256) void k_l2norm_bf16(const float* __restrict__ in,
                                                     ushort* __restrict__ out) {
    const int row  = blockIdx.x * 4 + (threadIdx.x >> 6);
    const int lane = threadIdx.x & 63;
    float4 v = ((const float4*)(in + (size_t)row * 256))[lane];
    float ss = v.x * v.x + v.y * v.y + v.z * v.z + v.w * v.w;
    #pragma unroll
    for (int off = 32; off; off >>= 1) ss += __shfl_xor(ss, off, 64);
    const float rn = 1.0f / sqrtf(ss);
    ushort4 o;
    o.x = f2bf(v.x * rn); o.y = f2bf(v.y * rn);
    o.z = f2bf(v.z * rn); o.w = f2bf(v.w * rn);
    ((ushort4*)(out + (size_t)row * 256))[lane] = o;
}

// ---------------------------------------------------------------- MFMA attention
// X[b][q][d] (bf16) = sum_k relu(qn[b,q,:].kn[b,k,:]) * ow[b,k] * vT[b,d,k]
// grid 1024 = b(4) x dhalf(2) x qtile(128, 32 rows each); block 256 (4 waves).
// Per 128-k chunk: wave kg computes S[32q][32k] slice kg -> P[32q][128k] in LDS;
// then each wave does PV for its own 32-d block over all 128 k.
__global__ __launch_bounds__(256, 3) void k_attn_mfma(
    const ushort* __restrict__ qn, const ushort* __restrict__ kn,
    const ushort* __restrict__ vpT, const float* __restrict__ ow,
    ushort* __restrict__ X)
{
    __shared__ __align__(16) char smem[8192];    // P [32q][128k] bf16, XOR-swizzled
    const int t  = threadIdx.x;
    const int kg = t >> 6, l = t & 63;
    const int lr = l & 31, lh = l >> 5;
    const int bid = blockIdx.x;
    const int b = bid >> 8, dh = (bid >> 7) & 1, qt = bid & 127;
    const int q0 = qt << 5;
    const int d0 = dh * 128 + kg * 32;           // wave's PV d-block

    // Q fragments (32 q rows, shared by all waves; L1-cached)
    const ushort* qrow = qn + ((size_t)b * kNQ + q0 + lr) * kD + lh * 8;
    bf16x8 qf[16];
    #pragma unroll
    for (int ks = 0; ks < 16; ++ks) qf[ks] = *(const bf16x8*)(qrow + ks * 16);

    f32x16 oacc{};
    const float* owb = ow + b * kNK;
    for (int kt = 0; kt < 32; ++kt) {
        const int k0 = kt << 7;
        const int kw = k0 + 32 * kg;             // this wave's QK k-slice
        const float wsc = owb[kw + lr];
        const ushort* krow = kn + ((size_t)b * kNK + kw + lr) * kD + lh * 8;
        // ---- QK^T: S[32q][32k], two 8-deep chains
        f32x16 sa{}, sb{};
        #pragma unroll
        for (int ks = 0; ks < 16; ks += 2) {
            bf16x8 ka = *(const bf16x8*)(krow + ks * 16);
            bf16x8 kb = *(const bf16x8*)(krow + ks * 16 + 16);
            sa = __builtin_amdgcn_mfma_f32_32x32x16_bf16(qf[ks],     ka, sa, 0, 0, 0);
            sb = __builtin_amdgcn_mfma_f32_32x32x16_bf16(qf[ks + 1], kb, sb, 0, 0, 0);
        }
        __syncthreads();   // prev PV done reading P
        // ---- P = relu(sa+sb)*w -> bf16 LDS, byte ^= (q&15)<<4
        {
            const int colb = (32 * kg + lr) << 1;
            #pragma unroll
            for (int r = 0; r < 16; ++r) {
                const int q = (r & 3) + 8 * (r >> 2) + 4 * lh;
                const float v = fmaxf(sa[r] + sb[r], 0.f) * wsc;
                int off = (q << 8) + colb;
                off ^= (q & 15) << 4;
                *(ushort*)(smem + off) = f2bf(v);
            }
        }
        __syncthreads();
        // ---- PV: O[32q][32d] += P[32q][128k] * V[128k][32d]
        {
            const ushort* vbase = vpT + ((size_t)b * kD + d0 + lr) * (size_t)kNK
                                + k0 + lh * 8;
            const int rbase = (lr << 8) + (lh << 4);
            const int rswz  = (lr & 15) << 4;
            #pragma unroll
            for (int s8 = 0; s8 < 8; ++s8) {
                const int poff = (rbase + (s8 << 5)) ^ rswz;
                bf16x8 pf = *(const bf16x8*)(smem + poff);
                bf16x8 vf = *(const bf16x8*)(vbase + s8 * 16);
                oacc = __builtin_amdgcn_mfma_f32_32x32x16_bf16(pf, vf, oacc, 0, 0, 0);
            }
        }
    }
    // ---- epilogue: bf16 X[b][q][d] (channel-last for the convs)
    ushort* Xo = X + ((size_t)b * kNQ + q0) * 256 + d0 + lr;
    #pragma unroll
    for (int r = 0; r < 16; ++r) {
        const int q = (r & 3) + 8 * (r >> 2) + 4 * lh;
        Xo[(size_t)q * 256] = f2bf(oacc[r]);
    }
}

// ------------------------------- conv3x3 + BN + SiLU as 9 shifted MFMA GEMMs
// X [b][p][ci] bf16 -> Y [b][p][co] bf16. Block: 64co x 128p, 4 waves (2x2).
__global__ __launch_bounds__(256, 2) void k_conv3_mfma(
    const ushort* __restrict__ X, const ushort* __restrict__ W9,
    const float* __restrict__ bn_g, const float* __restrict__ bn_b,
    const float* __restrict__ bn_m, const float* __restrict__ bn_v,
    ushort* __restrict__ Y)
{
    __shared__ float binv[256], badd[256];
    __shared__ ushort tr[128][72];               // [p_local][co_local], 144B rows
    const int t = threadIdx.x, w = t >> 6, l = t & 63, lr = l & 31, lh = l >> 5;
    {
        float inv = bn_g[t] * rsqrtf(bn_v[t] + 1e-3f);
        binv[t] = inv;
        badd[t] = bn_b[t] - bn_m[t] * inv;
    }
    __syncthreads();
    const int bid = blockIdx.x;                  // 4b x 4co x 32p
    const int b = bid >> 7, ct = (bid >> 5) & 3, pt = bid & 31;
    const int co0 = ct * 64, p0 = pt * 128;
    const int wc = w >> 1, wp = w & 1;
    const int h0 = (p0 >> 6) + wp;               // uniform h for this wave
    const int pA = p0 + wp * 64 + lr;            // w_ = lr (sub A), +32 (sub B)
    const ushort* Xb = X + (size_t)b * 4096 * 256;
    const ushort* Wbase = W9 + (size_t)(co0 + wc * 32 + lr) * 256 + lh * 8;
    const bf16x8 bz = {};
    f32x16 o0{}, o1{};
    for (int dy = -1; dy <= 1; ++dy) {
        const int hh = h0 + dy;
        if (hh < 0 || hh > 63) continue;
        for (int dx = -1; dx <= 1; ++dx) {
            const int s = (dy + 1) * 3 + (dx + 1);
            const bool invA = (dx == -1) && (lr == 0);
            const bool invB = (dx == 1) && (lr == 31);
            const ushort* pAp = Xb + (size_t)(pA + dy * 64 + dx) * 256 + lh * 8;
            const ushort* pBp = pAp + 32 * 256;
            const ushort* wr  = Wbase + (size_t)s * 65536;
            #pragma unroll
            for (int ks = 0; ks < 16; ++ks) {
                bf16x8 af = *(const bf16x8*)(wr + ks * 16);
                bf16x8 b0 = *(const bf16x8*)(pAp + ks * 16);
                bf16x8 b1 = *(const bf16x8*)(pBp + ks * 16);
                if (invA) b0 = bz;
                if (invB) b1 = bz;
                o0 = __builtin_amdgcn_mfma_f32_32x32x16_bf16(af, b0, o0, 0, 0, 0);
                o1 = __builtin_amdgcn_mfma_f32_32x32x16_bf16(af, b1, o1, 0, 0, 0);
            }
        }
    }
    // BN + SiLU -> bf16, transpose to [p][co] through LDS
    #pragma unroll
    for (int r = 0; r < 16; ++r) {
        const int co_l = wc * 32 + (r & 3) + 8 * (r >> 2) + 4 * lh;
        const int co = co0 + co_l;
        const float inv = binv[co], add = badd[co];
        float x0 = o0[r] * inv + add;
        float x1 = o1[r] * inv + add;
        x0 = x0 / (1.f + expf(-x0));
        x1 = x1 / (1.f + expf(-x1));
        tr[wp * 64 + lr][co_l]      = f2bf(x0);
        tr[wp * 64 + 32 + lr][co_l] = f2bf(x1);
    }
    __syncthreads();
    // write-out: 128 rows x 64 cols; 256 threads x 32 ushorts = full tile
    const int pp = t >> 1, half = t & 1;
    uint4 u0 = *(uint4*)&tr[pp][half * 32];
    uint4 u1 = *(uint4*)&tr[pp][half * 32 + 8];
    uint4 u2 = *(uint4*)&tr[pp][half * 32 + 16];
    uint4 u3 = *(uint4*)&tr[pp][half * 32 + 24];
    ushort* yb = Y + ((size_t)b * 4096 + p0 + pp) * 256 + co0 + half * 32;
    *(uint4*)yb        = u0; *(uint4*)(yb + 8)  = u1;
    *(uint4*)(yb + 16) = u2; *(uint4*)(yb + 24) = u3;
}

// ------------------------- conv1x1 + bias + residual: out = q + Y @ W2^T + b2
// Y [b][p][ci] bf16, W2 [co][ci] bf16 -> out [b][co][p] f32 (coalesced stores)
__global__ __launch_bounds__(256, 2) void k_conv1x1_mfma(
    const ushort* __restrict__ Y, const ushort* __restrict__ W2,
    const float* __restrict__ bias2, const float* __restrict__ query,
    float* __restrict__ out)
{
    const int t = threadIdx.x, w = t >> 6, l = t & 63, lr = l & 31, lh = l >> 5;
    const int bid = blockIdx.x;                  // 4b x 4co x 32p
    const int b = bid >> 7, ct = (bid >> 5) & 3, pt = bid & 31;
    const int co0 = ct * 64, p0 = pt * 128;
    const int wc = w >> 1, wp = w & 1;
    const ushort* Wr = W2 + (size_t)(co0 + wc * 32 + lr) * 256 + lh * 8;
    const ushort* Yp = Y + ((size_t)b * 4096 + p0 + wp * 64 + lr) * 256 + lh * 8;
    f32x16 o0{}, o1{};
    #pragma unroll
    for (int ks = 0; ks < 16; ++ks) {
        bf16x8 wf = *(const bf16x8*)(Wr + ks * 16);
        bf16x8 y0 = *(const bf16x8*)(Yp + ks * 16);
        bf16x8 y1 = *(const bf16x8*)(Yp + 32 * 256 + ks * 16);
        o0 = __builtin_amdgcn_mfma_f32_32x32x16_bf16(wf, y0, o0, 0, 0, 0);
        o1 = __builtin_amdgcn_mfma_f32_32x32x16_bf16(wf, y1, o1, 0, 0, 0);
    }
    #pragma unroll
    for (int r = 0; r < 16; ++r) {
        const int co = co0 + wc * 32 + (r & 3) + 8 * (r >> 2) + 4 * lh;
        const float bb = bias2[co];
        const size_t base = ((size_t)b * 256 + co) * 4096 + p0 + wp * 64 + lr;
        out[base]      = o0[r] + bb + query[base];
        out[base + 32] = o1[r] + bb + query[base + 32];
    }
}

// ---------------------------------------------------------------- launch
extern "C" void kernel_launch(void* const* d_in, const int* in_sizes, int n_in,
                              void* d_out, int out_size, void* d_ws, size_t ws_size,
                              hipStream_t stream) {
    const float* query   = (const float*)d_in[0];
    const float* v_in    = (const float*)d_in[1];
    const float* qpos    = (const float*)d_in[2];
    const float* kpos    = (const float*)d_in[3];
    const float* otherW  = (const float*)d_in[4];
    const float* w_vs    = (const float*)d_in[5];
    const float* mlp_w1  = (const float*)d_in[6];
    const float* mlp_b1  = (const float*)d_in[7];
    const float* mlp_w2  = (const float*)d_in[8];
    const float* mlp_b2  = (const float*)d_in[9];
    const float* conv1_w = (const float*)d_in[10];
    const float* bn_g    = (const float*)d_in[11];
    const float* bn_b    = (const float*)d_in[12];
    const float* bn_m    = (const float*)d_in[13];
    const float* bn_v    = (const float*)d_in[14];
    const float* conv2_w = (const float*)d_in[15];
    const float* conv2_b = (const float*)d_in[16];
    float* out = (float*)d_out;
    char* base = (char*)d_ws;

    constexpr size_t MB = 1u << 20;
    ushort* v_bf    = (ushort*)(base);             // 8MB   (dead after vproj)
    ushort* qpos_bf = (ushort*)(base + 8 * MB);    // 8MB   (dead after mlp1)
    float*  qp_f32  = (float*) (base);             // 16MB  (aliases v_bf+qpos_bf)
    ushort* qhid_bf = (ushort*)(base + 16 * MB);   // 8MB   (dead after mlp2)
    ushort* X_bf    = (ushort*)(base + 16 * MB);   // 8MB   (attn out, aliases qhid)
    ushort* qn_bf   = (ushort*)(base + 24 * MB);   // 8MB   (dead after attn)
    ushort* Y_bf    = (ushort*)(base + 24 * MB);   // 8MB   (conv3 out, aliases qn)
    ushort* kn_bf   = (ushort*)(base + 32 * MB);   // 8MB
    ushort* vT_bf   = (ushort*)(base + 40 * MB);   // 8MB
    ushort* wvs_bf  = (ushort*)(base + 48 * MB);
    ushort* w1e_bf  = (ushort*)(base + 48 * MB + 128 * 1024);
    ushort* w2_bf   = (ushort*)(base + 48 * MB + 256 * 1024);
    ushort* c2_bf   = (ushort*)(base + 48 * MB + 384 * 1024);
    ushort* w9_bf   = (ushort*)(base + 48 * MB + 512 * 1024);   // 1.125MB

    k_cvt_bf16<<<4096, 256, 0, stream>>>(v_in, v_bf);
    k_cvt_bf16<<<64, 256, 0, stream>>>(w_vs, wvs_bf);
    k_cvt_bf16<<<64, 256, 0, stream>>>(mlp_w2, w2_bf);
    k_cvt_bf16<<<64, 256, 0, stream>>>(conv2_w, c2_bf);
    k_fold_w1<<<256, 256, 0, stream>>>(mlp_w1, w1e_bf);
    k_repack_w9<<<2304, 256, 0, stream>>>(conv1_w, w9_bf);
    k_cvt_bf16<<<4096, 256, 0, stream>>>(qpos, qpos_bf);

    k_gemm_mfma<2, 0><<<512, 256, 0, stream>>>(v_bf, wvs_bf, nullptr, vT_bf);
    k_gemm_mfma<1, 1><<<512, 256, 0, stream>>>(qpos_bf, w1e_bf, mlp_b1, qhid_bf);
    k_gemm_mfma<0, 0><<<512, 256, 0, stream>>>(qhid_bf, w2_bf, mlp_b2, qp_f32);
    k_l2norm_bf16<<<4096, 256, 0, stream>>>(qp_f32, qn_bf);
    k_l2norm_bf16<<<4096, 256, 0, stream>>>(kpos, kn_bf);
    k_attn_mfma<<<1024, 256, 0, stream>>>(qn_bf, kn_bf, vT_bf, otherW, X_bf);
    k_conv3_mfma<<<512, 256, 0, stream>>>(X_bf, w9_bf, bn_g, bn_b, bn_m, bn_v, Y_bf);
    k_conv1x1_mfma<<<512, 256, 0, stream>>>(Y_bf, c2_bf, conv2_b, query, out);
}

// Round 7
// 543.288 us; speedup vs baseline: 1.1659x; 1.1659x over previous
//
#include <hip/hip_runtime.h>
#include <math.h>

// Fixed problem dims
constexpr int kB  = 4;
constexpr int kD  = 256;
constexpr int kNQ = 4096;
constexpr int kNK = 4096;
constexpr int kHW = 4096;   // 64*64

typedef __bf16 bf16x8 __attribute__((ext_vector_type(8)));
typedef float  f32x16 __attribute__((ext_vector_type(16)));

__device__ __forceinline__ unsigned short f2bf(float x) {
    unsigned int u = __builtin_bit_cast(unsigned int, x);
    u = (u + 0x7fffu + ((u >> 16) & 1u)) >> 16;
    return (unsigned short)u;
}

// ------------------------------------------------------------- f32 -> bf16
__global__ __launch_bounds__(256) void k_cvt_bf16(const float* __restrict__ in,
                                                  ushort* __restrict__ out) {
    const int i = blockIdx.x * 256 + threadIdx.x;   // one float4 each
    float4 v = ((const float4*)in)[i];
    ushort4 o;
    o.x = f2bf(v.x); o.y = f2bf(v.y); o.z = f2bf(v.z); o.w = f2bf(v.w);
    ((ushort4*)out)[i] = o;
}

// --------------------------------------- v * ow (row scale) -> bf16 (w-fold)
__global__ __launch_bounds__(256) void k_cvt_v_scaled(const float* __restrict__ in,
                                                      const float* __restrict__ ow,
                                                      ushort* __restrict__ out) {
    const int i = blockIdx.x * 256 + threadIdx.x;   // float4 id
    float4 v = ((const float4*)in)[i];
    const float wsc = ow[i >> 6];                   // (i*4)/256
    ushort4 o;
    o.x = f2bf(v.x * wsc); o.y = f2bf(v.y * wsc);
    o.z = f2bf(v.z * wsc); o.w = f2bf(v.w * wsc);
    ((ushort4*)out)[i] = o;
}

// ---------------------------------------------------------------- fold w1 -> bf16
__global__ void k_fold_w1(const float* __restrict__ w1, ushort* __restrict__ w1e) {
    int h = blockIdx.x, d = threadIdx.x;
    w1e[h * 256 + d] = f2bf(w1[h * 512 + d] + w1[h * 512 + 256 + d]);
}

// ------------------------------------------- conv1 weights -> bf16 [9][co][ci]
__global__ void k_repack_w9(const float* __restrict__ cw, ushort* __restrict__ w9) {
    const int ci = threadIdx.x;
    const int co = blockIdx.x & 255;
    const int s  = blockIdx.x >> 8;     // grid 9*256
    w9[((size_t)s * 256 + co) * 256 + ci] = f2bf(cw[((size_t)co * 256 + ci) * 9 + s]);
}

// ----------------------------------------------- generic MFMA GEMM  C = A @ W^T
// A [M,256] bf16, W [256,256] bf16 ([n][k]). Block: 128m x 64n, 4 waves (2x2).
// EPI: 0 = f32 [m][256]; 1 = bf16 [m][256]; 2 = bf16 transposed per-batch [b][n][4096]
template<int EPI, int RELU>
__global__ __launch_bounds__(256, 2) void k_gemm_mfma(
    const ushort* __restrict__ A, const ushort* __restrict__ W,
    const float* __restrict__ bias, void* __restrict__ outp)
{
    const int t = threadIdx.x, w = t >> 6, l = t & 63, lr = l & 31, lh = l >> 5;
    const int m0 = (blockIdx.x >> 2) * 128;
    const int n0 = (blockIdx.x & 3) * 64;
    const int wm = w >> 1, wn = w & 1;
    const ushort* Ar0 = A + (size_t)(m0 + wm * 64 + lr) * 256 + lh * 8;
    const ushort* Ar1 = Ar0 + 32 * 256;
    const ushort* Wr  = W + (size_t)(n0 + wn * 32 + lr) * 256 + lh * 8;
    f32x16 c0{}, c1{};
    #pragma unroll
    for (int ks = 0; ks < 16; ++ks) {
        bf16x8 a0 = *(const bf16x8*)(Ar0 + ks * 16);
        bf16x8 a1 = *(const bf16x8*)(Ar1 + ks * 16);
        bf16x8 wf = *(const bf16x8*)(Wr + ks * 16);
        c0 = __builtin_amdgcn_mfma_f32_32x32x16_bf16(a0, wf, c0, 0, 0, 0);
        c1 = __builtin_amdgcn_mfma_f32_32x32x16_bf16(a1, wf, c1, 0, 0, 0);
    }
    const int n = n0 + wn * 32 + lr;            // C col for both accs
    float bb = bias ? bias[n] : 0.f;
    if constexpr (EPI == 2) {
        __shared__ ushort tr[64][136];          // [n_local][m_local], 16B-aligned rows
        #pragma unroll
        for (int r = 0; r < 16; ++r) {
            const int ml = wm * 64 + (r & 3) + 8 * (r >> 2) + 4 * lh;
            float v0 = c0[r], v1 = c1[r];
            if (RELU) { v0 = fmaxf(v0, 0.f); v1 = fmaxf(v1, 0.f); }
            tr[wn * 32 + lr][ml]      = f2bf(v0);
            tr[wn * 32 + lr][ml + 32] = f2bf(v1);
        }
        __syncthreads();
        ushort* out = (ushort*)outp;
        const int b = m0 >> 12, mm = m0 & 4095;
        const int row = t >> 2, seg = t & 3;    // 64 rows x 4 segs of 32 cols
        uint4 u0 = *(uint4*)&tr[row][seg * 32];
        uint4 u1 = *(uint4*)&tr[row][seg * 32 + 8];
        uint4 u2 = *(uint4*)&tr[row][seg * 32 + 16];
        uint4 u3 = *(uint4*)&tr[row][seg * 32 + 24];
        ushort* ob = out + ((size_t)b * 256 + n0 + row) * 4096 + mm + seg * 32;
        *(uint4*)ob        = u0; *(uint4*)(ob + 8)  = u1;
        *(uint4*)(ob + 16) = u2; *(uint4*)(ob + 24) = u3;
    } else {
        #pragma unroll
        for (int r = 0; r < 16; ++r) {
            const int m = m0 + wm * 64 + (r & 3) + 8 * (r >> 2) + 4 * lh;
            float v0 = c0[r] + bb, v1 = c1[r] + bb;
            if (RELU) { v0 = fmaxf(v0, 0.f); v1 = fmaxf(v1, 0.f); }
            if constexpr (EPI == 0) {
                float* out = (float*)outp;
                out[(size_t)m * 256 + n]      = v0;
                out[(size_t)(m + 32) * 256 + n] = v1;
            } else {
                ushort* out = (ushort*)outp;
                out[(size_t)m * 256 + n]      = f2bf(v0);
                out[(size_t)(m + 32) * 256 + n] = f2bf(v1);
            }
        }
    }
}

// ---------------------------------------------------------------- L2 norm -> bf16
__global__ __launch_bounds__(256) void k_l2norm_bf16(const float* __restrict__ in,
                                                     ushort* __restrict__ out) {
    const int row  = blockIdx.x * 4 + (threadIdx.x >> 6);
    const int lane = threadIdx.x & 63;
    float4 v = ((const float4*)(in + (size_t)row * 256))[lane];
    float ss = v.x * v.x + v.y * v.y + v.z * v.z + v.w * v.w;
    #pragma unroll
    for (int off = 32; off; off >>= 1) ss += __shfl_xor(ss, off, 64);
    const float rn = 1.0f / sqrtf(ss);
    ushort4 o;
    o.x = f2bf(v.x * rn); o.y = f2bf(v.y * rn);
    o.z = f2bf(v.z * rn); o.w = f2bf(v.w * rn);
    ((ushort4*)(out + (size_t)row * 256))[lane] = o;
}

// ---------------------------------------------------------------- MFMA attention
// X[b][q][d] (bf16) = sum_k relu(qn[b,q,:].kn[b,k,:]) * vT'[b,d,k]   (w folded in V')
// Swapped-operand, barrier-free k-loop. grid 512 = b(4) x qtile(128); 4 waves:
// wave (dh,kh): 32q x 128d (dh half) x 2048k (kh half). End: LDS k-reduce.
__global__ __launch_bounds__(256, 2) void k_attn_mfma(
    const ushort* __restrict__ qn, const ushort* __restrict__ kn,
    const ushort* __restrict__ vpT, ushort* __restrict__ X)
{
    __shared__ float  red[2][32][132];    // k-split partial sums (f32)
    __shared__ ushort etr[2][32][136];    // transpose-out staging
    const int t = threadIdx.x, w = t >> 6, l = t & 63, lr = l & 31, lh = l >> 5;
    const int dh = w >> 1, kh = w & 1;
    const int bid0 = blockIdx.x;
    const int bid  = (bid0 & 7) * 64 + (bid0 >> 3);   // XCD b-clustering (bijective, 512=8*64)
    const int b = bid >> 7, qt = bid & 127;
    const int q0 = qt << 5, d0 = dh << 7;
    const size_t kb4 = (size_t)b * 4096;

    // Q fragments: lane holds Q[q = q0+lr][d = ks*16 + lh*8 + e]  (B-operand layout)
    const ushort* qrow = qn + (kb4 + q0 + lr) * 256 + lh * 8;
    bf16x8 qf[16];
    #pragma unroll
    for (int ks = 0; ks < 16; ++ks) qf[ks] = *(const bf16x8*)(qrow + ks * 16);

    f32x16 oa0{}, oa1{}, oa2{}, oa3{};    // d-blocks d0 + 32*db
    const int kbase = kh * 2048;
    const ushort* kbp = kn + (kb4 + kbase + lr) * 256 + lh * 8;
    const ushort* vbp = vpT + ((size_t)b * 256 + d0 + lr) * (size_t)4096 + kbase + lh * 8;

    for (int kt = 0; kt < 64; ++kt) {
        const ushort* krow = kbp + (size_t)(kt << 5) * 256;
        // ---- S^T[32k][32q] = K . Q^T  (A = K rows, B = Q cols), 2 chains
        f32x16 s0{}, s1{};
        #pragma unroll
        for (int ks = 0; ks < 16; ks += 2) {
            bf16x8 ka = *(const bf16x8*)(krow + ks * 16);
            bf16x8 kb = *(const bf16x8*)(krow + ks * 16 + 16);
            s0 = __builtin_amdgcn_mfma_f32_32x32x16_bf16(ka, qf[ks],     s0, 0, 0, 0);
            s1 = __builtin_amdgcn_mfma_f32_32x32x16_bf16(kb, qf[ks + 1], s1, 0, 0, 0);
        }
        f32x16 s = s0 + s1;
        // ---- in-register P^T B-frags via bf16-pack + half-wave exchange
        // lane holds P[q=lr(+q0)][kk = (r&3)+8*(r>>2)+4*lh]; B-frag needs k=8*lh+e (+16*ks)
        #define PKR(A, B) ((unsigned)f2bf(fmaxf((A), 0.f)) | ((unsigned)f2bf(fmaxf((B), 0.f)) << 16))
        unsigned p01 = PKR(s[0],  s[1]),  p23 = PKR(s[2],  s[3]);
        unsigned p45 = PKR(s[4],  s[5]),  p67 = PKR(s[6],  s[7]);
        unsigned p89 = PKR(s[8],  s[9]),  pAB = PKR(s[10], s[11]);
        unsigned pCD = PKR(s[12], s[13]), pEF = PKR(s[14], s[15]);
        #undef PKR
        unsigned e1a = lh ? p01 : p45,  e2a = lh ? p23 : p67;
        unsigned e1b = lh ? p89 : pCD,  e2b = lh ? pAB : pEF;
        unsigned f1a = (unsigned)__shfl_xor((int)e1a, 32, 64);
        unsigned f2a = (unsigned)__shfl_xor((int)e2a, 32, 64);
        unsigned f1b = (unsigned)__shfl_xor((int)e1b, 32, 64);
        unsigned f2b = (unsigned)__shfl_xor((int)e2b, 32, 64);
        union U4 { unsigned u[4]; bf16x8 v; };
        U4 a0, a1;
        a0.u[0] = lh ? f1a : p01;  a0.u[1] = lh ? f2a : p23;
        a0.u[2] = lh ? p45 : f1a;  a0.u[3] = lh ? p67 : f2a;
        a1.u[0] = lh ? f1b : p89;  a1.u[1] = lh ? f2b : pAB;
        a1.u[2] = lh ? pCD : f1b;  a1.u[3] = lh ? pEF : f2b;
        bf16x8 pf0 = a0.v, pf1 = a1.v;
        // ---- PV: O^T[d][q] += V'^T . P^T   (A = V'^T rows d, B = P^T)
        const ushort* vrow = vbp + (kt << 5);
        #define PVSTEP(OA, DB) { \
            bf16x8 v0 = *(const bf16x8*)(vrow + (size_t)(DB) * 32 * 4096); \
            bf16x8 v1 = *(const bf16x8*)(vrow + (size_t)(DB) * 32 * 4096 + 16); \
            OA = __builtin_amdgcn_mfma_f32_32x32x16_bf16(v0, pf0, OA, 0, 0, 0); \
            OA = __builtin_amdgcn_mfma_f32_32x32x16_bf16(v1, pf1, OA, 0, 0, 0); }
        PVSTEP(oa0, 0) PVSTEP(oa1, 1) PVSTEP(oa2, 2) PVSTEP(oa3, 3)
        #undef PVSTEP
    }
    // ---- k-split reduction (kh=1 writes partials, kh=0 combines)
    if (kh == 1) {
        #define REDW(OA, DB) _Pragma("unroll") \
            for (int r = 0; r < 16; r += 2) { \
                const int c = (DB) * 32 + (r & 3) + 8 * (r >> 2) + 4 * lh; \
                *(float2*)&red[dh][lr][c] = make_float2((OA)[r], (OA)[r + 1]); }
        REDW(oa0, 0) REDW(oa1, 1) REDW(oa2, 2) REDW(oa3, 3)
        #undef REDW
    }
    __syncthreads();
    if (kh == 0) {
        #define REDR(OA, DB) _Pragma("unroll") \
            for (int r = 0; r < 16; r += 2) { \
                const int c = (DB) * 32 + (r & 3) + 8 * (r >> 2) + 4 * lh; \
                float2 p = *(float2*)&red[dh][lr][c]; \
                (OA)[r] += p.x; (OA)[r + 1] += p.y; \
                ushort2 u; u.x = f2bf((OA)[r]); u.y = f2bf((OA)[r + 1]); \
                *(ushort2*)&etr[dh][lr][c] = u; }
        REDR(oa0, 0) REDR(oa1, 1) REDR(oa2, 2) REDR(oa3, 3)
        #undef REDR
        // wave-local transpose-out: rows q, 128 d contiguous -> coalesced stores
        #pragma unroll
        for (int p = 0; p < 8; ++p) {
            const int idx = p * 64 + l;          // 0..511
            const int row = idx >> 4, ch = idx & 15;
            uint4 u = *(uint4*)&etr[dh][row][ch * 8];
            *(uint4*)(X + (kb4 + q0 + row) * 256 + d0 + ch * 8) = u;
        }
    }
}

// ------------------------------- conv3x3 + BN + SiLU as 9 shifted MFMA GEMMs
// X [b][p][ci] bf16 -> Y [b][p][co] bf16. Block: 64co x 128p, 4 waves (2x2).
__global__ __launch_bounds__(256, 2) void k_conv3_mfma(
    const ushort* __restrict__ X, const ushort* __restrict__ W9,
    const float* __restrict__ bn_g, const float* __restrict__ bn_b,
    const float* __restrict__ bn_m, const float* __restrict__ bn_v,
    ushort* __restrict__ Y)
{
    __shared__ float binv[256], badd[256];
    __shared__ ushort tr[128][72];               // [p_local][co_local], 144B rows
    const int t = threadIdx.x, w = t >> 6, l = t & 63, lr = l & 31, lh = l >> 5;
    {
        float inv = bn_g[t] * rsqrtf(bn_v[t] + 1e-3f);
        binv[t] = inv;
        badd[t] = bn_b[t] - bn_m[t] * inv;
    }
    __syncthreads();
    const int bid = blockIdx.x;                  // 4b x 4co x 32p
    const int b = bid >> 7, ct = (bid >> 5) & 3, pt = bid & 31;
    const int co0 = ct * 64, p0 = pt * 128;
    const int wc = w >> 1, wp = w & 1;
    const int h0 = (p0 >> 6) + wp;               // uniform h for this wave
    const int pA = p0 + wp * 64 + lr;
    const ushort* Xb = X + (size_t)b * 4096 * 256;
    const ushort* Wbase = W9 + (size_t)(co0 + wc * 32 + lr) * 256 + lh * 8;
    const bf16x8 bz = {};
    f32x16 o0{}, o1{};
    for (int dy = -1; dy <= 1; ++dy) {
        const int hh = h0 + dy;
        if (hh < 0 || hh > 63) continue;
        for (int dx = -1; dx <= 1; ++dx) {
            const int s = (dy + 1) * 3 + (dx + 1);
            const bool invA = (dx == -1) && (lr == 0);
            const bool invB = (dx == 1) && (lr == 31);
            const ushort* pAp = Xb + (size_t)(pA + dy * 64 + dx) * 256 + lh * 8;
            const ushort* pBp = pAp + 32 * 256;
            const ushort* wr  = Wbase + (size_t)s * 65536;
            #pragma unroll
            for (int ks = 0; ks < 16; ++ks) {
                bf16x8 af = *(const bf16x8*)(wr + ks * 16);
                bf16x8 b0 = *(const bf16x8*)(pAp + ks * 16);
                bf16x8 b1 = *(const bf16x8*)(pBp + ks * 16);
                if (invA) b0 = bz;
                if (invB) b1 = bz;
                o0 = __builtin_amdgcn_mfma_f32_32x32x16_bf16(af, b0, o0, 0, 0, 0);
                o1 = __builtin_amdgcn_mfma_f32_32x32x16_bf16(af, b1, o1, 0, 0, 0);
            }
        }
    }
    // BN + SiLU -> bf16, transpose to [p][co] through LDS
    #pragma unroll
    for (int r = 0; r < 16; ++r) {
        const int co_l = wc * 32 + (r & 3) + 8 * (r >> 2) + 4 * lh;
        const int co = co0 + co_l;
        const float inv = binv[co], add = badd[co];
        float x0 = o0[r] * inv + add;
        float x1 = o1[r] * inv + add;
        x0 = x0 / (1.f + expf(-x0));
        x1 = x1 / (1.f + expf(-x1));
        tr[wp * 64 + lr][co_l]      = f2bf(x0);
        tr[wp * 64 + 32 + lr][co_l] = f2bf(x1);
    }
    __syncthreads();
    // write-out: 128 rows x 64 cols; 256 threads x 32 ushorts = full tile
    const int pp = t >> 1, half = t & 1;
    uint4 u0 = *(uint4*)&tr[pp][half * 32];
    uint4 u1 = *(uint4*)&tr[pp][half * 32 + 8];
    uint4 u2 = *(uint4*)&tr[pp][half * 32 + 16];
    uint4 u3 = *(uint4*)&tr[pp][half * 32 + 24];
    ushort* yb = Y + ((size_t)b * 4096 + p0 + pp) * 256 + co0 + half * 32;
    *(uint4*)yb        = u0; *(uint4*)(yb + 8)  = u1;
    *(uint4*)(yb + 16) = u2; *(uint4*)(yb + 24) = u3;
}

// ------------------------- conv1x1 + bias + residual: out = q + Y @ W2^T + b2
// Y [b][p][ci] bf16, W2 [co][ci] bf16 -> out [b][co][p] f32 (coalesced stores)
__global__ __launch_bounds__(256, 2) void k_conv1x1_mfma(
    const ushort* __restrict__ Y, const ushort* __restrict__ W2,
    const float* __restrict__ bias2, const float* __restrict__ query,
    float* __restrict__ out)
{
    const int t = threadIdx.x, w = t >> 6, l = t & 63, lr = l & 31, lh = l >> 5;
    const int bid = blockIdx.x;                  // 4b x 4co x 32p
    const int b = bid >> 7, ct = (bid >> 5) & 3, pt = bid & 31;
    const int co0 = ct * 64, p0 = pt * 128;
    const int wc = w >> 1, wp = w & 1;
    const ushort* Wr = W2 + (size_t)(co0 + wc * 32 + lr) * 256 + lh * 8;
    const ushort* Yp = Y + ((size_t)b * 4096 + p0 + wp * 64 + lr) * 256 + lh * 8;
    f32x16 o0{}, o1{};
    #pragma unroll
    for (int ks = 0; ks < 16; ++ks) {
        bf16x8 wf = *(const bf16x8*)(Wr + ks * 16);
        bf16x8 y0 = *(const bf16x8*)(Yp + ks * 16);
        bf16x8 y1 = *(const bf16x8*)(Yp + 32 * 256 + ks * 16);
        o0 = __builtin_amdgcn_mfma_f32_32x32x16_bf16(wf, y0, o0, 0, 0, 0);
        o1 = __builtin_amdgcn_mfma_f32_32x32x16_bf16(wf, y1, o1, 0, 0, 0);
    }
    #pragma unroll
    for (int r = 0; r < 16; ++r) {
        const int co = co0 + wc * 32 + (r & 3) + 8 * (r >> 2) + 4 * lh;
        const float bb = bias2[co];
        const size_t base = ((size_t)b * 256 + co) * 4096 + p0 + wp * 64 + lr;
        out[base]      = o0[r] + bb + query[base];
        out[base + 32] = o1[r] + bb + query[base + 32];
    }
}

// ---------------------------------------------------------------- launch
extern "C" void kernel_launch(void* const* d_in, const int* in_sizes, int n_in,
                              void* d_out, int out_size, void* d_ws, size_t ws_size,
                              hipStream_t stream) {
    const float* query   = (const float*)d_in[0];
    const float* v_in    = (const float*)d_in[1];
    const float* qpos    = (const float*)d_in[2];
    const float* kpos    = (const float*)d_in[3];
    const float* otherW  = (const float*)d_in[4];
    const float* w_vs    = (const float*)d_in[5];
    const float* mlp_w1  = (const float*)d_in[6];
    const float* mlp_b1  = (const float*)d_in[7];
    const float* mlp_w2  = (const float*)d_in[8];
    const float* mlp_b2  = (const float*)d_in[9];
    const float* conv1_w = (const float*)d_in[10];
    const float* bn_g    = (const float*)d_in[11];
    const float* bn_b    = (const float*)d_in[12];
    const float* bn_m    = (const float*)d_in[13];
    const float* bn_v    = (const float*)d_in[14];
    const float* conv2_w = (const float*)d_in[15];
    const float* conv2_b = (const float*)d_in[16];
    float* out = (float*)d_out;
    char* base = (char*)d_ws;

    constexpr size_t MB = 1u << 20;
    ushort* v_bf    = (ushort*)(base);             // 8MB   (dead after vproj)
    ushort* qpos_bf = (ushort*)(base + 8 * MB);    // 8MB   (dead after mlp1)
    float*  qp_f32  = (float*) (base);             // 16MB  (aliases v_bf+qpos_bf)
    ushort* qhid_bf = (ushort*)(base + 16 * MB);   // 8MB   (dead after mlp2)
    ushort* X_bf    = (ushort*)(base + 16 * MB);   // 8MB   (attn out, aliases qhid)
    ushort* qn_bf   = (ushort*)(base + 24 * MB);   // 8MB   (dead after attn)
    ushort* Y_bf    = (ushort*)(base + 24 * MB);   // 8MB   (conv3 out, aliases qn)
    ushort* kn_bf   = (ushort*)(base + 32 * MB);   // 8MB
    ushort* vT_bf   = (ushort*)(base + 40 * MB);   // 8MB  (w-scaled V'^T)
    ushort* wvs_bf  = (ushort*)(base + 48 * MB);
    ushort* w1e_bf  = (ushort*)(base + 48 * MB + 128 * 1024);
    ushort* w2_bf   = (ushort*)(base + 48 * MB + 256 * 1024);
    ushort* c2_bf   = (ushort*)(base + 48 * MB + 384 * 1024);
    ushort* w9_bf   = (ushort*)(base + 48 * MB + 512 * 1024);   // 1.125MB

    k_cvt_v_scaled<<<4096, 256, 0, stream>>>(v_in, otherW, v_bf);
    k_cvt_bf16<<<64, 256, 0, stream>>>(w_vs, wvs_bf);
    k_cvt_bf16<<<64, 256, 0, stream>>>(mlp_w2, w2_bf);
    k_cvt_bf16<<<64, 256, 0, stream>>>(conv2_w, c2_bf);
    k_fold_w1<<<256, 256, 0, stream>>>(mlp_w1, w1e_bf);
    k_repack_w9<<<2304, 256, 0, stream>>>(conv1_w, w9_bf);
    k_cvt_bf16<<<4096, 256, 0, stream>>>(qpos, qpos_bf);

    k_gemm_mfma<2, 0><<<512, 256, 0, stream>>>(v_bf, wvs_bf, nullptr, vT_bf);
    k_gemm_mfma<1, 1><<<512, 256, 0, stream>>>(qpos_bf, w1e_bf, mlp_b1, qhid_bf);
    k_gemm_mfma<0, 0><<<512, 256, 0, stream>>>(qhid_bf, w2_bf, mlp_b2, qp_f32);
    k_l2norm_bf16<<<4096, 256, 0, stream>>>(qp_f32, qn_bf);
    k_l2norm_bf16<<<4096, 256, 0, stream>>>(kpos, kn_bf);
    k_attn_mfma<<<512, 256, 0, stream>>>(qn_bf, kn_bf, vT_bf, X_bf);
    k_conv3_mfma<<<512, 256, 0, stream>>>(X_bf, w9_bf, bn_g, bn_b, bn_m, bn_v, Y_bf);
    k_conv1x1_mfma<<<512, 256, 0, stream>>>(Y_bf, c2_bf, conv2_b, query, out);
}

// Round 8
// 320.931 us; speedup vs baseline: 1.9737x; 1.6928x over previous
//
#include <hip/hip_runtime.h>
#include <math.h>

// Fixed problem dims
constexpr int kB  = 4;
constexpr int kD  = 256;
constexpr int kNQ = 4096;
constexpr int kNK = 4096;
constexpr int kHW = 4096;   // 64*64

typedef __bf16 bf16x8 __attribute__((ext_vector_type(8)));
typedef float  f32x16 __attribute__((ext_vector_type(16)));

__device__ __forceinline__ unsigned short f2bf(float x) {
    unsigned int u = __builtin_bit_cast(unsigned int, x);
    u = (u + 0x7fffu + ((u >> 16) & 1u)) >> 16;
    return (unsigned short)u;
}

// ------------------------------------------------------------- f32 -> bf16
__global__ __launch_bounds__(256) void k_cvt_bf16(const float* __restrict__ in,
                                                  ushort* __restrict__ out) {
    const int i = blockIdx.x * 256 + threadIdx.x;   // one float4 each
    float4 v = ((const float4*)in)[i];
    ushort4 o;
    o.x = f2bf(v.x); o.y = f2bf(v.y); o.z = f2bf(v.z); o.w = f2bf(v.w);
    ((ushort4*)out)[i] = o;
}

// --------------------------------------- v * ow (row scale) -> bf16 (w-fold)
__global__ __launch_bounds__(256) void k_cvt_v_scaled(const float* __restrict__ in,
                                                      const float* __restrict__ ow,
                                                      ushort* __restrict__ out) {
    const int i = blockIdx.x * 256 + threadIdx.x;   // float4 id
    float4 v = ((const float4*)in)[i];
    const float wsc = ow[i >> 6];                   // (i*4)/256
    ushort4 o;
    o.x = f2bf(v.x * wsc); o.y = f2bf(v.y * wsc);
    o.z = f2bf(v.z * wsc); o.w = f2bf(v.w * wsc);
    ((ushort4*)out)[i] = o;
}

// ---------------------------------------------------------------- fold w1 -> bf16
__global__ void k_fold_w1(const float* __restrict__ w1, ushort* __restrict__ w1e) {
    int h = blockIdx.x, d = threadIdx.x;
    w1e[h * 256 + d] = f2bf(w1[h * 512 + d] + w1[h * 512 + 256 + d]);
}

// ------------------------------------------- conv1 weights -> bf16 [9][co][ci]
__global__ void k_repack_w9(const float* __restrict__ cw, ushort* __restrict__ w9) {
    const int ci = threadIdx.x;
    const int co = blockIdx.x & 255;
    const int s  = blockIdx.x >> 8;     // grid 9*256
    w9[((size_t)s * 256 + co) * 256 + ci] = f2bf(cw[((size_t)co * 256 + ci) * 9 + s]);
}

// ----------------------------------------------- generic MFMA GEMM  C = A @ W^T
// A [M,256] bf16, W [256,256] bf16 ([n][k]). Block: 128m x 64n, 4 waves (2x2).
// EPI: 0 = f32 [m][256]; 1 = bf16 [m][256];
// EPI 2 = bf16 K-TILED transpose: [b][kt=m/32][n(256)][m%32] (16KB contiguous tiles)
template<int EPI, int RELU>
__global__ __launch_bounds__(256, 2) void k_gemm_mfma(
    const ushort* __restrict__ A, const ushort* __restrict__ W,
    const float* __restrict__ bias, void* __restrict__ outp)
{
    const int t = threadIdx.x, w = t >> 6, l = t & 63, lr = l & 31, lh = l >> 5;
    const int m0 = (blockIdx.x >> 2) * 128;
    const int n0 = (blockIdx.x & 3) * 64;
    const int wm = w >> 1, wn = w & 1;
    const ushort* Ar0 = A + (size_t)(m0 + wm * 64 + lr) * 256 + lh * 8;
    const ushort* Ar1 = Ar0 + 32 * 256;
    const ushort* Wr  = W + (size_t)(n0 + wn * 32 + lr) * 256 + lh * 8;
    f32x16 c0{}, c1{};
    #pragma unroll
    for (int ks = 0; ks < 16; ++ks) {
        bf16x8 a0 = *(const bf16x8*)(Ar0 + ks * 16);
        bf16x8 a1 = *(const bf16x8*)(Ar1 + ks * 16);
        bf16x8 wf = *(const bf16x8*)(Wr + ks * 16);
        c0 = __builtin_amdgcn_mfma_f32_32x32x16_bf16(a0, wf, c0, 0, 0, 0);
        c1 = __builtin_amdgcn_mfma_f32_32x32x16_bf16(a1, wf, c1, 0, 0, 0);
    }
    const int n = n0 + wn * 32 + lr;            // C col for both accs
    float bb = bias ? bias[n] : 0.f;
    if constexpr (EPI == 2) {
        __shared__ ushort tr[64][136];          // [n_local][m_local]
        #pragma unroll
        for (int r = 0; r < 16; ++r) {
            const int ml = wm * 64 + (r & 3) + 8 * (r >> 2) + 4 * lh;
            float v0 = c0[r], v1 = c1[r];
            if (RELU) { v0 = fmaxf(v0, 0.f); v1 = fmaxf(v1, 0.f); }
            tr[wn * 32 + lr][ml]      = f2bf(v0);
            tr[wn * 32 + lr][ml + 32] = f2bf(v1);
        }
        __syncthreads();
        ushort* out = (ushort*)outp;
        const int b = m0 >> 12, mm = m0 & 4095;
        const int row = t >> 2, seg = t & 3;    // 64 rows x 4 segs of 32 cols
        uint4 u0 = *(uint4*)&tr[row][seg * 32];
        uint4 u1 = *(uint4*)&tr[row][seg * 32 + 8];
        uint4 u2 = *(uint4*)&tr[row][seg * 32 + 16];
        uint4 u3 = *(uint4*)&tr[row][seg * 32 + 24];
        // tiled layout: tile kt = mm/32 + seg, row d = n0+row, 32 contiguous k
        ushort* ob = out + ((size_t)(b * 128 + (mm >> 5) + seg) * 256 + n0 + row) * 32;
        *(uint4*)ob        = u0; *(uint4*)(ob + 8)  = u1;
        *(uint4*)(ob + 16) = u2; *(uint4*)(ob + 24) = u3;
    } else {
        #pragma unroll
        for (int r = 0; r < 16; ++r) {
            const int m = m0 + wm * 64 + (r & 3) + 8 * (r >> 2) + 4 * lh;
            float v0 = c0[r] + bb, v1 = c1[r] + bb;
            if (RELU) { v0 = fmaxf(v0, 0.f); v1 = fmaxf(v1, 0.f); }
            if constexpr (EPI == 0) {
                float* out = (float*)outp;
                out[(size_t)m * 256 + n]      = v0;
                out[(size_t)(m + 32) * 256 + n] = v1;
            } else {
                ushort* out = (ushort*)outp;
                out[(size_t)m * 256 + n]      = f2bf(v0);
                out[(size_t)(m + 32) * 256 + n] = f2bf(v1);
            }
        }
    }
}

// ---------------------------------------------------------------- L2 norm -> bf16
__global__ __launch_bounds__(256) void k_l2norm_bf16(const float* __restrict__ in,
                                                     ushort* __restrict__ out) {
    const int row  = blockIdx.x * 4 + (threadIdx.x >> 6);
    const int lane = threadIdx.x & 63;
    float4 v = ((const float4*)(in + (size_t)row * 256))[lane];
    float ss = v.x * v.x + v.y * v.y + v.z * v.z + v.w * v.w;
    #pragma unroll
    for (int off = 32; off; off >>= 1) ss += __shfl_xor(ss, off, 64);
    const float rn = 1.0f / sqrtf(ss);
    ushort4 o;
    o.x = f2bf(v.x * rn); o.y = f2bf(v.y * rn);
    o.z = f2bf(v.z * rn); o.w = f2bf(v.w * rn);
    ((ushort4*)(out + (size_t)row * 256))[lane] = o;
}

// ---------------------------------------------------------------- MFMA attention
// X[b][q][d] (bf16) = sum_k relu(qn.kn) * vT'[d][k]  (w folded in V')
// m97-canonical: global_load_lds staging -> dbuf LDS -> swizzled ds_read frags.
// grid 256 = b(4) x qtile(64 rows); 4 waves = (qg 0/1 x dh 0/1); QK dup x2 over dh.
__global__ __launch_bounds__(256, 2) void k_attn_mfma(
    const ushort* __restrict__ qn, const ushort* __restrict__ kn,
    const ushort* __restrict__ vpT, ushort* __restrict__ X)
{
    __shared__ __align__(16) char lds[65536];   // 2 bufs x (K 16K + V 16K)
    const int t = threadIdx.x, w = t >> 6, l = t & 63, lr = l & 31, lh = l >> 5;
    const int qg = w >> 1, dh = w & 1;
    const int bid0 = blockIdx.x;
    const int L = (bid0 & 7) * 32 + (bid0 >> 3);    // XCD clustering (256 = 8*32)
    const int b = L >> 6, qt = L & 63;
    const int q0 = qt << 6;

    // per-lane staging source offsets (constant across k-chunks)
    int koff[4], voff[4];
    #pragma unroll
    for (int i = 0; i < 4; ++i) {
        const int p = i * 256 + t;
        koff[i] = ((p >> 5) << 9) + ((((p & 31) ^ (p >> 5))) << 4);
        const int R  = p >> 4;
        const int ch = (p & 15) ^ (R & 15);
        voff[i] = (((((ch >> 2) << 6) | R)) << 6) + ((ch & 3) << 4);
    }
    const char* kgb = (const char*)(kn + (size_t)b * 4096 * 256);
    const char* vgb = (const char*)vpT + (size_t)b * 128 * 16384;

    #define STAGE(bb, tc) do { \
        const char* ks_ = kgb + (size_t)(tc) * 16384; \
        const char* vs_ = vgb + (size_t)(tc) * 16384; \
        char* kd_ = lds + (bb) * 32768; \
        char* vd_ = kd_ + 16384; \
        _Pragma("unroll") \
        for (int i_ = 0; i_ < 4; ++i_) { \
            __builtin_amdgcn_global_load_lds( \
                (const __attribute__((address_space(1))) unsigned*)(ks_ + koff[i_]), \
                (__attribute__((address_space(3))) unsigned*)(kd_ + (i_ * 256 + w * 64) * 16), 16, 0, 0); \
            __builtin_amdgcn_global_load_lds( \
                (const __attribute__((address_space(1))) unsigned*)(vs_ + voff[i_]), \
                (__attribute__((address_space(3))) unsigned*)(vd_ + (i_ * 256 + w * 64) * 16), 16, 0, 0); \
        } } while (0)

    // Q fragments (wave's 32 q rows; one-time gather, amortized)
    const ushort* qrow = qn + ((size_t)b * 4096 + q0 + qg * 32 + lr) * 256 + lh * 8;
    bf16x8 qf[16];
    #pragma unroll
    for (int ks = 0; ks < 16; ++ks) qf[ks] = *(const bf16x8*)(qrow + ks * 16);

    f32x16 oa0{}, oa1{}, oa2{}, oa3{};

    STAGE(0, 0);
    __syncthreads();
    for (int kt = 0; kt < 128; ++kt) {
        const int bb = kt & 1;
        if (kt + 1 < 128) STAGE(bb ^ 1, kt + 1);
        const char* kb = lds + bb * 32768;
        const char* vb = kb + 16384;
        // ---- QK^T: S^T[32k][32q], A = K rows (LDS, 32-slot swizzle), B = Q regs
        f32x16 s0{}, s1{};
        #pragma unroll
        for (int ks = 0; ks < 16; ks += 2) {
            bf16x8 ka = *(const bf16x8*)(kb + lr * 512 + (((2 * ks     + lh) ^ lr) << 4));
            bf16x8 kc = *(const bf16x8*)(kb + lr * 512 + (((2 * ks + 2 + lh) ^ lr) << 4));
            s0 = __builtin_amdgcn_mfma_f32_32x32x16_bf16(ka, qf[ks],     s0, 0, 0, 0);
            s1 = __builtin_amdgcn_mfma_f32_32x32x16_bf16(kc, qf[ks + 1], s1, 0, 0, 0);
        }
        f32x16 s = s0 + s1;
        // ---- in-register P^T B-frags (round-7-verified pack)
        #define PKR(A, B) ((unsigned)f2bf(fmaxf((A), 0.f)) | ((unsigned)f2bf(fmaxf((B), 0.f)) << 16))
        unsigned p01 = PKR(s[0],  s[1]),  p23 = PKR(s[2],  s[3]);
        unsigned p45 = PKR(s[4],  s[5]),  p67 = PKR(s[6],  s[7]);
        unsigned p89 = PKR(s[8],  s[9]),  pAB = PKR(s[10], s[11]);
        unsigned pCD = PKR(s[12], s[13]), pEF = PKR(s[14], s[15]);
        #undef PKR
        unsigned e1a = lh ? p01 : p45,  e2a = lh ? p23 : p67;
        unsigned e1b = lh ? p89 : pCD,  e2b = lh ? pAB : pEF;
        unsigned f1a = (unsigned)__shfl_xor((int)e1a, 32, 64);
        unsigned f2a = (unsigned)__shfl_xor((int)e2a, 32, 64);
        unsigned f1b = (unsigned)__shfl_xor((int)e1b, 32, 64);
        unsigned f2b = (unsigned)__shfl_xor((int)e2b, 32, 64);
        union U4 { unsigned u[4]; bf16x8 v; };
        U4 a0, a1;
        a0.u[0] = lh ? f1a : p01;  a0.u[1] = lh ? f2a : p23;
        a0.u[2] = lh ? p45 : f1a;  a0.u[3] = lh ? p67 : f2a;
        a1.u[0] = lh ? f1b : p89;  a1.u[1] = lh ? f2b : pAB;
        a1.u[2] = lh ? pCD : f1b;  a1.u[3] = lh ? pEF : f2b;
        bf16x8 pf0 = a0.v, pf1 = a1.v;
        // ---- PV: O^T[d][q] += V'^T . P^T ; A = V rows d (LDS, 16-slot swizzle)
        #define PVD(OA, DB) { \
            const int R_  = (((dh << 2) + (DB)) & 1) * 32 + lr; \
            const int sg_ = ((dh << 2) + (DB)) >> 1; \
            bf16x8 v0_ = *(const bf16x8*)(vb + R_ * 256 + ((((sg_ << 2) + lh)     ^ (lr & 15)) << 4)); \
            bf16x8 v1_ = *(const bf16x8*)(vb + R_ * 256 + ((((sg_ << 2) + 2 + lh) ^ (lr & 15)) << 4)); \
            OA = __builtin_amdgcn_mfma_f32_32x32x16_bf16(v0_, pf0, OA, 0, 0, 0); \
            OA = __builtin_amdgcn_mfma_f32_32x32x16_bf16(v1_, pf1, OA, 0, 0, 0); }
        PVD(oa0, 0) PVD(oa1, 1) PVD(oa2, 2) PVD(oa3, 3)
        #undef PVD
        __syncthreads();   // stage(kt+1) landed (drain) + all waves done with buf bb
    }
    #undef STAGE
    // ---- epilogue: direct bf16 scatter (once): lane lr = q row, regs = d
    ushort* Xb = X + ((size_t)b * 4096 + q0 + qg * 32 + lr) * 256 + dh * 128;
    #define OUTD(OA, DB) _Pragma("unroll") \
        for (int r = 0; r < 16; r += 2) { \
            const int d_ = (DB) * 32 + (r & 3) + 8 * (r >> 2) + 4 * lh; \
            ushort2 u_; u_.x = f2bf((OA)[r]); u_.y = f2bf((OA)[r + 1]); \
            *(ushort2*)(Xb + d_) = u_; }
    OUTD(oa0, 0) OUTD(oa1, 1) OUTD(oa2, 2) OUTD(oa3, 3)
    #undef OUTD
}

// ------------------------------- conv3x3 + BN + SiLU as 9 shifted MFMA GEMMs
// X [b][p][ci] bf16 -> Y [b][p][co] bf16. Block: 64co x 128p, 4 waves (2x2).
__global__ __launch_bounds__(256, 2) void k_conv3_mfma(
    const ushort* __restrict__ X, const ushort* __restrict__ W9,
    const float* __restrict__ bn_g, const float* __restrict__ bn_b,
    const float* __restrict__ bn_m, const float* __restrict__ bn_v,
    ushort* __restrict__ Y)
{
    __shared__ float binv[256], badd[256];
    __shared__ ushort tr[128][72];               // [p_local][co_local]
    const int t = threadIdx.x, w = t >> 6, l = t & 63, lr = l & 31, lh = l >> 5;
    {
        float inv = bn_g[t] * rsqrtf(bn_v[t] + 1e-3f);
        binv[t] = inv;
        badd[t] = bn_b[t] - bn_m[t] * inv;
    }
    __syncthreads();
    const int bid = blockIdx.x;                  // 4b x 4co x 32p
    const int b = bid >> 7, ct = (bid >> 5) & 3, pt = bid & 31;
    const int co0 = ct * 64, p0 = pt * 128;
    const int wc = w >> 1, wp = w & 1;
    const int h0 = (p0 >> 6) + wp;
    const int pA = p0 + wp * 64 + lr;
    const ushort* Xb = X + (size_t)b * 4096 * 256;
    const ushort* Wbase = W9 + (size_t)(co0 + wc * 32 + lr) * 256 + lh * 8;
    const bf16x8 bz = {};
    f32x16 o0{}, o1{};
    for (int dy = -1; dy <= 1; ++dy) {
        const int hh = h0 + dy;
        if (hh < 0 || hh > 63) continue;
        for (int dx = -1; dx <= 1; ++dx) {
            const int s = (dy + 1) * 3 + (dx + 1);
            const bool invA = (dx == -1) && (lr == 0);
            const bool invB = (dx == 1) && (lr == 31);
            const ushort* pAp = Xb + (size_t)(pA + dy * 64 + dx) * 256 + lh * 8;
            const ushort* pBp = pAp + 32 * 256;
            const ushort* wr  = Wbase + (size_t)s * 65536;
            #pragma unroll
            for (int ks = 0; ks < 16; ++ks) {
                bf16x8 af = *(const bf16x8*)(wr + ks * 16);
                bf16x8 b0 = *(const bf16x8*)(pAp + ks * 16);
                bf16x8 b1 = *(const bf16x8*)(pBp + ks * 16);
                if (invA) b0 = bz;
                if (invB) b1 = bz;
                o0 = __builtin_amdgcn_mfma_f32_32x32x16_bf16(af, b0, o0, 0, 0, 0);
                o1 = __builtin_amdgcn_mfma_f32_32x32x16_bf16(af, b1, o1, 0, 0, 0);
            }
        }
    }
    #pragma unroll
    for (int r = 0; r < 16; ++r) {
        const int co_l = wc * 32 + (r & 3) + 8 * (r >> 2) + 4 * lh;
        const int co = co0 + co_l;
        const float inv = binv[co], add = badd[co];
        float x0 = o0[r] * inv + add;
        float x1 = o1[r] * inv + add;
        x0 = x0 / (1.f + expf(-x0));
        x1 = x1 / (1.f + expf(-x1));
        tr[wp * 64 + lr][co_l]      = f2bf(x0);
        tr[wp * 64 + 32 + lr][co_l] = f2bf(x1);
    }
    __syncthreads();
    const int pp = t >> 1, half = t & 1;
    uint4 u0 = *(uint4*)&tr[pp][half * 32];
    uint4 u1 = *(uint4*)&tr[pp][half * 32 + 8];
    uint4 u2 = *(uint4*)&tr[pp][half * 32 + 16];
    uint4 u3 = *(uint4*)&tr[pp][half * 32 + 24];
    ushort* yb = Y + ((size_t)b * 4096 + p0 + pp) * 256 + co0 + half * 32;
    *(uint4*)yb        = u0; *(uint4*)(yb + 8)  = u1;
    *(uint4*)(yb + 16) = u2; *(uint4*)(yb + 24) = u3;
}

// ------------------------- conv1x1 + bias + residual: out = q + Y @ W2^T + b2
__global__ __launch_bounds__(256, 2) void k_conv1x1_mfma(
    const ushort* __restrict__ Y, const ushort* __restrict__ W2,
    const float* __restrict__ bias2, const float* __restrict__ query,
    float* __restrict__ out)
{
    const int t = threadIdx.x, w = t >> 6, l = t & 63, lr = l & 31, lh = l >> 5;
    const int bid = blockIdx.x;                  // 4b x 4co x 32p
    const int b = bid >> 7, ct = (bid >> 5) & 3, pt = bid & 31;
    const int co0 = ct * 64, p0 = pt * 128;
    const int wc = w >> 1, wp = w & 1;
    const ushort* Wr = W2 + (size_t)(co0 + wc * 32 + lr) * 256 + lh * 8;
    const ushort* Yp = Y + ((size_t)b * 4096 + p0 + wp * 64 + lr) * 256 + lh * 8;
    f32x16 o0{}, o1{};
    #pragma unroll
    for (int ks = 0; ks < 16; ++ks) {
        bf16x8 wf = *(const bf16x8*)(Wr + ks * 16);
        bf16x8 y0 = *(const bf16x8*)(Yp + ks * 16);
        bf16x8 y1 = *(const bf16x8*)(Yp + 32 * 256 + ks * 16);
        o0 = __builtin_amdgcn_mfma_f32_32x32x16_bf16(wf, y0, o0, 0, 0, 0);
        o1 = __builtin_amdgcn_mfma_f32_32x32x16_bf16(wf, y1, o1, 0, 0, 0);
    }
    #pragma unroll
    for (int r = 0; r < 16; ++r) {
        const int co = co0 + wc * 32 + (r & 3) + 8 * (r >> 2) + 4 * lh;
        const float bb = bias2[co];
        const size_t base = ((size_t)b * 256 + co) * 4096 + p0 + wp * 64 + lr;
        out[base]      = o0[r] + bb + query[base];
        out[base + 32] = o1[r] + bb + query[base + 32];
    }
}

// ---------------------------------------------------------------- launch
extern "C" void kernel_launch(void* const* d_in, const int* in_sizes, int n_in,
                              void* d_out, int out_size, void* d_ws, size_t ws_size,
                              hipStream_t stream) {
    const float* query   = (const float*)d_in[0];
    const float* v_in    = (const float*)d_in[1];
    const float* qpos    = (const float*)d_in[2];
    const float* kpos    = (const float*)d_in[3];
    const float* otherW  = (const float*)d_in[4];
    const float* w_vs    = (const float*)d_in[5];
    const float* mlp_w1  = (const float*)d_in[6];
    const float* mlp_b1  = (const float*)d_in[7];
    const float* mlp_w2  = (const float*)d_in[8];
    const float* mlp_b2  = (const float*)d_in[9];
    const float* conv1_w = (const float*)d_in[10];
    const float* bn_g    = (const float*)d_in[11];
    const float* bn_b    = (const float*)d_in[12];
    const float* bn_m    = (const float*)d_in[13];
    const float* bn_v    = (const float*)d_in[14];
    const float* conv2_w = (const float*)d_in[15];
    const float* conv2_b = (const float*)d_in[16];
    float* out = (float*)d_out;
    char* base = (char*)d_ws;

    constexpr size_t MB = 1u << 20;
    ushort* v_bf    = (ushort*)(base);             // 8MB   (dead after vproj)
    ushort* qpos_bf = (ushort*)(base + 8 * MB);    // 8MB   (dead after mlp1)
    float*  qp_f32  = (float*) (base);             // 16MB  (aliases v_bf+qpos_bf)
    ushort* qhid_bf = (ushort*)(base + 16 * MB);   // 8MB   (dead after mlp2)
    ushort* X_bf    = (ushort*)(base + 16 * MB);   // 8MB   (attn out, aliases qhid)
    ushort* qn_bf   = (ushort*)(base + 24 * MB);   // 8MB   (dead after attn)
    ushort* Y_bf    = (ushort*)(base + 24 * MB);   // 8MB   (conv3 out, aliases qn)
    ushort* kn_bf   = (ushort*)(base + 32 * MB);   // 8MB
    ushort* vT_bf   = (ushort*)(base + 40 * MB);   // 8MB  (w-scaled V'^T, k-tiled)
    ushort* wvs_bf  = (ushort*)(base + 48 * MB);
    ushort* w1e_bf  = (ushort*)(base + 48 * MB + 128 * 1024);
    ushort* w2_bf   = (ushort*)(base + 48 * MB + 256 * 1024);
    ushort* c2_bf   = (ushort*)(base + 48 * MB + 384 * 1024);
    ushort* w9_bf   = (ushort*)(base + 48 * MB + 512 * 1024);   // 1.125MB

    k_cvt_v_scaled<<<4096, 256, 0, stream>>>(v_in, otherW, v_bf);
    k_cvt_bf16<<<64, 256, 0, stream>>>(w_vs, wvs_bf);
    k_cvt_bf16<<<64, 256, 0, stream>>>(mlp_w2, w2_bf);
    k_cvt_bf16<<<64, 256, 0, stream>>>(conv2_w, c2_bf);
    k_fold_w1<<<256, 256, 0, stream>>>(mlp_w1, w1e_bf);
    k_repack_w9<<<2304, 256, 0, stream>>>(conv1_w, w9_bf);
    k_cvt_bf16<<<4096, 256, 0, stream>>>(qpos, qpos_bf);

    k_gemm_mfma<2, 0><<<512, 256, 0, stream>>>(v_bf, wvs_bf, nullptr, vT_bf);
    k_gemm_mfma<1, 1><<<512, 256, 0, stream>>>(qpos_bf, w1e_bf, mlp_b1, qhid_bf);
    k_gemm_mfma<0, 0><<<512, 256, 0, stream>>>(qhid_bf, w2_bf, mlp_b2, qp_f32);
    k_l2norm_bf16<<<4096, 256, 0, stream>>>(qp_f32, qn_bf);
    k_l2norm_bf16<<<4096, 256, 0, stream>>>(kpos, kn_bf);
    k_attn_mfma<<<256, 256, 0, stream>>>(qn_bf, kn_bf, vT_bf, X_bf);
    k_conv3_mfma<<<512, 256, 0, stream>>>(X_bf, w9_bf, bn_g, bn_b, bn_m, bn_v, Y_bf);
    k_conv1x1_mfma<<<512, 256, 0, stream>>>(Y_bf, c2_bf, conv2_b, query, out);
}

// Round 9
// 281.395 us; speedup vs baseline: 2.2510x; 1.1405x over previous
//
#include <hip/hip_runtime.h>
#include <math.h>

// Fixed problem dims
constexpr int kB  = 4;
constexpr int kD  = 256;
constexpr int kNQ = 4096;
constexpr int kNK = 4096;
constexpr int kHW = 4096;   // 64*64

typedef __bf16 bf16x8 __attribute__((ext_vector_type(8)));
typedef float  f32x16 __attribute__((ext_vector_type(16)));

__device__ __forceinline__ unsigned short f2bf(float x) {
    unsigned int u = __builtin_bit_cast(unsigned int, x);
    u = (u + 0x7fffu + ((u >> 16) & 1u)) >> 16;
    return (unsigned short)u;
}

// =============================================== fused prep (1 launch, 15040 blocks)
// [0,4096)      v * ow -> bf16
// [4096,8192)   qpos -> bf16
// [8192,12288)  l2norm(kpos) -> bf16
// [12288,14592) conv1 w repack -> packed [s][cb][k][lane][8]
// [14592,14656) w_vs cvt ; [14656,14720) mlp_w2 cvt ; [14720,14784) conv2_w cvt
// [14784,15040) fold w1 -> bf16
__global__ __launch_bounds__(256) void k_prep(
    const float* __restrict__ v_in, const float* __restrict__ ow, ushort* __restrict__ v_bf,
    const float* __restrict__ qpos, ushort* __restrict__ qpos_bf,
    const float* __restrict__ kpos, ushort* __restrict__ kn_bf,
    const float* __restrict__ conv1_w, ushort* __restrict__ w9p,
    const float* __restrict__ w_vs, ushort* __restrict__ wvs_bf,
    const float* __restrict__ mlp_w2, ushort* __restrict__ w2_bf,
    const float* __restrict__ conv2_w, ushort* __restrict__ c2_bf,
    const float* __restrict__ mlp_w1, ushort* __restrict__ w1e_bf)
{
    const int bid = blockIdx.x, t = threadIdx.x;
    if (bid < 4096) {
        const int i = bid * 256 + t;
        float4 v = ((const float4*)v_in)[i];
        const float wsc = ow[i >> 6];
        ushort4 o;
        o.x = f2bf(v.x * wsc); o.y = f2bf(v.y * wsc);
        o.z = f2bf(v.z * wsc); o.w = f2bf(v.w * wsc);
        ((ushort4*)v_bf)[i] = o;
    } else if (bid < 8192) {
        const int i = (bid - 4096) * 256 + t;
        float4 v = ((const float4*)qpos)[i];
        ushort4 o;
        o.x = f2bf(v.x); o.y = f2bf(v.y); o.z = f2bf(v.z); o.w = f2bf(v.w);
        ((ushort4*)qpos_bf)[i] = o;
    } else if (bid < 12288) {
        const int row  = (bid - 8192) * 4 + (t >> 6);
        const int lane = t & 63;
        float4 v = ((const float4*)(kpos + (size_t)row * 256))[lane];
        float ss = v.x * v.x + v.y * v.y + v.z * v.z + v.w * v.w;
        #pragma unroll
        for (int off = 32; off; off >>= 1) ss += __shfl_xor(ss, off, 64);
        const float rn = 1.0f / sqrtf(ss);
        ushort4 o;
        o.x = f2bf(v.x * rn); o.y = f2bf(v.y * rn);
        o.z = f2bf(v.z * rn); o.w = f2bf(v.w * rn);
        ((ushort4*)(kn_bf + (size_t)row * 256))[lane] = o;
    } else if (bid < 14592) {
        const int idx = bid - 12288;
        const int s = idx >> 8, co = idx & 255, ci = t;
        const int oidx = ((s * 8 + (co >> 5)) * 16 + (ci >> 4)) * 512
                       + ((ci >> 3) & 1) * 256 + (co & 31) * 8 + (ci & 7);
        w9p[oidx] = f2bf(conv1_w[((size_t)co * 256 + ci) * 9 + s]);
    } else if (bid < 14784) {
        const float* src = (bid < 14656) ? w_vs : (bid < 14720) ? mlp_w2 : conv2_w;
        ushort* dst = (bid < 14656) ? wvs_bf : (bid < 14720) ? w2_bf : c2_bf;
        const int i = ((bid - 14592) & 63) * 256 + t;
        float4 v = ((const float4*)src)[i];
        ushort4 o;
        o.x = f2bf(v.x); o.y = f2bf(v.y); o.z = f2bf(v.z); o.w = f2bf(v.w);
        ((ushort4*)dst)[i] = o;
    } else {
        const int h = bid - 14784;
        w1e_bf[h * 256 + t] = f2bf(mlp_w1[h * 512 + t] + mlp_w1[h * 512 + 256 + t]);
    }
}

// ----------------------------------------------- generic MFMA GEMM  C = A @ W^T
// A [M,256] bf16, W [256,256] bf16 ([n][k]). Block: 128m x 64n, 4 waves (2x2).
// EPI: 0 = f32 [m][256]; 1 = bf16 [m][256];
// EPI 2 = bf16 K-TILED transpose: [b][kt=m/32][n(256)][m%32] (16KB contiguous tiles)
template<int EPI, int RELU>
__global__ __launch_bounds__(256, 2) void k_gemm_mfma(
    const ushort* __restrict__ A, const ushort* __restrict__ W,
    const float* __restrict__ bias, void* __restrict__ outp)
{
    const int t = threadIdx.x, w = t >> 6, l = t & 63, lr = l & 31, lh = l >> 5;
    const int m0 = (blockIdx.x >> 2) * 128;
    const int n0 = (blockIdx.x & 3) * 64;
    const int wm = w >> 1, wn = w & 1;
    const ushort* Ar0 = A + (size_t)(m0 + wm * 64 + lr) * 256 + lh * 8;
    const ushort* Ar1 = Ar0 + 32 * 256;
    const ushort* Wr  = W + (size_t)(n0 + wn * 32 + lr) * 256 + lh * 8;
    f32x16 c0{}, c1{};
    #pragma unroll
    for (int ks = 0; ks < 16; ++ks) {
        bf16x8 a0 = *(const bf16x8*)(Ar0 + ks * 16);
        bf16x8 a1 = *(const bf16x8*)(Ar1 + ks * 16);
        bf16x8 wf = *(const bf16x8*)(Wr + ks * 16);
        c0 = __builtin_amdgcn_mfma_f32_32x32x16_bf16(a0, wf, c0, 0, 0, 0);
        c1 = __builtin_amdgcn_mfma_f32_32x32x16_bf16(a1, wf, c1, 0, 0, 0);
    }
    const int n = n0 + wn * 32 + lr;            // C col for both accs
    float bb = bias ? bias[n] : 0.f;
    if constexpr (EPI == 2) {
        __shared__ ushort tr[64][136];          // [n_local][m_local]
        #pragma unroll
        for (int r = 0; r < 16; ++r) {
            const int ml = wm * 64 + (r & 3) + 8 * (r >> 2) + 4 * lh;
            float v0 = c0[r], v1 = c1[r];
            if (RELU) { v0 = fmaxf(v0, 0.f); v1 = fmaxf(v1, 0.f); }
            tr[wn * 32 + lr][ml]      = f2bf(v0);
            tr[wn * 32 + lr][ml + 32] = f2bf(v1);
        }
        __syncthreads();
        ushort* out = (ushort*)outp;
        const int b = m0 >> 12, mm = m0 & 4095;
        const int row = t >> 2, seg = t & 3;    // 64 rows x 4 segs of 32 cols
        uint4 u0 = *(uint4*)&tr[row][seg * 32];
        uint4 u1 = *(uint4*)&tr[row][seg * 32 + 8];
        uint4 u2 = *(uint4*)&tr[row][seg * 32 + 16];
        uint4 u3 = *(uint4*)&tr[row][seg * 32 + 24];
        // tiled layout: tile kt = mm/32 + seg, row d = n0+row, 32 contiguous k
        ushort* ob = out + ((size_t)(b * 128 + (mm >> 5) + seg) * 256 + n0 + row) * 32;
        *(uint4*)ob        = u0; *(uint4*)(ob + 8)  = u1;
        *(uint4*)(ob + 16) = u2; *(uint4*)(ob + 24) = u3;
    } else {
        #pragma unroll
        for (int r = 0; r < 16; ++r) {
            const int m = m0 + wm * 64 + (r & 3) + 8 * (r >> 2) + 4 * lh;
            float v0 = c0[r] + bb, v1 = c1[r] + bb;
            if (RELU) { v0 = fmaxf(v0, 0.f); v1 = fmaxf(v1, 0.f); }
            if constexpr (EPI == 0) {
                float* out = (float*)outp;
                out[(size_t)m * 256 + n]      = v0;
                out[(size_t)(m + 32) * 256 + n] = v1;
            } else {
                ushort* out = (ushort*)outp;
                out[(size_t)m * 256 + n]      = f2bf(v0);
                out[(size_t)(m + 32) * 256 + n] = f2bf(v1);
            }
        }
    }
}

// ---------------------------------------------------------------- L2 norm -> bf16
__global__ __launch_bounds__(256) void k_l2norm_bf16(const float* __restrict__ in,
                                                     ushort* __restrict__ out) {
    const int row  = blockIdx.x * 4 + (threadIdx.x >> 6);
    const int lane = threadIdx.x & 63;
    float4 v = ((const float4*)(in + (size_t)row * 256))[lane];
    float ss = v.x * v.x + v.y * v.y + v.z * v.z + v.w * v.w;
    #pragma unroll
    for (int off = 32; off; off >>= 1) ss += __shfl_xor(ss, off, 64);
    const float rn = 1.0f / sqrtf(ss);
    ushort4 o;
    o.x = f2bf(v.x * rn); o.y = f2bf(v.y * rn);
    o.z = f2bf(v.z * rn); o.w = f2bf(v.w * rn);
    ((ushort4*)(out + (size_t)row * 256))[lane] = o;
}

// ---------------------------------------------------------------- MFMA attention
// X[b][q][d] (bf16) = sum_k relu(qn.kn) * vT'[d][k]  (w folded in V')
// 4-buf global_load_lds pipeline, counted vmcnt (T3/T4), setprio (T5).
// grid 256 = b(4) x qtile(64 rows); 4 waves = (qg 0/1 x dh 0/1); QK dup x2 over dh.
__global__ __launch_bounds__(256, 1) void k_attn_mfma(
    const ushort* __restrict__ qn, const ushort* __restrict__ kn,
    const ushort* __restrict__ vpT, ushort* __restrict__ X)
{
    __shared__ __align__(16) char lds[131072];   // 4 bufs x (K 16K + V 16K)
    const int t = threadIdx.x, w = t >> 6, l = t & 63, lr = l & 31, lh = l >> 5;
    const int qg = w >> 1, dh = w & 1;
    const int bid0 = blockIdx.x;
    const int L = (bid0 & 7) * 32 + (bid0 >> 3);    // XCD clustering (256 = 8*32)
    const int b = L >> 6, qt = L & 63;
    const int q0 = qt << 6;

    // per-lane staging source offsets (constant across k-chunks)
    int koff[4], voff[4];
    #pragma unroll
    for (int i = 0; i < 4; ++i) {
        const int p = i * 256 + t;
        koff[i] = ((p >> 5) << 9) + ((((p & 31) ^ (p >> 5))) << 4);
        const int R  = p >> 4;
        const int ch = (p & 15) ^ (R & 15);
        voff[i] = (((((ch >> 2) << 6) | R)) << 6) + ((ch & 3) << 4);
    }
    const char* kgb = (const char*)(kn + (size_t)b * 4096 * 256);
    const char* vgb = (const char*)vpT + (size_t)b * 128 * 16384;

    #define STAGE(bb, tc) do { \
        const char* ks_ = kgb + (size_t)(tc) * 16384; \
        const char* vs_ = vgb + (size_t)(tc) * 16384; \
        char* kd_ = lds + (bb) * 32768; \
        char* vd_ = kd_ + 16384; \
        _Pragma("unroll") \
        for (int i_ = 0; i_ < 4; ++i_) { \
            __builtin_amdgcn_global_load_lds( \
                (const __attribute__((address_space(1))) unsigned*)(ks_ + koff[i_]), \
                (__attribute__((address_space(3))) unsigned*)(kd_ + (i_ * 256 + w * 64) * 16), 16, 0, 0); \
            __builtin_amdgcn_global_load_lds( \
                (const __attribute__((address_space(1))) unsigned*)(vs_ + voff[i_]), \
                (__attribute__((address_space(3))) unsigned*)(vd_ + (i_ * 256 + w * 64) * 16), 16, 0, 0); \
        } } while (0)

    // Q fragments (wave's 32 q rows; one-time gather, amortized)
    const ushort* qrow = qn + ((size_t)b * 4096 + q0 + qg * 32 + lr) * 256 + lh * 8;
    bf16x8 qf[16];
    #pragma unroll
    for (int ks = 0; ks < 16; ++ks) qf[ks] = *(const bf16x8*)(qrow + ks * 16);

    f32x16 oa0{}, oa1{}, oa2{}, oa3{};

    STAGE(0, 0); STAGE(1, 1); STAGE(2, 2);
    for (int kt = 0; kt < 128; ++kt) {
        // counted wait: tile kt landed; up to 2 tiles stay in flight (T4)
        if (kt < 126)       asm volatile("s_waitcnt vmcnt(16)" ::: "memory");
        else if (kt == 126) asm volatile("s_waitcnt vmcnt(8)" ::: "memory");
        else                asm volatile("s_waitcnt vmcnt(0)" ::: "memory");
        __builtin_amdgcn_s_barrier();
        if (kt + 3 < 128) STAGE((kt + 3) & 3, kt + 3);   // overwrites buf of kt-1 (all done)
        const char* kb = lds + (kt & 3) * 32768;
        const char* vb = kb + 16384;
        // ---- QK^T: S^T[32k][32q], A = K rows (LDS, 32-slot swizzle), B = Q regs
        f32x16 s0{}, s1{};
        __builtin_amdgcn_s_setprio(1);
        #pragma unroll
        for (int ks = 0; ks < 16; ks += 2) {
            bf16x8 ka = *(const bf16x8*)(kb + lr * 512 + (((2 * ks     + lh) ^ lr) << 4));
            bf16x8 kc = *(const bf16x8*)(kb + lr * 512 + (((2 * ks + 2 + lh) ^ lr) << 4));
            s0 = __builtin_amdgcn_mfma_f32_32x32x16_bf16(ka, qf[ks],     s0, 0, 0, 0);
            s1 = __builtin_amdgcn_mfma_f32_32x32x16_bf16(kc, qf[ks + 1], s1, 0, 0, 0);
        }
        __builtin_amdgcn_s_setprio(0);
        f32x16 s = s0 + s1;
        // ---- in-register P^T B-frags (round-7-verified pack)
        #define PKR(A, B) ((unsigned)f2bf(fmaxf((A), 0.f)) | ((unsigned)f2bf(fmaxf((B), 0.f)) << 16))
        unsigned p01 = PKR(s[0],  s[1]),  p23 = PKR(s[2],  s[3]);
        unsigned p45 = PKR(s[4],  s[5]),  p67 = PKR(s[6],  s[7]);
        unsigned p89 = PKR(s[8],  s[9]),  pAB = PKR(s[10], s[11]);
        unsigned pCD = PKR(s[12], s[13]), pEF = PKR(s[14], s[15]);
        #undef PKR
        unsigned e1a = lh ? p01 : p45,  e2a = lh ? p23 : p67;
        unsigned e1b = lh ? p89 : pCD,  e2b = lh ? pAB : pEF;
        unsigned f1a = (unsigned)__shfl_xor((int)e1a, 32, 64);
        unsigned f2a = (unsigned)__shfl_xor((int)e2a, 32, 64);
        unsigned f1b = (unsigned)__shfl_xor((int)e1b, 32, 64);
        unsigned f2b = (unsigned)__shfl_xor((int)e2b, 32, 64);
        union U4 { unsigned u[4]; bf16x8 v; };
        U4 a0, a1;
        a0.u[0] = lh ? f1a : p01;  a0.u[1] = lh ? f2a : p23;
        a0.u[2] = lh ? p45 : f1a;  a0.u[3] = lh ? p67 : f2a;
        a1.u[0] = lh ? f1b : p89;  a1.u[1] = lh ? f2b : pAB;
        a1.u[2] = lh ? pCD : f1b;  a1.u[3] = lh ? pEF : f2b;
        bf16x8 pf0 = a0.v, pf1 = a1.v;
        // ---- PV: O^T[d][q] += V'^T . P^T ; A = V rows d (LDS, 16-slot swizzle)
        __builtin_amdgcn_s_setprio(1);
        #define PVD(OA, DB) { \
            const int R_  = (((dh << 2) + (DB)) & 1) * 32 + lr; \
            const int sg_ = ((dh << 2) + (DB)) >> 1; \
            bf16x8 v0_ = *(const bf16x8*)(vb + R_ * 256 + ((((sg_ << 2) + lh)     ^ (lr & 15)) << 4)); \
            bf16x8 v1_ = *(const bf16x8*)(vb + R_ * 256 + ((((sg_ << 2) + 2 + lh) ^ (lr & 15)) << 4)); \
            OA = __builtin_amdgcn_mfma_f32_32x32x16_bf16(v0_, pf0, OA, 0, 0, 0); \
            OA = __builtin_amdgcn_mfma_f32_32x32x16_bf16(v1_, pf1, OA, 0, 0, 0); }
        PVD(oa0, 0) PVD(oa1, 1) PVD(oa2, 2) PVD(oa3, 3)
        #undef PVD
        __builtin_amdgcn_s_setprio(0);
    }
    #undef STAGE
    // ---- epilogue: direct bf16 scatter (once): lane lr = q row, regs = d
    ushort* Xb = X + ((size_t)b * 4096 + q0 + qg * 32 + lr) * 256 + dh * 128;
    #define OUTD(OA, DB) _Pragma("unroll") \
        for (int r = 0; r < 16; r += 2) { \
            const int d_ = (DB) * 32 + (r & 3) + 8 * (r >> 2) + 4 * lh; \
            ushort2 u_; u_.x = f2bf((OA)[r]); u_.y = f2bf((OA)[r + 1]); \
            *(ushort2*)(Xb + d_) = u_; }
    OUTD(oa0, 0) OUTD(oa1, 1) OUTD(oa2, 2) OUTD(oa3, 3)
    #undef OUTD
}

// ------------------------------- conv3x3 + BN + SiLU as 9 shifted MFMA GEMMs
// X [b][p][ci] bf16 -> Y [b][p][co] bf16. Block: 64co x 128p, 4 waves (2co x 2p).
// LDS-staged: 6 tiles (3 dy x 2 ci-half) of 128 rows x 128 ci (halo-free: w-edge
// lanes are masked, so every tap stays within [p0+64dy, p0+64dy+128)).
__global__ __launch_bounds__(256, 2) void k_conv3_mfma(
    const ushort* __restrict__ X, const ushort* __restrict__ w9p,
    const float* __restrict__ bn_g, const float* __restrict__ bn_b,
    const float* __restrict__ bn_m, const float* __restrict__ bn_v,
    ushort* __restrict__ Y)
{
    __shared__ __align__(16) char smem[67584];   // 2x32KB bufs + 2KB bn (tr aliases bufs)
    float* bnv = (float*)(smem + 65536);
    const int t = threadIdx.x, w = t >> 6, l = t & 63, lr = l & 31, lh = l >> 5;
    {
        float inv = bn_g[t] * rsqrtf(bn_v[t] + 1e-3f);
        bnv[t]       = inv;
        bnv[256 + t] = bn_b[t] - bn_m[t] * inv;
    }
    const int bid = blockIdx.x;                  // 4b x 4ct x 32pt
    const int b = bid >> 7, ct = (bid >> 5) & 3, pt = bid & 31;
    const int co0 = ct * 64, p0 = pt * 128;
    const int wc = w >> 1, wp = w & 1;
    const int h0 = pt * 2 + wp;
    const int cb = ct * 2 + wc;
    const char* Xbytes = (const char*)(X + (size_t)b * 4096 * 256);
    const bf16x8 bz = {};
    f32x16 o0{}, o1{};

    #define CSTAGE(bufb, st_) do { \
        const char* src_ = Xbytes + (ptrdiff_t)(p0 + 64 * ((st_) >> 1) - 64) * 512 \
                         + ((st_) & 1) * 256; \
        char* dst_ = smem + (bufb) * 32768; \
        _Pragma("unroll") \
        for (int i_ = 0; i_ < 8; ++i_) { \
            const int di_ = i_ * 256 + t; \
            const int R_ = di_ >> 4, sl_ = di_ & 15; \
            __builtin_amdgcn_global_load_lds( \
                (const __attribute__((address_space(1))) unsigned*)(src_ + (ptrdiff_t)R_ * 512 + ((sl_ ^ (R_ & 15)) << 4)), \
                (__attribute__((address_space(3))) unsigned*)(dst_ + di_ * 16), 16, 0, 0); \
        } } while (0)

    CSTAGE(0, 0);
    __syncthreads();   // bn table ready (also covers first-use ordering)
    for (int st = 0; st < 6; ++st) {
        if (st < 5) CSTAGE((st + 1) & 1, st + 1);
        if (st < 5) asm volatile("s_waitcnt vmcnt(8)" ::: "memory");
        else        asm volatile("s_waitcnt vmcnt(0)" ::: "memory");
        __builtin_amdgcn_s_barrier();
        const char* xb = smem + (st & 1) * 32768;
        const int dyi = st >> 1, cih = st & 1;
        const int hh = h0 + dyi - 1;
        if (hh >= 0 && hh <= 63) {
            __builtin_amdgcn_s_setprio(1);
            #pragma unroll
            for (int dxi = 0; dxi < 3; ++dxi) {
                const int dx = dxi - 1;
                const int s = dyi * 3 + dxi;
                const bool mA = (dxi == 0) && (lr == 0);
                const bool mB = (dxi == 2) && (lr == 31);
                const int R0 = mA ? 0 : (wp * 64 + lr + dx);
                const int R1 = mB ? 0 : (wp * 64 + lr + dx + 32);
                const ushort* wb = w9p + ((size_t)(s * 8 + cb) * 16 + cih * 8) * 512 + l * 8;
                #pragma unroll
                for (int k8 = 0; k8 < 8; ++k8) {
                    bf16x8 af = *(const bf16x8*)(wb + k8 * 512);
                    bf16x8 b0 = *(const bf16x8*)(xb + R0 * 256 + (((k8 * 2 + lh) ^ (R0 & 15)) << 4));
                    bf16x8 b1 = *(const bf16x8*)(xb + R1 * 256 + (((k8 * 2 + lh) ^ (R1 & 15)) << 4));
                    if (mA) b0 = bz;
                    if (mB) b1 = bz;
                    o0 = __builtin_amdgcn_mfma_f32_32x32x16_bf16(af, b0, o0, 0, 0, 0);
                    o1 = __builtin_amdgcn_mfma_f32_32x32x16_bf16(af, b1, o1, 0, 0, 0);
                }
            }
            __builtin_amdgcn_s_setprio(0);
        }
        __builtin_amdgcn_s_barrier();   // protect buf (st&1) before overwrite at st+2
    }
    #undef CSTAGE
    // BN + SiLU -> bf16, transpose to [p][co] through LDS (aliases bufs; all compute done)
    ushort (*tr)[72] = (ushort(*)[72])smem;
    #pragma unroll
    for (int r = 0; r < 16; ++r) {
        const int co_l = wc * 32 + (r & 3) + 8 * (r >> 2) + 4 * lh;
        const int co = co0 + co_l;
        const float inv = bnv[co], add = bnv[256 + co];
        float x0 = o0[r] * inv + add;
        float x1 = o1[r] * inv + add;
        x0 = x0 / (1.f + expf(-x0));
        x1 = x1 / (1.f + expf(-x1));
        tr[wp * 64 + lr][co_l]      = f2bf(x0);
        tr[wp * 64 + 32 + lr][co_l] = f2bf(x1);
    }
    __syncthreads();
    const int pp = t >> 1, half = t & 1;
    uint4 u0 = *(uint4*)&tr[pp][half * 32];
    uint4 u1 = *(uint4*)&tr[pp][half * 32 + 8];
    uint4 u2 = *(uint4*)&tr[pp][half * 32 + 16];
    uint4 u3 = *(uint4*)&tr[pp][half * 32 + 24];
    ushort* yb = Y + ((size_t)b * 4096 + p0 + pp) * 256 + co0 + half * 32;
    *(uint4*)yb        = u0; *(uint4*)(yb + 8)  = u1;
    *(uint4*)(yb + 16) = u2; *(uint4*)(yb + 24) = u3;
}

// ------------------------- conv1x1 + bias + residual: out = q + Y @ W2^T + b2
__global__ __launch_bounds__(256, 2) void k_conv1x1_mfma(
    const ushort* __restrict__ Y, const ushort* __restrict__ W2,
    const float* __restrict__ bias2, const float* __restrict__ query,
    float* __restrict__ out)
{
    const int t = threadIdx.x, w = t >> 6, l = t & 63, lr = l & 31, lh = l >> 5;
    const int bid = blockIdx.x;                  // 4b x 4co x 32p
    const int b = bid >> 7, ct = (bid >> 5) & 3, pt = bid & 31;
    const int co0 = ct * 64, p0 = pt * 128;
    const int wc = w >> 1, wp = w & 1;
    const ushort* Wr = W2 + (size_t)(co0 + wc * 32 + lr) * 256 + lh * 8;
    const ushort* Yp = Y + ((size_t)b * 4096 + p0 + wp * 64 + lr) * 256 + lh * 8;
    f32x16 o0{}, o1{};
    #pragma unroll
    for (int ks = 0; ks < 16; ++ks) {
        bf16x8 wf = *(const bf16x8*)(Wr + ks * 16);
        bf16x8 y0 = *(const bf16x8*)(Yp + ks * 16);
        bf16x8 y1 = *(const bf16x8*)(Yp + 32 * 256 + ks * 16);
        o0 = __builtin_amdgcn_mfma_f32_32x32x16_bf16(wf, y0, o0, 0, 0, 0);
        o1 = __builtin_amdgcn_mfma_f32_32x32x16_bf16(wf, y1, o1, 0, 0, 0);
    }
    #pragma unroll
    for (int r = 0; r < 16; ++r) {
        const int co = co0 + wc * 32 + (r & 3) + 8 * (r >> 2) + 4 * lh;
        const float bb = bias2[co];
        const size_t base = ((size_t)b * 256 + co) * 4096 + p0 + wp * 64 + lr;
        out[base]      = o0[r] + bb + query[base];
        out[base + 32] = o1[r] + bb + query[base + 32];
    }
}

// ---------------------------------------------------------------- launch
extern "C" void kernel_launch(void* const* d_in, const int* in_sizes, int n_in,
                              void* d_out, int out_size, void* d_ws, size_t ws_size,
                              hipStream_t stream) {
    const float* query   = (const float*)d_in[0];
    const float* v_in    = (const float*)d_in[1];
    const float* qpos    = (const float*)d_in[2];
    const float* kpos    = (const float*)d_in[3];
    const float* otherW  = (const float*)d_in[4];
    const float* w_vs    = (const float*)d_in[5];
    const float* mlp_w1  = (const float*)d_in[6];
    const float* mlp_b1  = (const float*)d_in[7];
    const float* mlp_w2  = (const float*)d_in[8];
    const float* mlp_b2  = (const float*)d_in[9];
    const float* conv1_w = (const float*)d_in[10];
    const float* bn_g    = (const float*)d_in[11];
    const float* bn_b    = (const float*)d_in[12];
    const float* bn_m    = (const float*)d_in[13];
    const float* bn_v    = (const float*)d_in[14];
    const float* conv2_w = (const float*)d_in[15];
    const float* conv2_b = (const float*)d_in[16];
    float* out = (float*)d_out;
    char* base = (char*)d_ws;

    constexpr size_t MB = 1u << 20;
    ushort* v_bf    = (ushort*)(base);             // 8MB   (dead after vproj)
    ushort* qpos_bf = (ushort*)(base + 8 * MB);    // 8MB   (dead after mlp1)
    float*  qp_f32  = (float*) (base);             // 16MB  (aliases v_bf+qpos_bf)
    ushort* qhid_bf = (ushort*)(base + 16 * MB);   // 8MB   (dead after mlp2)
    ushort* X_bf    = (ushort*)(base + 16 * MB);   // 8MB   (attn out, aliases qhid)
    ushort* qn_bf   = (ushort*)(base + 24 * MB);   // 8MB   (dead after attn)
    ushort* Y_bf    = (ushort*)(base + 24 * MB);   // 8MB   (conv3 out, aliases qn)
    ushort* kn_bf   = (ushort*)(base + 32 * MB);   // 8MB
    ushort* vT_bf   = (ushort*)(base + 40 * MB);   // 8MB  (w-scaled V'^T, k-tiled)
    ushort* wvs_bf  = (ushort*)(base + 48 * MB);
    ushort* w1e_bf  = (ushort*)(base + 48 * MB + 128 * 1024);
    ushort* w2_bf   = (ushort*)(base + 48 * MB + 256 * 1024);
    ushort* c2_bf   = (ushort*)(base + 48 * MB + 384 * 1024);
    ushort* w9p_bf  = (ushort*)(base + 48 * MB + 512 * 1024);   // 1.125MB packed

    k_prep<<<15040, 256, 0, stream>>>(v_in, otherW, v_bf, qpos, qpos_bf,
                                      kpos, kn_bf, conv1_w, w9p_bf,
                                      w_vs, wvs_bf, mlp_w2, w2_bf,
                                      conv2_w, c2_bf, mlp_w1, w1e_bf);
    k_gemm_mfma<2, 0><<<512, 256, 0, stream>>>(v_bf, wvs_bf, nullptr, vT_bf);
    k_gemm_mfma<1, 1><<<512, 256, 0, stream>>>(qpos_bf, w1e_bf, mlp_b1, qhid_bf);
    k_gemm_mfma<0, 0><<<512, 256, 0, stream>>>(qhid_bf, w2_bf, mlp_b2, qp_f32);
    k_l2norm_bf16<<<4096, 256, 0, stream>>>(qp_f32, qn_bf);
    k_attn_mfma<<<256, 256, 0, stream>>>(qn_bf, kn_bf, vT_bf, X_bf);
    k_conv3_mfma<<<512, 256, 0, stream>>>(X_bf, w9p_bf, bn_g, bn_b, bn_m, bn_v, Y_bf);
    k_conv1x1_mfma<<<512, 256, 0, stream>>>(Y_bf, c2_bf, conv2_b, query, out);
}

// Round 10
// 229.793 us; speedup vs baseline: 2.7565x; 1.2246x over previous
//
#include <hip/hip_runtime.h>
#include <math.h>

// Fixed problem dims
constexpr int kB  = 4;
constexpr int kD  = 256;
constexpr int kNQ = 4096;
constexpr int kNK = 4096;
constexpr int kHW = 4096;   // 64*64

typedef __bf16 bf16x8 __attribute__((ext_vector_type(8)));
typedef float  f32x16 __attribute__((ext_vector_type(16)));

__device__ __forceinline__ unsigned short f2bf(float x) {
    unsigned int u = __builtin_bit_cast(unsigned int, x);
    u = (u + 0x7fffu + ((u >> 16) & 1u)) >> 16;
    return (unsigned short)u;
}

// =============================================== fused prep (1 launch, 15040 blocks)
__global__ __launch_bounds__(256) void k_prep(
    const float* __restrict__ v_in, const float* __restrict__ ow, ushort* __restrict__ v_bf,
    const float* __restrict__ qpos, ushort* __restrict__ qpos_bf,
    const float* __restrict__ kpos, ushort* __restrict__ kn_bf,
    const float* __restrict__ conv1_w, ushort* __restrict__ w9p,
    const float* __restrict__ w_vs, ushort* __restrict__ wvs_bf,
    const float* __restrict__ mlp_w2, ushort* __restrict__ w2_bf,
    const float* __restrict__ conv2_w, ushort* __restrict__ c2_bf,
    const float* __restrict__ mlp_w1, ushort* __restrict__ w1e_bf)
{
    const int bid = blockIdx.x, t = threadIdx.x;
    if (bid < 4096) {
        const int i = bid * 256 + t;
        float4 v = ((const float4*)v_in)[i];
        const float wsc = ow[i >> 6];
        ushort4 o;
        o.x = f2bf(v.x * wsc); o.y = f2bf(v.y * wsc);
        o.z = f2bf(v.z * wsc); o.w = f2bf(v.w * wsc);
        ((ushort4*)v_bf)[i] = o;
    } else if (bid < 8192) {
        const int i = (bid - 4096) * 256 + t;
        float4 v = ((const float4*)qpos)[i];
        ushort4 o;
        o.x = f2bf(v.x); o.y = f2bf(v.y); o.z = f2bf(v.z); o.w = f2bf(v.w);
        ((ushort4*)qpos_bf)[i] = o;
    } else if (bid < 12288) {
        const int row  = (bid - 8192) * 4 + (t >> 6);
        const int lane = t & 63;
        float4 v = ((const float4*)(kpos + (size_t)row * 256))[lane];
        float ss = v.x * v.x + v.y * v.y + v.z * v.z + v.w * v.w;
        #pragma unroll
        for (int off = 32; off; off >>= 1) ss += __shfl_xor(ss, off, 64);
        const float rn = 1.0f / sqrtf(ss);
        ushort4 o;
        o.x = f2bf(v.x * rn); o.y = f2bf(v.y * rn);
        o.z = f2bf(v.z * rn); o.w = f2bf(v.w * rn);
        ((ushort4*)(kn_bf + (size_t)row * 256))[lane] = o;
    } else if (bid < 14592) {
        const int idx = bid - 12288;
        const int s = idx >> 8, co = idx & 255, ci = t;
        const int oidx = ((s * 8 + (co >> 5)) * 16 + (ci >> 4)) * 512
                       + ((ci >> 3) & 1) * 256 + (co & 31) * 8 + (ci & 7);
        w9p[oidx] = f2bf(conv1_w[((size_t)co * 256 + ci) * 9 + s]);
    } else if (bid < 14784) {
        const float* src = (bid < 14656) ? w_vs : (bid < 14720) ? mlp_w2 : conv2_w;
        ushort* dst = (bid < 14656) ? wvs_bf : (bid < 14720) ? w2_bf : c2_bf;
        const int i = ((bid - 14592) & 63) * 256 + t;
        float4 v = ((const float4*)src)[i];
        ushort4 o;
        o.x = f2bf(v.x); o.y = f2bf(v.y); o.z = f2bf(v.z); o.w = f2bf(v.w);
        ((ushort4*)dst)[i] = o;
    } else {
        const int h = bid - 14784;
        w1e_bf[h * 256 + t] = f2bf(mlp_w1[h * 512 + t] + mlp_w1[h * 512 + 256 + t]);
    }
}

// ----------------------------------------------- generic MFMA GEMM  C = A @ W^T
// A [M,256] bf16, W [256,256] bf16 ([n][k]). Block: 128m x 64n, 4 waves (2x2).
// EPI: 0 = f32 [m][256]; 1 = bf16 [m][256];
// EPI 2 = bf16 K-TILED transpose: [b][kt=m/32][n(256)][m%32] (16KB contiguous tiles)
template<int EPI, int RELU>
__global__ __launch_bounds__(256, 2) void k_gemm_mfma(
    const ushort* __restrict__ A, const ushort* __restrict__ W,
    const float* __restrict__ bias, void* __restrict__ outp)
{
    const int t = threadIdx.x, w = t >> 6, l = t & 63, lr = l & 31, lh = l >> 5;
    const int m0 = (blockIdx.x >> 2) * 128;
    const int n0 = (blockIdx.x & 3) * 64;
    const int wm = w >> 1, wn = w & 1;
    const ushort* Ar0 = A + (size_t)(m0 + wm * 64 + lr) * 256 + lh * 8;
    const ushort* Ar1 = Ar0 + 32 * 256;
    const ushort* Wr  = W + (size_t)(n0 + wn * 32 + lr) * 256 + lh * 8;
    f32x16 c0{}, c1{};
    #pragma unroll
    for (int ks = 0; ks < 16; ++ks) {
        bf16x8 a0 = *(const bf16x8*)(Ar0 + ks * 16);
        bf16x8 a1 = *(const bf16x8*)(Ar1 + ks * 16);
        bf16x8 wf = *(const bf16x8*)(Wr + ks * 16);
        c0 = __builtin_amdgcn_mfma_f32_32x32x16_bf16(a0, wf, c0, 0, 0, 0);
        c1 = __builtin_amdgcn_mfma_f32_32x32x16_bf16(a1, wf, c1, 0, 0, 0);
    }
    const int n = n0 + wn * 32 + lr;            // C col for both accs
    float bb = bias ? bias[n] : 0.f;
    if constexpr (EPI == 2) {
        __shared__ ushort tr[64][136];          // [n_local][m_local]
        #pragma unroll
        for (int r = 0; r < 16; ++r) {
            const int ml = wm * 64 + (r & 3) + 8 * (r >> 2) + 4 * lh;
            float v0 = c0[r], v1 = c1[r];
            if (RELU) { v0 = fmaxf(v0, 0.f); v1 = fmaxf(v1, 0.f); }
            tr[wn * 32 + lr][ml]      = f2bf(v0);
            tr[wn * 32 + lr][ml + 32] = f2bf(v1);
        }
        __syncthreads();
        ushort* out = (ushort*)outp;
        const int b = m0 >> 12, mm = m0 & 4095;
        const int row = t >> 2, seg = t & 3;    // 64 rows x 4 segs of 32 cols
        uint4 u0 = *(uint4*)&tr[row][seg * 32];
        uint4 u1 = *(uint4*)&tr[row][seg * 32 + 8];
        uint4 u2 = *(uint4*)&tr[row][seg * 32 + 16];
        uint4 u3 = *(uint4*)&tr[row][seg * 32 + 24];
        // tiled layout: tile kt = mm/32 + seg, row d = n0+row, 32 contiguous k
        ushort* ob = out + ((size_t)(b * 128 + (mm >> 5) + seg) * 256 + n0 + row) * 32;
        *(uint4*)ob        = u0; *(uint4*)(ob + 8)  = u1;
        *(uint4*)(ob + 16) = u2; *(uint4*)(ob + 24) = u3;
    } else {
        #pragma unroll
        for (int r = 0; r < 16; ++r) {
            const int m = m0 + wm * 64 + (r & 3) + 8 * (r >> 2) + 4 * lh;
            float v0 = c0[r] + bb, v1 = c1[r] + bb;
            if (RELU) { v0 = fmaxf(v0, 0.f); v1 = fmaxf(v1, 0.f); }
            if constexpr (EPI == 0) {
                float* out = (float*)outp;
                out[(size_t)m * 256 + n]      = v0;
                out[(size_t)(m + 32) * 256 + n] = v1;
            } else {
                ushort* out = (ushort*)outp;
                out[(size_t)m * 256 + n]      = f2bf(v0);
                out[(size_t)(m + 32) * 256 + n] = f2bf(v1);
            }
        }
    }
}

// ---------------------------------------------------------------- L2 norm -> bf16
__global__ __launch_bounds__(256) void k_l2norm_bf16(const float* __restrict__ in,
                                                     ushort* __restrict__ out) {
    const int row  = blockIdx.x * 4 + (threadIdx.x >> 6);
    const int lane = threadIdx.x & 63;
    float4 v = ((const float4*)(in + (size_t)row * 256))[lane];
    float ss = v.x * v.x + v.y * v.y + v.z * v.z + v.w * v.w;
    #pragma unroll
    for (int off = 32; off; off >>= 1) ss += __shfl_xor(ss, off, 64);
    const float rn = 1.0f / sqrtf(ss);
    ushort4 o;
    o.x = f2bf(v.x * rn); o.y = f2bf(v.y * rn);
    o.z = f2bf(v.z * rn); o.w = f2bf(v.w * rn);
    ((ushort4*)(out + (size_t)row * 256))[lane] = o;
}

// ---------------------------------------------------------------- MFMA attention
// X[b][q][d] (bf16) = sum_k relu(qn.kn) * vT'[d][k]  (w folded in V')
// Round-8 sync structure (2-buf, stage->compute->syncthreads) at 8 waves/block
// (2 waves/SIMD for TLP). Tile = 64k (K 32KB + V 32KB). Waves (qg,dh,kh): kh
// splits the tile's k-halves; partial O merged once at the end via f32 LDS.
// grid 256 = b(4) x qtile(64 rows); block 512.
__global__ __launch_bounds__(512, 2) void k_attn_mfma(
    const ushort* __restrict__ qn, const ushort* __restrict__ kn,
    const ushort* __restrict__ vpT, ushort* __restrict__ X)
{
    __shared__ __align__(16) char lds[131072];   // 2 bufs x (K 32K + V 32K)
    const int t = threadIdx.x, w = t >> 6, l = t & 63, lr = l & 31, lh = l >> 5;
    const int kh = w & 1, dhw = (w >> 1) & 1, qg = w >> 2;
    const int bid0 = blockIdx.x;
    const int L = (bid0 & 7) * 32 + (bid0 >> 3);    // XCD clustering (256 = 8*32)
    const int b = L >> 6, qt = L & 63;
    const int q0 = qt << 6;

    // per-lane staging source offsets (constant across k-chunks)
    int koff[4], voff[4];
    #pragma unroll
    for (int i = 0; i < 4; ++i) {
        const int p = i * 512 + t;
        {   // K: 64 rows x 512B, slot xor (row&31)
            const int R = p >> 5, sl = p & 31;
            koff[i] = R * 512 + ((sl ^ (R & 31)) << 4);
        }
        {   // V: two 16KB sub-tiles, each 64 rows x 256B, slot xor (R&15)
            const int sub = p >> 10, q = p & 1023;
            const int R = q >> 4, ch = (q & 15) ^ (R & 15);
            voff[i] = sub * 16384 + ((ch >> 2) * 64 + R) * 64 + ((ch & 3) << 4);
        }
    }
    const char* kgb = (const char*)(kn + (size_t)b * 4096 * 256);
    const char* vgb = (const char*)vpT + (size_t)b * 128 * 16384;

    #define STAGE64(bb, tc) do { \
        const char* ks_ = kgb + (size_t)(tc) * 32768; \
        const char* vs_ = vgb + (size_t)(tc) * 32768; \
        char* kd_ = lds + (bb) * 65536; \
        char* vd_ = kd_ + 32768; \
        _Pragma("unroll") \
        for (int i_ = 0; i_ < 4; ++i_) { \
            __builtin_amdgcn_global_load_lds( \
                (const __attribute__((address_space(1))) unsigned*)(ks_ + koff[i_]), \
                (__attribute__((address_space(3))) unsigned*)(kd_ + (i_ * 512 + w * 64) * 16), 16, 0, 0); \
            __builtin_amdgcn_global_load_lds( \
                (const __attribute__((address_space(1))) unsigned*)(vs_ + voff[i_]), \
                (__attribute__((address_space(3))) unsigned*)(vd_ + (i_ * 512 + w * 64) * 16), 16, 0, 0); \
        } } while (0)

    // Q fragments (wave's 32 q rows; one-time gather, amortized)
    const ushort* qrow = qn + ((size_t)b * 4096 + q0 + qg * 32 + lr) * 256 + lh * 8;
    bf16x8 qf[16];
    #pragma unroll
    for (int ks = 0; ks < 16; ++ks) qf[ks] = *(const bf16x8*)(qrow + ks * 16);

    f32x16 oa0{}, oa1{}, oa2{}, oa3{};

    STAGE64(0, 0);
    __syncthreads();
    for (int tt = 0; tt < 64; ++tt) {
        if (tt + 1 < 64) STAGE64((tt + 1) & 1, tt + 1);
        const char* kb = lds + (tt & 1) * 65536 + kh * 16384;           // wave's K 32k-half
        const char* vb = lds + (tt & 1) * 65536 + 32768 + kh * 16384;   // wave's V sub-tile
        // ---- QK^T: S^T[32k][32q], A = K rows (LDS, 32-slot swizzle), B = Q regs
        f32x16 s0{}, s1{};
        #pragma unroll
        for (int ks = 0; ks < 16; ks += 2) {
            bf16x8 ka = *(const bf16x8*)(kb + lr * 512 + (((2 * ks     + lh) ^ lr) << 4));
            bf16x8 kc = *(const bf16x8*)(kb + lr * 512 + (((2 * ks + 2 + lh) ^ lr) << 4));
            s0 = __builtin_amdgcn_mfma_f32_32x32x16_bf16(ka, qf[ks],     s0, 0, 0, 0);
            s1 = __builtin_amdgcn_mfma_f32_32x32x16_bf16(kc, qf[ks + 1], s1, 0, 0, 0);
        }
        f32x16 s = s0 + s1;
        // ---- in-register P^T B-frags (round-7-verified pack)
        #define PKR(A, B) ((unsigned)f2bf(fmaxf((A), 0.f)) | ((unsigned)f2bf(fmaxf((B), 0.f)) << 16))
        unsigned p01 = PKR(s[0],  s[1]),  p23 = PKR(s[2],  s[3]);
        unsigned p45 = PKR(s[4],  s[5]),  p67 = PKR(s[6],  s[7]);
        unsigned p89 = PKR(s[8],  s[9]),  pAB = PKR(s[10], s[11]);
        unsigned pCD = PKR(s[12], s[13]), pEF = PKR(s[14], s[15]);
        #undef PKR
        unsigned e1a = lh ? p01 : p45,  e2a = lh ? p23 : p67;
        unsigned e1b = lh ? p89 : pCD,  e2b = lh ? pAB : pEF;
        unsigned f1a = (unsigned)__shfl_xor((int)e1a, 32, 64);
        unsigned f2a = (unsigned)__shfl_xor((int)e2a, 32, 64);
        unsigned f1b = (unsigned)__shfl_xor((int)e1b, 32, 64);
        unsigned f2b = (unsigned)__shfl_xor((int)e2b, 32, 64);
        union U4 { unsigned u[4]; bf16x8 v; };
        U4 a0, a1;
        a0.u[0] = lh ? f1a : p01;  a0.u[1] = lh ? f2a : p23;
        a0.u[2] = lh ? p45 : f1a;  a0.u[3] = lh ? p67 : f2a;
        a1.u[0] = lh ? f1b : p89;  a1.u[1] = lh ? f2b : pAB;
        a1.u[2] = lh ? pCD : f1b;  a1.u[3] = lh ? pEF : f2b;
        bf16x8 pf0 = a0.v, pf1 = a1.v;
        // ---- PV: O^T[d][q] += V'^T . P^T ; A = V rows d (LDS, 16-slot swizzle)
        #define PVD(OA, DB) { \
            const int R_  = (((DB) & 1)) * 32 + lr; \
            const int sg_ = dhw * 2 + ((DB) >> 1); \
            bf16x8 v0_ = *(const bf16x8*)(vb + R_ * 256 + ((((sg_ << 2) + lh)     ^ (lr & 15)) << 4)); \
            bf16x8 v1_ = *(const bf16x8*)(vb + R_ * 256 + ((((sg_ << 2) + 2 + lh) ^ (lr & 15)) << 4)); \
            OA = __builtin_amdgcn_mfma_f32_32x32x16_bf16(v0_, pf0, OA, 0, 0, 0); \
            OA = __builtin_amdgcn_mfma_f32_32x32x16_bf16(v1_, pf1, OA, 0, 0, 0); }
        PVD(oa0, 0) PVD(oa1, 1) PVD(oa2, 2) PVD(oa3, 3)
        #undef PVD
        __syncthreads();   // stage(tt+1) landed + all waves done with buf (tt&1)
    }
    #undef STAGE64
    // ---- kh-split merge: kh=1 writes f32 partials to LDS (aliases staging bufs),
    //      kh=0 adds + converts + stores. Pad 132 to spread banks.
    float* red = (float*)lds;
    const int rowbase = ((qg * 2 + dhw) * 32 + lr) * 132;
    if (kh == 1) {
        #define REDW(OA, DB) _Pragma("unroll") \
            for (int r = 0; r < 16; r += 2) { \
                const int d_ = (DB) * 32 + (r & 3) + 8 * (r >> 2) + 4 * lh; \
                *(float2*)&red[rowbase + d_] = make_float2((OA)[r], (OA)[r + 1]); }
        REDW(oa0, 0) REDW(oa1, 1) REDW(oa2, 2) REDW(oa3, 3)
        #undef REDW
    }
    __syncthreads();
    if (kh == 0) {
        ushort* Xb = X + ((size_t)b * 4096 + q0 + qg * 32 + lr) * 256 + dhw * 128;
        #define OUTD(OA, DB) _Pragma("unroll") \
            for (int r = 0; r < 16; r += 2) { \
                const int d_ = (DB) * 32 + (r & 3) + 8 * (r >> 2) + 4 * lh; \
                float2 p = *(float2*)&red[rowbase + d_]; \
                ushort2 u_; u_.x = f2bf((OA)[r] + p.x); u_.y = f2bf((OA)[r + 1] + p.y); \
                *(ushort2*)(Xb + d_) = u_; }
        OUTD(oa0, 0) OUTD(oa1, 1) OUTD(oa2, 2) OUTD(oa3, 3)
        #undef OUTD
    }
}

// ------------------------------- conv3x3 + BN + SiLU as 9 shifted MFMA GEMMs
// X [b][p][ci] bf16 -> Y [b][p][co] bf16. Block: 64co x 128p, 4 waves (2co x 2p).
__global__ __launch_bounds__(256, 2) void k_conv3_mfma(
    const ushort* __restrict__ X, const ushort* __restrict__ w9p,
    const float* __restrict__ bn_g, const float* __restrict__ bn_b,
    const float* __restrict__ bn_m, const float* __restrict__ bn_v,
    ushort* __restrict__ Y)
{
    __shared__ __align__(16) char smem[67584];   // 2x32KB bufs + 2KB bn (tr aliases bufs)
    float* bnv = (float*)(smem + 65536);
    const int t = threadIdx.x, w = t >> 6, l = t & 63, lr = l & 31, lh = l >> 5;
    {
        float inv = bn_g[t] * rsqrtf(bn_v[t] + 1e-3f);
        bnv[t]       = inv;
        bnv[256 + t] = bn_b[t] - bn_m[t] * inv;
    }
    const int bid = blockIdx.x;                  // 4b x 4ct x 32pt
    const int b = bid >> 7, ct = (bid >> 5) & 3, pt = bid & 31;
    const int co0 = ct * 64, p0 = pt * 128;
    const int wc = w >> 1, wp = w & 1;
    const int h0 = pt * 2 + wp;
    const int cb = ct * 2 + wc;
    const char* Xbytes = (const char*)(X + (size_t)b * 4096 * 256);
    const bf16x8 bz = {};
    f32x16 o0{}, o1{};

    #define CSTAGE(bufb, st_) do { \
        const char* src_ = Xbytes + (ptrdiff_t)(p0 + 64 * ((st_) >> 1) - 64) * 512 \
                         + ((st_) & 1) * 256; \
        char* dst_ = smem + (bufb) * 32768; \
        _Pragma("unroll") \
        for (int i_ = 0; i_ < 8; ++i_) { \
            const int di_ = i_ * 256 + t; \
            const int R_ = di_ >> 4, sl_ = di_ & 15; \
            __builtin_amdgcn_global_load_lds( \
                (const __attribute__((address_space(1))) unsigned*)(src_ + (ptrdiff_t)R_ * 512 + ((sl_ ^ (R_ & 15)) << 4)), \
                (__attribute__((address_space(3))) unsigned*)(dst_ + di_ * 16), 16, 0, 0); \
        } } while (0)

    CSTAGE(0, 0);
    __syncthreads();   // bn table ready (also covers first-use ordering)
    for (int st = 0; st < 6; ++st) {
        if (st < 5) CSTAGE((st + 1) & 1, st + 1);
        if (st < 5) asm volatile("s_waitcnt vmcnt(8)" ::: "memory");
        else        asm volatile("s_waitcnt vmcnt(0)" ::: "memory");
        __builtin_amdgcn_s_barrier();
        const char* xb = smem + (st & 1) * 32768;
        const int dyi = st >> 1, cih = st & 1;
        const int hh = h0 + dyi - 1;
        if (hh >= 0 && hh <= 63) {
            __builtin_amdgcn_s_setprio(1);
            #pragma unroll
            for (int dxi = 0; dxi < 3; ++dxi) {
                const int dx = dxi - 1;
                const int s = dyi * 3 + dxi;
                const bool mA = (dxi == 0) && (lr == 0);
                const bool mB = (dxi == 2) && (lr == 31);
                const int R0 = mA ? 0 : (wp * 64 + lr + dx);
                const int R1 = mB ? 0 : (wp * 64 + lr + dx + 32);
                const ushort* wb = w9p + ((size_t)(s * 8 + cb) * 16 + cih * 8) * 512 + l * 8;
                #pragma unroll
                for (int k8 = 0; k8 < 8; ++k8) {
                    bf16x8 af = *(const bf16x8*)(wb + k8 * 512);
                    bf16x8 b0 = *(const bf16x8*)(xb + R0 * 256 + (((k8 * 2 + lh) ^ (R0 & 15)) << 4));
                    bf16x8 b1 = *(const bf16x8*)(xb + R1 * 256 + (((k8 * 2 + lh) ^ (R1 & 15)) << 4));
                    if (mA) b0 = bz;
                    if (mB) b1 = bz;
                    o0 = __builtin_amdgcn_mfma_f32_32x32x16_bf16(af, b0, o0, 0, 0, 0);
                    o1 = __builtin_amdgcn_mfma_f32_32x32x16_bf16(af, b1, o1, 0, 0, 0);
                }
            }
            __builtin_amdgcn_s_setprio(0);
        }
        __builtin_amdgcn_s_barrier();   // protect buf (st&1) before overwrite at st+2
    }
    #undef CSTAGE
    // BN + SiLU -> bf16, transpose to [p][co] through LDS (aliases bufs; all compute done)
    ushort (*tr)[72] = (ushort(*)[72])smem;
    #pragma unroll
    for (int r = 0; r < 16; ++r) {
        const int co_l = wc * 32 + (r & 3) + 8 * (r >> 2) + 4 * lh;
        const int co = co0 + co_l;
        const float inv = bnv[co], add = bnv[256 + co];
        float x0 = o0[r] * inv + add;
        float x1 = o1[r] * inv + add;
        x0 = x0 / (1.f + expf(-x0));
        x1 = x1 / (1.f + expf(-x1));
        tr[wp * 64 + lr][co_l]      = f2bf(x0);
        tr[wp * 64 + 32 + lr][co_l] = f2bf(x1);
    }
    __syncthreads();
    const int pp = t >> 1, half = t & 1;
    uint4 u0 = *(uint4*)&tr[pp][half * 32];
    uint4 u1 = *(uint4*)&tr[pp][half * 32 + 8];
    uint4 u2 = *(uint4*)&tr[pp][half * 32 + 16];
    uint4 u3 = *(uint4*)&tr[pp][half * 32 + 24];
    ushort* yb = Y + ((size_t)b * 4096 + p0 + pp) * 256 + co0 + half * 32;
    *(uint4*)yb        = u0; *(uint4*)(yb + 8)  = u1;
    *(uint4*)(yb + 16) = u2; *(uint4*)(yb + 24) = u3;
}

// ------------------------- conv1x1 + bias + residual: out = q + Y @ W2^T + b2
__global__ __launch_bounds__(256, 2) void k_conv1x1_mfma(
    const ushort* __restrict__ Y, const ushort* __restrict__ W2,
    const float* __restrict__ bias2, const float* __restrict__ query,
    float* __restrict__ out)
{
    const int t = threadIdx.x, w = t >> 6, l = t & 63, lr = l & 31, lh = l >> 5;
    const int bid = blockIdx.x;                  // 4b x 4co x 32p
    const int b = bid >> 7, ct = (bid >> 5) & 3, pt = bid & 31;
    const int co0 = ct * 64, p0 = pt * 128;
    const int wc = w >> 1, wp = w & 1;
    const ushort* Wr = W2 + (size_t)(co0 + wc * 32 + lr) * 256 + lh * 8;
    const ushort* Yp = Y + ((size_t)b * 4096 + p0 + wp * 64 + lr) * 256 + lh * 8;
    f32x16 o0{}, o1{};
    #pragma unroll
    for (int ks = 0; ks < 16; ++ks) {
        bf16x8 wf = *(const bf16x8*)(Wr + ks * 16);
        bf16x8 y0 = *(const bf16x8*)(Yp + ks * 16);
        bf16x8 y1 = *(const bf16x8*)(Yp + 32 * 256 + ks * 16);
        o0 = __builtin_amdgcn_mfma_f32_32x32x16_bf16(wf, y0, o0, 0, 0, 0);
        o1 = __builtin_amdgcn_mfma_f32_32x32x16_bf16(wf, y1, o1, 0, 0, 0);
    }
    #pragma unroll
    for (int r = 0; r < 16; ++r) {
        const int co = co0 + wc * 32 + (r & 3) + 8 * (r >> 2) + 4 * lh;
        const float bb = bias2[co];
        const size_t base = ((size_t)b * 256 + co) * 4096 + p0 + wp * 64 + lr;
        out[base]      = o0[r] + bb + query[base];
        out[base + 32] = o1[r] + bb + query[base + 32];
    }
}

// ---------------------------------------------------------------- launch
extern "C" void kernel_launch(void* const* d_in, const int* in_sizes, int n_in,
                              void* d_out, int out_size, void* d_ws, size_t ws_size,
                              hipStream_t stream) {
    const float* query   = (const float*)d_in[0];
    const float* v_in    = (const float*)d_in[1];
    const float* qpos    = (const float*)d_in[2];
    const float* kpos    = (const float*)d_in[3];
    const float* otherW  = (const float*)d_in[4];
    const float* w_vs    = (const float*)d_in[5];
    const float* mlp_w1  = (const float*)d_in[6];
    const float* mlp_b1  = (const float*)d_in[7];
    const float* mlp_w2  = (const float*)d_in[8];
    const float* mlp_b2  = (const float*)d_in[9];
    const float* conv1_w = (const float*)d_in[10];
    const float* bn_g    = (const float*)d_in[11];
    const float* bn_b    = (const float*)d_in[12];
    const float* bn_m    = (const float*)d_in[13];
    const float* bn_v    = (const float*)d_in[14];
    const float* conv2_w = (const float*)d_in[15];
    const float* conv2_b = (const float*)d_in[16];
    float* out = (float*)d_out;
    char* base = (char*)d_ws;

    constexpr size_t MB = 1u << 20;
    ushort* v_bf    = (ushort*)(base);             // 8MB   (dead after vproj)
    ushort* qpos_bf = (ushort*)(base + 8 * MB);    // 8MB   (dead after mlp1)
    float*  qp_f32  = (float*) (base);             // 16MB  (aliases v_bf+qpos_bf)
    ushort* qhid_bf = (ushort*)(base + 16 * MB);   // 8MB   (dead after mlp2)
    ushort* X_bf    = (ushort*)(base + 16 * MB);   // 8MB   (attn out, aliases qhid)
    ushort* qn_bf   = (ushort*)(base + 24 * MB);   // 8MB   (dead after attn)
    ushort* Y_bf    = (ushort*)(base + 24 * MB);   // 8MB   (conv3 out, aliases qn)
    ushort* kn_bf   = (ushort*)(base + 32 * MB);   // 8MB
    ushort* vT_bf   = (ushort*)(base + 40 * MB);   // 8MB  (w-scaled V'^T, k-tiled)
    ushort* wvs_bf  = (ushort*)(base + 48 * MB);
    ushort* w1e_bf  = (ushort*)(base + 48 * MB + 128 * 1024);
    ushort* w2_bf   = (ushort*)(base + 48 * MB + 256 * 1024);
    ushort* c2_bf   = (ushort*)(base + 48 * MB + 384 * 1024);
    ushort* w9p_bf  = (ushort*)(base + 48 * MB + 512 * 1024);   // 1.125MB packed

    k_prep<<<15040, 256, 0, stream>>>(v_in, otherW, v_bf, qpos, qpos_bf,
                                      kpos, kn_bf, conv1_w, w9p_bf,
                                      w_vs, wvs_bf, mlp_w2, w2_bf,
                                      conv2_w, c2_bf, mlp_w1, w1e_bf);
    k_gemm_mfma<2, 0><<<512, 256, 0, stream>>>(v_bf, wvs_bf, nullptr, vT_bf);
    k_gemm_mfma<1, 1><<<512, 256, 0, stream>>>(qpos_bf, w1e_bf, mlp_b1, qhid_bf);
    k_gemm_mfma<0, 0><<<512, 256, 0, stream>>>(qhid_bf, w2_bf, mlp_b2, qp_f32);
    k_l2norm_bf16<<<4096, 256, 0, stream>>>(qp_f32, qn_bf);
    k_attn_mfma<<<256, 512, 0, stream>>>(qn_bf, kn_bf, vT_bf, X_bf);
    k_conv3_mfma<<<512, 256, 0, stream>>>(X_bf, w9p_bf, bn_g, bn_b, bn_m, bn_v, Y_bf);
    k_conv1x1_mfma<<<512, 256, 0, stream>>>(Y_bf, c2_bf, conv2_b, query, out);
}

// Round 11
// 209.368 us; speedup vs baseline: 3.0254x; 1.0976x over previous
//
#include <hip/hip_runtime.h>
#include <math.h>

// Fixed problem dims
constexpr int kB  = 4;
constexpr int kD  = 256;
constexpr int kNQ = 4096;
constexpr int kNK = 4096;
constexpr int kHW = 4096;   // 64*64

typedef __bf16 bf16x8 __attribute__((ext_vector_type(8)));
typedef float  f32x16 __attribute__((ext_vector_type(16)));

__device__ __forceinline__ unsigned short f2bf(float x) {
    unsigned int u = __builtin_bit_cast(unsigned int, x);
    u = (u + 0x7fffu + ((u >> 16) & 1u)) >> 16;
    return (unsigned short)u;
}

// =============================================== fused prep (1 launch, 15040 blocks)
__global__ __launch_bounds__(256) void k_prep(
    const float* __restrict__ v_in, const float* __restrict__ ow, ushort* __restrict__ v_bf,
    const float* __restrict__ qpos, ushort* __restrict__ qpos_bf,
    const float* __restrict__ kpos, ushort* __restrict__ kn_bf,
    const float* __restrict__ conv1_w, ushort* __restrict__ w9p,
    const float* __restrict__ w_vs, ushort* __restrict__ wvs_bf,
    const float* __restrict__ mlp_w2, ushort* __restrict__ w2_bf,
    const float* __restrict__ conv2_w, ushort* __restrict__ c2_bf,
    const float* __restrict__ mlp_w1, ushort* __restrict__ w1e_bf)
{
    const int bid = blockIdx.x, t = threadIdx.x;
    if (bid < 4096) {
        const int i = bid * 256 + t;
        float4 v = ((const float4*)v_in)[i];
        const float wsc = ow[i >> 6];
        ushort4 o;
        o.x = f2bf(v.x * wsc); o.y = f2bf(v.y * wsc);
        o.z = f2bf(v.z * wsc); o.w = f2bf(v.w * wsc);
        ((ushort4*)v_bf)[i] = o;
    } else if (bid < 8192) {
        const int i = (bid - 4096) * 256 + t;
        float4 v = ((const float4*)qpos)[i];
        ushort4 o;
        o.x = f2bf(v.x); o.y = f2bf(v.y); o.z = f2bf(v.z); o.w = f2bf(v.w);
        ((ushort4*)qpos_bf)[i] = o;
    } else if (bid < 12288) {
        const int row  = (bid - 8192) * 4 + (t >> 6);
        const int lane = t & 63;
        float4 v = ((const float4*)(kpos + (size_t)row * 256))[lane];
        float ss = v.x * v.x + v.y * v.y + v.z * v.z + v.w * v.w;
        #pragma unroll
        for (int off = 32; off; off >>= 1) ss += __shfl_xor(ss, off, 64);
        const float rn = 1.0f / sqrtf(ss);
        ushort4 o;
        o.x = f2bf(v.x * rn); o.y = f2bf(v.y * rn);
        o.z = f2bf(v.z * rn); o.w = f2bf(v.w * rn);
        ((ushort4*)(kn_bf + (size_t)row * 256))[lane] = o;
    } else if (bid < 14592) {
        const int idx = bid - 12288;
        const int s = idx >> 8, co = idx & 255, ci = t;
        const int oidx = ((s * 8 + (co >> 5)) * 16 + (ci >> 4)) * 512
                       + ((ci >> 3) & 1) * 256 + (co & 31) * 8 + (ci & 7);
        w9p[oidx] = f2bf(conv1_w[((size_t)co * 256 + ci) * 9 + s]);
    } else if (bid < 14784) {
        const float* src = (bid < 14656) ? w_vs : (bid < 14720) ? mlp_w2 : conv2_w;
        ushort* dst = (bid < 14656) ? wvs_bf : (bid < 14720) ? w2_bf : c2_bf;
        const int i = ((bid - 14592) & 63) * 256 + t;
        float4 v = ((const float4*)src)[i];
        ushort4 o;
        o.x = f2bf(v.x); o.y = f2bf(v.y); o.z = f2bf(v.z); o.w = f2bf(v.w);
        ((ushort4*)dst)[i] = o;
    } else {
        const int h = bid - 14784;
        w1e_bf[h * 256 + t] = f2bf(mlp_w1[h * 512 + t] + mlp_w1[h * 512 + 256 + t]);
    }
}

// ----------------------------------------------- generic MFMA GEMM  C = A @ W^T
// A [M,256] bf16, W [256,256] bf16 ([n][k]). Block: 128m x 64n, 4 waves (2x2).
// EPI: 0 = f32 [m][256]; 1 = bf16 [m][256];
// EPI 2 = bf16 K-TILED transpose: [b][kt=m/32][n(256)][m%32] (16KB contiguous tiles)
template<int EPI, int RELU>
__global__ __launch_bounds__(256, 2) void k_gemm_mfma(
    const ushort* __restrict__ A, const ushort* __restrict__ W,
    const float* __restrict__ bias, void* __restrict__ outp)
{
    const int t = threadIdx.x, w = t >> 6, l = t & 63, lr = l & 31, lh = l >> 5;
    const int m0 = (blockIdx.x >> 2) * 128;
    const int n0 = (blockIdx.x & 3) * 64;
    const int wm = w >> 1, wn = w & 1;
    const ushort* Ar0 = A + (size_t)(m0 + wm * 64 + lr) * 256 + lh * 8;
    const ushort* Ar1 = Ar0 + 32 * 256;
    const ushort* Wr  = W + (size_t)(n0 + wn * 32 + lr) * 256 + lh * 8;
    f32x16 c0{}, c1{};
    #pragma unroll
    for (int ks = 0; ks < 16; ++ks) {
        bf16x8 a0 = *(const bf16x8*)(Ar0 + ks * 16);
        bf16x8 a1 = *(const bf16x8*)(Ar1 + ks * 16);
        bf16x8 wf = *(const bf16x8*)(Wr + ks * 16);
        c0 = __builtin_amdgcn_mfma_f32_32x32x16_bf16(a0, wf, c0, 0, 0, 0);
        c1 = __builtin_amdgcn_mfma_f32_32x32x16_bf16(a1, wf, c1, 0, 0, 0);
    }
    const int n = n0 + wn * 32 + lr;            // C col for both accs
    float bb = bias ? bias[n] : 0.f;
    if constexpr (EPI == 2) {
        __shared__ ushort tr[64][136];          // [n_local][m_local]
        #pragma unroll
        for (int r = 0; r < 16; ++r) {
            const int ml = wm * 64 + (r & 3) + 8 * (r >> 2) + 4 * lh;
            float v0 = c0[r], v1 = c1[r];
            if (RELU) { v0 = fmaxf(v0, 0.f); v1 = fmaxf(v1, 0.f); }
            tr[wn * 32 + lr][ml]      = f2bf(v0);
            tr[wn * 32 + lr][ml + 32] = f2bf(v1);
        }
        __syncthreads();
        ushort* out = (ushort*)outp;
        const int b = m0 >> 12, mm = m0 & 4095;
        const int row = t >> 2, seg = t & 3;    // 64 rows x 4 segs of 32 cols
        uint4 u0 = *(uint4*)&tr[row][seg * 32];
        uint4 u1 = *(uint4*)&tr[row][seg * 32 + 8];
        uint4 u2 = *(uint4*)&tr[row][seg * 32 + 16];
        uint4 u3 = *(uint4*)&tr[row][seg * 32 + 24];
        // tiled layout: tile kt = mm/32 + seg, row d = n0+row, 32 contiguous k
        ushort* ob = out + ((size_t)(b * 128 + (mm >> 5) + seg) * 256 + n0 + row) * 32;
        *(uint4*)ob        = u0; *(uint4*)(ob + 8)  = u1;
        *(uint4*)(ob + 16) = u2; *(uint4*)(ob + 24) = u3;
    } else {
        #pragma unroll
        for (int r = 0; r < 16; ++r) {
            const int m = m0 + wm * 64 + (r & 3) + 8 * (r >> 2) + 4 * lh;
            float v0 = c0[r] + bb, v1 = c1[r] + bb;
            if (RELU) { v0 = fmaxf(v0, 0.f); v1 = fmaxf(v1, 0.f); }
            if constexpr (EPI == 0) {
                float* out = (float*)outp;
                out[(size_t)m * 256 + n]      = v0;
                out[(size_t)(m + 32) * 256 + n] = v1;
            } else {
                ushort* out = (ushort*)outp;
                out[(size_t)m * 256 + n]      = f2bf(v0);
                out[(size_t)(m + 32) * 256 + n] = f2bf(v1);
            }
        }
    }
}

// ---------------------------------------------------------------- L2 norm -> bf16
__global__ __launch_bounds__(256) void k_l2norm_bf16(const float* __restrict__ in,
                                                     ushort* __restrict__ out) {
    const int row  = blockIdx.x * 4 + (threadIdx.x >> 6);
    const int lane = threadIdx.x & 63;
    float4 v = ((const float4*)(in + (size_t)row * 256))[lane];
    float ss = v.x * v.x + v.y * v.y + v.z * v.z + v.w * v.w;
    #pragma unroll
    for (int off = 32; off; off >>= 1) ss += __shfl_xor(ss, off, 64);
    const float rn = 1.0f / sqrtf(ss);
    ushort4 o;
    o.x = f2bf(v.x * rn); o.y = f2bf(v.y * rn);
    o.z = f2bf(v.z * rn); o.w = f2bf(v.w * rn);
    ((ushort4*)(out + (size_t)row * 256))[lane] = o;
}

// ---------------------------------------------------------------- MFMA attention
// X[b][q][d] (bf16) = sum_k relu(qn.kn) * vT'[d][k]  (w folded in V')
// Cross-tile pipelined QK dedup: dh=0 waves (one per SIMD) compute QK(t) + pack
// P(t) -> regs + LDS; ALL waves compute PV(t-1) (dh=1 reads P(t-1) from LDS).
// One barrier per tile. Buffers: Kbuf x2 (stage K(t+1)), Vbuf x2 (stage V(t),
// consumed at t+1), Pbuf x2. grid 256 = b(4) x qtile(64); block 512 (8 waves).
__global__ __launch_bounds__(512, 2) void k_attn_mfma(
    const ushort* __restrict__ qn, const ushort* __restrict__ kn,
    const ushort* __restrict__ vpT, ushort* __restrict__ X)
{
    __shared__ __align__(16) char lds[147456];   // K 2x32K | V 2x32K | P 2x8K
    const int t = threadIdx.x, w = t >> 6, l = t & 63, lr = l & 31, lh = l >> 5;
    const int dh = w >> 2, qg = (w >> 1) & 1, kh = w & 1;   // dh pairs 1 producer+1 consumer per SIMD
    const int bid0 = blockIdx.x;
    const int L = (bid0 & 7) * 32 + (bid0 >> 3);    // XCD clustering (256 = 8*32)
    const int b = L >> 6, qt = L & 63;
    const int q0 = qt << 6;
    union U4 { unsigned u[4]; bf16x8 v; };

    // per-lane staging source offsets (constant across k-chunks)
    int koff[4], voff[4];
    #pragma unroll
    for (int i = 0; i < 4; ++i) {
        const int p = i * 512 + t;
        {   // K: 64 rows x 512B, slot xor (row&31)
            const int R = p >> 5, sl = p & 31;
            koff[i] = R * 512 + ((sl ^ (R & 31)) << 4);
        }
        {   // V: two 16KB sub-tiles, each 64 rows x 256B, slot xor (R&15)
            const int sub = p >> 10, q = p & 1023;
            const int R = q >> 4, ch = (q & 15) ^ (R & 15);
            voff[i] = sub * 16384 + ((ch >> 2) * 64 + R) * 64 + ((ch & 3) << 4);
        }
    }
    const char* kgb = (const char*)(kn + (size_t)b * 4096 * 256);
    const char* vgb = (const char*)vpT + (size_t)b * 128 * 16384;

    #define STAGE_K(bb, tc) do { \
        const char* ks_ = kgb + (size_t)(tc) * 32768; \
        char* kd_ = lds + (bb) * 32768; \
        _Pragma("unroll") \
        for (int i_ = 0; i_ < 4; ++i_) \
            __builtin_amdgcn_global_load_lds( \
                (const __attribute__((address_space(1))) unsigned*)(ks_ + koff[i_]), \
                (__attribute__((address_space(3))) unsigned*)(kd_ + (i_ * 512 + w * 64) * 16), 16, 0, 0); \
        } while (0)
    #define STAGE_V(bb, tc) do { \
        const char* vs_ = vgb + (size_t)(tc) * 32768; \
        char* vd_ = lds + 65536 + (bb) * 32768; \
        _Pragma("unroll") \
        for (int i_ = 0; i_ < 4; ++i_) \
            __builtin_amdgcn_global_load_lds( \
                (const __attribute__((address_space(1))) unsigned*)(vs_ + voff[i_]), \
                (__attribute__((address_space(3))) unsigned*)(vd_ + (i_ * 512 + w * 64) * 16), 16, 0, 0); \
        } while (0)

    // Q fragments (wave's 32 q rows; only dh=0 uses them)
    const ushort* qrow = qn + ((size_t)b * 4096 + q0 + qg * 32 + lr) * 256 + lh * 8;
    bf16x8 qf[16];
    #pragma unroll
    for (int ks = 0; ks < 16; ++ks) qf[ks] = *(const bf16x8*)(qrow + ks * 16);

    f32x16 oa0{}, oa1{}, oa2{}, oa3{};
    bf16x8 pf0{}, pf1{};                    // dh=0's P(t-1) carried in regs

    STAGE_K(0, 0);
    __syncthreads();
    for (int tt = 0; tt <= 64; ++tt) {
        if (tt < 64) {
            if (tt + 1 < 64) STAGE_K((tt + 1) & 1, tt + 1);
            STAGE_V(tt & 1, tt);
        }
        // ---- PV(tt-1): all waves; O^T[d][q] += V'^T . P^T
        if (tt > 0) {
            const char* vb = lds + 65536 + ((tt - 1) & 1) * 32768 + kh * 16384;
            bf16x8 qp0, qp1;
            if (dh == 0) { qp0 = pf0; qp1 = pf1; }
            else {
                const unsigned* pr = (const unsigned*)(lds + 131072
                                   + ((tt - 1) & 1) * 8192 + (qg * 2 + kh) * 2048);
                U4 a0, a1;
                #pragma unroll
                for (int wd = 0; wd < 4; ++wd) {
                    a0.u[wd] = pr[wd * 64 + l];
                    a1.u[wd] = pr[(4 + wd) * 64 + l];
                }
                qp0 = a0.v; qp1 = a1.v;
            }
            #define PVD(OA, DB) { \
                const int R_  = (((DB) & 1)) * 32 + lr; \
                const int sg_ = dh * 2 + ((DB) >> 1); \
                bf16x8 v0_ = *(const bf16x8*)(vb + R_ * 256 + ((((sg_ << 2) + lh)     ^ (lr & 15)) << 4)); \
                bf16x8 v1_ = *(const bf16x8*)(vb + R_ * 256 + ((((sg_ << 2) + 2 + lh) ^ (lr & 15)) << 4)); \
                OA = __builtin_amdgcn_mfma_f32_32x32x16_bf16(v0_, qp0, OA, 0, 0, 0); \
                OA = __builtin_amdgcn_mfma_f32_32x32x16_bf16(v1_, qp1, OA, 0, 0, 0); }
            PVD(oa0, 0) PVD(oa1, 1) PVD(oa2, 2) PVD(oa3, 3)
            #undef PVD
        }
        // ---- QK(tt): dh=0 only; S^T[32k][32q], 4 chains; pack -> pf + LDS
        if (dh == 0 && tt < 64) {
            const char* kb = lds + (tt & 1) * 32768 + kh * 16384;
            f32x16 s0{}, s1{}, s2{}, s3{};
            #pragma unroll
            for (int ks = 0; ks < 16; ks += 4) {
                bf16x8 k0 = *(const bf16x8*)(kb + lr * 512 + (((2 * ks     + lh) ^ lr) << 4));
                bf16x8 k1 = *(const bf16x8*)(kb + lr * 512 + (((2 * ks + 2 + lh) ^ lr) << 4));
                bf16x8 k2 = *(const bf16x8*)(kb + lr * 512 + (((2 * ks + 4 + lh) ^ lr) << 4));
                bf16x8 k3 = *(const bf16x8*)(kb + lr * 512 + (((2 * ks + 6 + lh) ^ lr) << 4));
                s0 = __builtin_amdgcn_mfma_f32_32x32x16_bf16(k0, qf[ks],     s0, 0, 0, 0);
                s1 = __builtin_amdgcn_mfma_f32_32x32x16_bf16(k1, qf[ks + 1], s1, 0, 0, 0);
                s2 = __builtin_amdgcn_mfma_f32_32x32x16_bf16(k2, qf[ks + 2], s2, 0, 0, 0);
                s3 = __builtin_amdgcn_mfma_f32_32x32x16_bf16(k3, qf[ks + 3], s3, 0, 0, 0);
            }
            f32x16 s = (s0 + s1) + (s2 + s3);
            #define PKR(A, B) ((unsigned)f2bf(fmaxf((A), 0.f)) | ((unsigned)f2bf(fmaxf((B), 0.f)) << 16))
            unsigned p01 = PKR(s[0],  s[1]),  p23 = PKR(s[2],  s[3]);
            unsigned p45 = PKR(s[4],  s[5]),  p67 = PKR(s[6],  s[7]);
            unsigned p89 = PKR(s[8],  s[9]),  pAB = PKR(s[10], s[11]);
            unsigned pCD = PKR(s[12], s[13]), pEF = PKR(s[14], s[15]);
            #undef PKR
            unsigned e1a = lh ? p01 : p45,  e2a = lh ? p23 : p67;
            unsigned e1b = lh ? p89 : pCD,  e2b = lh ? pAB : pEF;
            unsigned f1a = (unsigned)__shfl_xor((int)e1a, 32, 64);
            unsigned f2a = (unsigned)__shfl_xor((int)e2a, 32, 64);
            unsigned f1b = (unsigned)__shfl_xor((int)e1b, 32, 64);
            unsigned f2b = (unsigned)__shfl_xor((int)e2b, 32, 64);
            U4 a0, a1;
            a0.u[0] = lh ? f1a : p01;  a0.u[1] = lh ? f2a : p23;
            a0.u[2] = lh ? p45 : f1a;  a0.u[3] = lh ? p67 : f2a;
            a1.u[0] = lh ? f1b : p89;  a1.u[1] = lh ? f2b : pAB;
            a1.u[2] = lh ? pCD : f1b;  a1.u[3] = lh ? pEF : f2b;
            pf0 = a0.v; pf1 = a1.v;
            unsigned* pw = (unsigned*)(lds + 131072 + (tt & 1) * 8192 + (qg * 2 + kh) * 2048);
            #pragma unroll
            for (int wd = 0; wd < 4; ++wd) {
                pw[wd * 64 + l]       = a0.u[wd];
                pw[(4 + wd) * 64 + l] = a1.u[wd];
            }
        }
        if (tt < 64) __syncthreads();   // staging landed + bufs/P consumed
    }
    #undef STAGE_K
    #undef STAGE_V
    // ---- kh-split merge: kh=1 writes f32 partials to LDS (aliases K/V bufs),
    //      kh=0 adds + converts + stores. Pad 132 to spread banks.
    float* red = (float*)lds;
    const int rowbase = ((qg * 2 + dh) * 32 + lr) * 132;
    if (kh == 1) {
        #define REDW(OA, DB) _Pragma("unroll") \
            for (int r = 0; r < 16; r += 2) { \
                const int d_ = (DB) * 32 + (r & 3) + 8 * (r >> 2) + 4 * lh; \
                *(float2*)&red[rowbase + d_] = make_float2((OA)[r], (OA)[r + 1]); }
        REDW(oa0, 0) REDW(oa1, 1) REDW(oa2, 2) REDW(oa3, 3)
        #undef REDW
    }
    __syncthreads();
    if (kh == 0) {
        ushort* Xb = X + ((size_t)b * 4096 + q0 + qg * 32 + lr) * 256 + dh * 128;
        #define OUTD(OA, DB) _Pragma("unroll") \
            for (int r = 0; r < 16; r += 2) { \
                const int d_ = (DB) * 32 + (r & 3) + 8 * (r >> 2) + 4 * lh; \
                float2 p = *(float2*)&red[rowbase + d_]; \
                ushort2 u_; u_.x = f2bf((OA)[r] + p.x); u_.y = f2bf((OA)[r + 1] + p.y); \
                *(ushort2*)(Xb + d_) = u_; }
        OUTD(oa0, 0) OUTD(oa1, 1) OUTD(oa2, 2) OUTD(oa3, 3)
        #undef OUTD
    }
}

// ------------------------------- conv3x3 + BN + SiLU as 9 shifted MFMA GEMMs
// X [b][p][ci] bf16 -> Y [b][p][co] bf16. Block: 64co x 128p, 4 waves (2co x 2p).
__global__ __launch_bounds__(256, 2) void k_conv3_mfma(
    const ushort* __restrict__ X, const ushort* __restrict__ w9p,
    const float* __restrict__ bn_g, const float* __restrict__ bn_b,
    const float* __restrict__ bn_m, const float* __restrict__ bn_v,
    ushort* __restrict__ Y)
{
    __shared__ __align__(16) char smem[67584];   // 2x32KB bufs + 2KB bn (tr aliases bufs)
    float* bnv = (float*)(smem + 65536);
    const int t = threadIdx.x, w = t >> 6, l = t & 63, lr = l & 31, lh = l >> 5;
    {
        float inv = bn_g[t] * rsqrtf(bn_v[t] + 1e-3f);
        bnv[t]       = inv;
        bnv[256 + t] = bn_b[t] - bn_m[t] * inv;
    }
    const int bid = blockIdx.x;                  // 4b x 4ct x 32pt
    const int b = bid >> 7, ct = (bid >> 5) & 3, pt = bid & 31;
    const int co0 = ct * 64, p0 = pt * 128;
    const int wc = w >> 1, wp = w & 1;
    const int h0 = pt * 2 + wp;
    const int cb = ct * 2 + wc;
    const char* Xbytes = (const char*)(X + (size_t)b * 4096 * 256);
    const bf16x8 bz = {};
    f32x16 o0{}, o1{};

    #define CSTAGE(bufb, st_) do { \
        const char* src_ = Xbytes + (ptrdiff_t)(p0 + 64 * ((st_) >> 1) - 64) * 512 \
                         + ((st_) & 1) * 256; \
        char* dst_ = smem + (bufb) * 32768; \
        _Pragma("unroll") \
        for (int i_ = 0; i_ < 8; ++i_) { \
            const int di_ = i_ * 256 + t; \
            const int R_ = di_ >> 4, sl_ = di_ & 15; \
            __builtin_amdgcn_global_load_lds( \
                (const __attribute__((address_space(1))) unsigned*)(src_ + (ptrdiff_t)R_ * 512 + ((sl_ ^ (R_ & 15)) << 4)), \
                (__attribute__((address_space(3))) unsigned*)(dst_ + di_ * 16), 16, 0, 0); \
        } } while (0)

    CSTAGE(0, 0);
    __syncthreads();   // bn table ready (also covers first-use ordering)
    for (int st = 0; st < 6; ++st) {
        if (st < 5) CSTAGE((st + 1) & 1, st + 1);
        if (st < 5) asm volatile("s_waitcnt vmcnt(8)" ::: "memory");
        else        asm volatile("s_waitcnt vmcnt(0)" ::: "memory");
        __builtin_amdgcn_s_barrier();
        const char* xb = smem + (st & 1) * 32768;
        const int dyi = st >> 1, cih = st & 1;
        const int hh = h0 + dyi - 1;
        if (hh >= 0 && hh <= 63) {
            __builtin_amdgcn_s_setprio(1);
            #pragma unroll
            for (int dxi = 0; dxi < 3; ++dxi) {
                const int dx = dxi - 1;
                const int s = dyi * 3 + dxi;
                const bool mA = (dxi == 0) && (lr == 0);
                const bool mB = (dxi == 2) && (lr == 31);
                const int R0 = mA ? 0 : (wp * 64 + lr + dx);
                const int R1 = mB ? 0 : (wp * 64 + lr + dx + 32);
                const ushort* wb = w9p + ((size_t)(s * 8 + cb) * 16 + cih * 8) * 512 + l * 8;
                #pragma unroll
                for (int k8 = 0; k8 < 8; ++k8) {
                    bf16x8 af = *(const bf16x8*)(wb + k8 * 512);
                    bf16x8 b0 = *(const bf16x8*)(xb + R0 * 256 + (((k8 * 2 + lh) ^ (R0 & 15)) << 4));
                    bf16x8 b1 = *(const bf16x8*)(xb + R1 * 256 + (((k8 * 2 + lh) ^ (R1 & 15)) << 4));
                    if (mA) b0 = bz;
                    if (mB) b1 = bz;
                    o0 = __builtin_amdgcn_mfma_f32_32x32x16_bf16(af, b0, o0, 0, 0, 0);
                    o1 = __builtin_amdgcn_mfma_f32_32x32x16_bf16(af, b1, o1, 0, 0, 0);
                }
            }
            __builtin_amdgcn_s_setprio(0);
        }
        __builtin_amdgcn_s_barrier();   // protect buf (st&1) before overwrite at st+2
    }
    #undef CSTAGE
    // BN + SiLU -> bf16, transpose to [p][co] through LDS (aliases bufs; all compute done)
    ushort (*tr)[72] = (ushort(*)[72])smem;
    #pragma unroll
    for (int r = 0; r < 16; ++r) {
        const int co_l = wc * 32 + (r & 3) + 8 * (r >> 2) + 4 * lh;
        const int co = co0 + co_l;
        const float inv = bnv[co], add = bnv[256 + co];
        float x0 = o0[r] * inv + add;
        float x1 = o1[r] * inv + add;
        x0 = x0 / (1.f + expf(-x0));
        x1 = x1 / (1.f + expf(-x1));
        tr[wp * 64 + lr][co_l]      = f2bf(x0);
        tr[wp * 64 + 32 + lr][co_l] = f2bf(x1);
    }
    __syncthreads();
    const int pp = t >> 1, half = t & 1;
    uint4 u0 = *(uint4*)&tr[pp][half * 32];
    uint4 u1 = *(uint4*)&tr[pp][half * 32 + 8];
    uint4 u2 = *(uint4*)&tr[pp][half * 32 + 16];
    uint4 u3 = *(uint4*)&tr[pp][half * 32 + 24];
    ushort* yb = Y + ((size_t)b * 4096 + p0 + pp) * 256 + co0 + half * 32;
    *(uint4*)yb        = u0; *(uint4*)(yb + 8)  = u1;
    *(uint4*)(yb + 16) = u2; *(uint4*)(yb + 24) = u3;
}

// ------------------------- conv1x1 + bias + residual: out = q + Y @ W2^T + b2
__global__ __launch_bounds__(256, 2) void k_conv1x1_mfma(
    const ushort* __restrict__ Y, const ushort* __restrict__ W2,
    const float* __restrict__ bias2, const float* __restrict__ query,
    float* __restrict__ out)
{
    const int t = threadIdx.x, w = t >> 6, l = t & 63, lr = l & 31, lh = l >> 5;
    const int bid = blockIdx.x;                  // 4b x 4co x 32p
    const int b = bid >> 7, ct = (bid >> 5) & 3, pt = bid & 31;
    const int co0 = ct * 64, p0 = pt * 128;
    const int wc = w >> 1, wp = w & 1;
    const ushort* Wr = W2 + (size_t)(co0 + wc * 32 + lr) * 256 + lh * 8;
    const ushort* Yp = Y + ((size_t)b * 4096 + p0 + wp * 64 + lr) * 256 + lh * 8;
    f32x16 o0{}, o1{};
    #pragma unroll
    for (int ks = 0; ks < 16; ++ks) {
        bf16x8 wf = *(const bf16x8*)(Wr + ks * 16);
        bf16x8 y0 = *(const bf16x8*)(Yp + ks * 16);
        bf16x8 y1 = *(const bf16x8*)(Yp + 32 * 256 + ks * 16);
        o0 = __builtin_amdgcn_mfma_f32_32x32x16_bf16(wf, y0, o0, 0, 0, 0);
        o1 = __builtin_amdgcn_mfma_f32_32x32x16_bf16(wf, y1, o1, 0, 0, 0);
    }
    #pragma unroll
    for (int r = 0; r < 16; ++r) {
        const int co = co0 + wc * 32 + (r & 3) + 8 * (r >> 2) + 4 * lh;
        const float bb = bias2[co];
        const size_t base = ((size_t)b * 256 + co) * 4096 + p0 + wp * 64 + lr;
        out[base]      = o0[r] + bb + query[base];
        out[base + 32] = o1[r] + bb + query[base + 32];
    }
}

// ---------------------------------------------------------------- launch
extern "C" void kernel_launch(void* const* d_in, const int* in_sizes, int n_in,
                              void* d_out, int out_size, void* d_ws, size_t ws_size,
                              hipStream_t stream) {
    const float* query   = (const float*)d_in[0];
    const float* v_in    = (const float*)d_in[1];
    const float* qpos    = (const float*)d_in[2];
    const float* kpos    = (const float*)d_in[3];
    const float* otherW  = (const float*)d_in[4];
    const float* w_vs    = (const float*)d_in[5];
    const float* mlp_w1  = (const float*)d_in[6];
    const float* mlp_b1  = (const float*)d_in[7];
    const float* mlp_w2  = (const float*)d_in[8];
    const float* mlp_b2  = (const float*)d_in[9];
    const float* conv1_w = (const float*)d_in[10];
    const float* bn_g    = (const float*)d_in[11];
    const float* bn_b    = (const float*)d_in[12];
    const float* bn_m    = (const float*)d_in[13];
    const float* bn_v    = (const float*)d_in[14];
    const float* conv2_w = (const float*)d_in[15];
    const float* conv2_b = (const float*)d_in[16];
    float* out = (float*)d_out;
    char* base = (char*)d_ws;

    constexpr size_t MB = 1u << 20;
    ushort* v_bf    = (ushort*)(base);             // 8MB   (dead after vproj)
    ushort* qpos_bf = (ushort*)(base + 8 * MB);    // 8MB   (dead after mlp1)
    float*  qp_f32  = (float*) (base);             // 16MB  (aliases v_bf+qpos_bf)
    ushort* qhid_bf = (ushort*)(base + 16 * MB);   // 8MB   (dead after mlp2)
    ushort* X_bf    = (ushort*)(base + 16 * MB);   // 8MB   (attn out, aliases qhid)
    ushort* qn_bf   = (ushort*)(base + 24 * MB);   // 8MB   (dead after attn)
    ushort* Y_bf    = (ushort*)(base + 24 * MB);   // 8MB   (conv3 out, aliases qn)
    ushort* kn_bf   = (ushort*)(base + 32 * MB);   // 8MB
    ushort* vT_bf   = (ushort*)(base + 40 * MB);   // 8MB  (w-scaled V'^T, k-tiled)
    ushort* wvs_bf  = (ushort*)(base + 48 * MB);
    ushort* w1e_bf  = (ushort*)(base + 48 * MB + 128 * 1024);
    ushort* w2_bf   = (ushort*)(base + 48 * MB + 256 * 1024);
    ushort* c2_bf   = (ushort*)(base + 48 * MB + 384 * 1024);
    ushort* w9p_bf  = (ushort*)(base + 48 * MB + 512 * 1024);   // 1.125MB packed

    k_prep<<<15040, 256, 0, stream>>>(v_in, otherW, v_bf, qpos, qpos_bf,
                                      kpos, kn_bf, conv1_w, w9p_bf,
                                      w_vs, wvs_bf, mlp_w2, w2_bf,
                                      conv2_w, c2_bf, mlp_w1, w1e_bf);
    k_gemm_mfma<2, 0><<<512, 256, 0, stream>>>(v_bf, wvs_bf, nullptr, vT_bf);
    k_gemm_mfma<1, 1><<<512, 256, 0, stream>>>(qpos_bf, w1e_bf, mlp_b1, qhid_bf);
    k_gemm_mfma<0, 0><<<512, 256, 0, stream>>>(qhid_bf, w2_bf, mlp_b2, qp_f32);
    k_l2norm_bf16<<<4096, 256, 0, stream>>>(qp_f32, qn_bf);
    k_attn_mfma<<<256, 512, 0, stream>>>(qn_bf, kn_bf, vT_bf, X_bf);
    k_conv3_mfma<<<512, 256, 0, stream>>>(X_bf, w9p_bf, bn_g, bn_b, bn_m, bn_v, Y_bf);
    k_conv1x1_mfma<<<512, 256, 0, stream>>>(Y_bf, c2_bf, conv2_b, query, out);
}

// Round 12
// 183.676 us; speedup vs baseline: 3.4486x; 1.1399x over previous
//
#include <hip/hip_runtime.h>
#include <math.h>

// Fixed problem dims
constexpr int kB  = 4;
constexpr int kD  = 256;
constexpr int kNQ = 4096;
constexpr int kNK = 4096;
constexpr int kHW = 4096;   // 64*64

typedef __bf16 bf16x8 __attribute__((ext_vector_type(8)));
typedef float  f32x16 __attribute__((ext_vector_type(16)));

__device__ __forceinline__ unsigned short f2bf(float x) {
    unsigned int u = __builtin_bit_cast(unsigned int, x);
    u = (u + 0x7fffu + ((u >> 16) & 1u)) >> 16;
    return (unsigned short)u;
}

// =============================================== fused prep (1 launch, 15040 blocks)
__global__ __launch_bounds__(256) void k_prep(
    const float* __restrict__ v_in, const float* __restrict__ ow, ushort* __restrict__ v_bf,
    const float* __restrict__ qpos, ushort* __restrict__ qpos_bf,
    const float* __restrict__ kpos, ushort* __restrict__ kn_bf,
    const float* __restrict__ conv1_w, ushort* __restrict__ w9p,
    const float* __restrict__ w_vs, ushort* __restrict__ wvs_bf,
    const float* __restrict__ mlp_w2, ushort* __restrict__ w2_bf,
    const float* __restrict__ conv2_w, ushort* __restrict__ c2_bf,
    const float* __restrict__ mlp_w1, ushort* __restrict__ w1e_bf)
{
    const int bid = blockIdx.x, t = threadIdx.x;
    if (bid < 4096) {
        const int i = bid * 256 + t;
        float4 v = ((const float4*)v_in)[i];
        const float wsc = ow[i >> 6];
        ushort4 o;
        o.x = f2bf(v.x * wsc); o.y = f2bf(v.y * wsc);
        o.z = f2bf(v.z * wsc); o.w = f2bf(v.w * wsc);
        ((ushort4*)v_bf)[i] = o;
    } else if (bid < 8192) {
        const int i = (bid - 4096) * 256 + t;
        float4 v = ((const float4*)qpos)[i];
        ushort4 o;
        o.x = f2bf(v.x); o.y = f2bf(v.y); o.z = f2bf(v.z); o.w = f2bf(v.w);
        ((ushort4*)qpos_bf)[i] = o;
    } else if (bid < 12288) {
        const int row  = (bid - 8192) * 4 + (t >> 6);
        const int lane = t & 63;
        float4 v = ((const float4*)(kpos + (size_t)row * 256))[lane];
        float ss = v.x * v.x + v.y * v.y + v.z * v.z + v.w * v.w;
        #pragma unroll
        for (int off = 32; off; off >>= 1) ss += __shfl_xor(ss, off, 64);
        const float rn = 1.0f / sqrtf(ss);
        ushort4 o;
        o.x = f2bf(v.x * rn); o.y = f2bf(v.y * rn);
        o.z = f2bf(v.z * rn); o.w = f2bf(v.w * rn);
        ((ushort4*)(kn_bf + (size_t)row * 256))[lane] = o;
    } else if (bid < 14592) {
        const int idx = bid - 12288;
        const int s = idx >> 8, co = idx & 255, ci = t;
        const int oidx = ((s * 8 + (co >> 5)) * 16 + (ci >> 4)) * 512
                       + ((ci >> 3) & 1) * 256 + (co & 31) * 8 + (ci & 7);
        w9p[oidx] = f2bf(conv1_w[((size_t)co * 256 + ci) * 9 + s]);
    } else if (bid < 14784) {
        const float* src = (bid < 14656) ? w_vs : (bid < 14720) ? mlp_w2 : conv2_w;
        ushort* dst = (bid < 14656) ? wvs_bf : (bid < 14720) ? w2_bf : c2_bf;
        const int i = ((bid - 14592) & 63) * 256 + t;
        float4 v = ((const float4*)src)[i];
        ushort4 o;
        o.x = f2bf(v.x); o.y = f2bf(v.y); o.z = f2bf(v.z); o.w = f2bf(v.w);
        ((ushort4*)dst)[i] = o;
    } else {
        const int h = bid - 14784;
        w1e_bf[h * 256 + t] = f2bf(mlp_w1[h * 512 + t] + mlp_w1[h * 512 + 256 + t]);
    }
}

// ----------------------------------------------- staged MFMA GEMM  C = A @ W^T
// A [M,256] bf16, W [256,256] bf16 ([n][k]). Block: 128m x 128n, 8 waves (2m x 4n).
// A-tile (64KB) + W-tile (64KB) staged via global_load_lds (pre-swizzled source,
// slot ^= row&31); frags via swizzled ds_read_b128; K=256 fully unrolled.
// EPI: 0 = f32 [m][256]; 1 = bf16 [m][256];
// EPI 2 = bf16 K-TILED transpose: [b][kt=m/32][n(256)][m%32] (16KB contiguous tiles)
template<int EPI, int RELU>
__global__ __launch_bounds__(512, 1) void k_gemm_mfma(
    const ushort* __restrict__ A, const ushort* __restrict__ W,
    const float* __restrict__ bias, void* __restrict__ outp)
{
    __shared__ __align__(16) char lds[131072];   // A 64K | W 64K (tr aliases A)
    const int t = threadIdx.x, w = t >> 6, l = t & 63, lr = l & 31, lh = l >> 5;
    const int wm = w >> 2, wn = w & 3;
    const int m0 = (blockIdx.x >> 1) * 128;
    const int n0 = (blockIdx.x & 1) * 128;
    const char* Ab = (const char*)A + (size_t)m0 * 512;
    const char* Wb = (const char*)W + (size_t)n0 * 512;
    #pragma unroll
    for (int i = 0; i < 8; ++i) {
        const int p = i * 512 + t;
        const int R = p >> 5, sl = p & 31;
        const int so = R * 512 + ((sl ^ (R & 31)) << 4);
        __builtin_amdgcn_global_load_lds(
            (const __attribute__((address_space(1))) unsigned*)(Ab + so),
            (__attribute__((address_space(3))) unsigned*)(lds + p * 16), 16, 0, 0);
        __builtin_amdgcn_global_load_lds(
            (const __attribute__((address_space(1))) unsigned*)(Wb + so),
            (__attribute__((address_space(3))) unsigned*)(lds + 65536 + p * 16), 16, 0, 0);
    }
    __syncthreads();
    const char* Abuf = lds;
    const char* Wbuf = lds + 65536;
    const int ar0 = wm * 64 + lr, ar1 = ar0 + 32;
    const int wrr = wn * 32 + lr;
    f32x16 c0{}, c1{};
    #pragma unroll
    for (int ks = 0; ks < 16; ++ks) {
        const int j = 2 * ks + lh;
        bf16x8 a0 = *(const bf16x8*)(Abuf + ar0 * 512 + ((j ^ lr) << 4));
        bf16x8 a1 = *(const bf16x8*)(Abuf + ar1 * 512 + ((j ^ lr) << 4));
        bf16x8 wf = *(const bf16x8*)(Wbuf + wrr * 512 + ((j ^ lr) << 4));
        c0 = __builtin_amdgcn_mfma_f32_32x32x16_bf16(a0, wf, c0, 0, 0, 0);
        c1 = __builtin_amdgcn_mfma_f32_32x32x16_bf16(a1, wf, c1, 0, 0, 0);
    }
    const int n = n0 + wn * 32 + lr;
    float bb = bias ? bias[n] : 0.f;
    if constexpr (EPI == 2) {
        __syncthreads();                         // all frag reads done before alias
        ushort (*tr)[136] = (ushort(*)[136])lds; // [n_local 128][m_local 128+pad]
        #pragma unroll
        for (int r = 0; r < 16; ++r) {
            const int ml = wm * 64 + (r & 3) + 8 * (r >> 2) + 4 * lh;
            float v0 = c0[r], v1 = c1[r];
            if (RELU) { v0 = fmaxf(v0, 0.f); v1 = fmaxf(v1, 0.f); }
            tr[wn * 32 + lr][ml]      = f2bf(v0);
            tr[wn * 32 + lr][ml + 32] = f2bf(v1);
        }
        __syncthreads();
        ushort* out = (ushort*)outp;
        const int b = m0 >> 12, mm = m0 & 4095;
        const int row = t >> 2, seg = t & 3;     // 128 rows x 4 segs of 32 m
        uint4 u0 = *(uint4*)&tr[row][seg * 32];
        uint4 u1 = *(uint4*)&tr[row][seg * 32 + 8];
        uint4 u2 = *(uint4*)&tr[row][seg * 32 + 16];
        uint4 u3 = *(uint4*)&tr[row][seg * 32 + 24];
        ushort* ob = out + ((size_t)(b * 128 + (mm >> 5) + seg) * 256 + n0 + row) * 32;
        *(uint4*)ob        = u0; *(uint4*)(ob + 8)  = u1;
        *(uint4*)(ob + 16) = u2; *(uint4*)(ob + 24) = u3;
    } else {
        #pragma unroll
        for (int r = 0; r < 16; ++r) {
            const int m = m0 + wm * 64 + (r & 3) + 8 * (r >> 2) + 4 * lh;
            float v0 = c0[r] + bb, v1 = c1[r] + bb;
            if (RELU) { v0 = fmaxf(v0, 0.f); v1 = fmaxf(v1, 0.f); }
            if constexpr (EPI == 0) {
                float* out = (float*)outp;
                out[(size_t)m * 256 + n]      = v0;
                out[(size_t)(m + 32) * 256 + n] = v1;
            } else {
                ushort* out = (ushort*)outp;
                out[(size_t)m * 256 + n]      = f2bf(v0);
                out[(size_t)(m + 32) * 256 + n] = f2bf(v1);
            }
        }
    }
}

// ---------------------------------------------------------------- L2 norm -> bf16
__global__ __launch_bounds__(256) void k_l2norm_bf16(const float* __restrict__ in,
                                                     ushort* __restrict__ out) {
    const int row  = blockIdx.x * 4 + (threadIdx.x >> 6);
    const int lane = threadIdx.x & 63;
    float4 v = ((const float4*)(in + (size_t)row * 256))[lane];
    float ss = v.x * v.x + v.y * v.y + v.z * v.z + v.w * v.w;
    #pragma unroll
    for (int off = 32; off; off >>= 1) ss += __shfl_xor(ss, off, 64);
    const float rn = 1.0f / sqrtf(ss);
    ushort4 o;
    o.x = f2bf(v.x * rn); o.y = f2bf(v.y * rn);
    o.z = f2bf(v.z * rn); o.w = f2bf(v.w * rn);
    ((ushort4*)(out + (size_t)row * 256))[lane] = o;
}

// ---------------------------------------------------------------- MFMA attention
// X[b][q][d] (bf16) = sum_k relu(qn.kn) * vT'[d][k]  (w folded in V')
// Cross-tile pipelined QK dedup (round-11 verified). grid 256; block 512.
__global__ __launch_bounds__(512, 2) void k_attn_mfma(
    const ushort* __restrict__ qn, const ushort* __restrict__ kn,
    const ushort* __restrict__ vpT, ushort* __restrict__ X)
{
    __shared__ __align__(16) char lds[147456];   // K 2x32K | V 2x32K | P 2x8K
    const int t = threadIdx.x, w = t >> 6, l = t & 63, lr = l & 31, lh = l >> 5;
    const int dh = w >> 2, qg = (w >> 1) & 1, kh = w & 1;
    const int bid0 = blockIdx.x;
    const int L = (bid0 & 7) * 32 + (bid0 >> 3);    // XCD clustering (256 = 8*32)
    const int b = L >> 6, qt = L & 63;
    const int q0 = qt << 6;
    union U4 { unsigned u[4]; bf16x8 v; };

    int koff[4], voff[4];
    #pragma unroll
    for (int i = 0; i < 4; ++i) {
        const int p = i * 512 + t;
        {
            const int R = p >> 5, sl = p & 31;
            koff[i] = R * 512 + ((sl ^ (R & 31)) << 4);
        }
        {
            const int sub = p >> 10, q = p & 1023;
            const int R = q >> 4, ch = (q & 15) ^ (R & 15);
            voff[i] = sub * 16384 + ((ch >> 2) * 64 + R) * 64 + ((ch & 3) << 4);
        }
    }
    const char* kgb = (const char*)(kn + (size_t)b * 4096 * 256);
    const char* vgb = (const char*)vpT + (size_t)b * 128 * 16384;

    #define STAGE_K(bb, tc) do { \
        const char* ks_ = kgb + (size_t)(tc) * 32768; \
        char* kd_ = lds + (bb) * 32768; \
        _Pragma("unroll") \
        for (int i_ = 0; i_ < 4; ++i_) \
            __builtin_amdgcn_global_load_lds( \
                (const __attribute__((address_space(1))) unsigned*)(ks_ + koff[i_]), \
                (__attribute__((address_space(3))) unsigned*)(kd_ + (i_ * 512 + w * 64) * 16), 16, 0, 0); \
        } while (0)
    #define STAGE_V(bb, tc) do { \
        const char* vs_ = vgb + (size_t)(tc) * 32768; \
        char* vd_ = lds + 65536 + (bb) * 32768; \
        _Pragma("unroll") \
        for (int i_ = 0; i_ < 4; ++i_) \
            __builtin_amdgcn_global_load_lds( \
                (const __attribute__((address_space(1))) unsigned*)(vs_ + voff[i_]), \
                (__attribute__((address_space(3))) unsigned*)(vd_ + (i_ * 512 + w * 64) * 16), 16, 0, 0); \
        } while (0)

    const ushort* qrow = qn + ((size_t)b * 4096 + q0 + qg * 32 + lr) * 256 + lh * 8;
    bf16x8 qf[16];
    #pragma unroll
    for (int ks = 0; ks < 16; ++ks) qf[ks] = *(const bf16x8*)(qrow + ks * 16);

    f32x16 oa0{}, oa1{}, oa2{}, oa3{};
    bf16x8 pf0{}, pf1{};

    STAGE_K(0, 0);
    __syncthreads();
    for (int tt = 0; tt <= 64; ++tt) {
        if (tt < 64) {
            if (tt + 1 < 64) STAGE_K((tt + 1) & 1, tt + 1);
            STAGE_V(tt & 1, tt);
        }
        if (tt > 0) {
            const char* vb = lds + 65536 + ((tt - 1) & 1) * 32768 + kh * 16384;
            bf16x8 qp0, qp1;
            if (dh == 0) { qp0 = pf0; qp1 = pf1; }
            else {
                const unsigned* pr = (const unsigned*)(lds + 131072
                                   + ((tt - 1) & 1) * 8192 + (qg * 2 + kh) * 2048);
                U4 a0, a1;
                #pragma unroll
                for (int wd = 0; wd < 4; ++wd) {
                    a0.u[wd] = pr[wd * 64 + l];
                    a1.u[wd] = pr[(4 + wd) * 64 + l];
                }
                qp0 = a0.v; qp1 = a1.v;
            }
            #define PVD(OA, DB) { \
                const int R_  = (((DB) & 1)) * 32 + lr; \
                const int sg_ = dh * 2 + ((DB) >> 1); \
                bf16x8 v0_ = *(const bf16x8*)(vb + R_ * 256 + ((((sg_ << 2) + lh)     ^ (lr & 15)) << 4)); \
                bf16x8 v1_ = *(const bf16x8*)(vb + R_ * 256 + ((((sg_ << 2) + 2 + lh) ^ (lr & 15)) << 4)); \
                OA = __builtin_amdgcn_mfma_f32_32x32x16_bf16(v0_, qp0, OA, 0, 0, 0); \
                OA = __builtin_amdgcn_mfma_f32_32x32x16_bf16(v1_, qp1, OA, 0, 0, 0); }
            PVD(oa0, 0) PVD(oa1, 1) PVD(oa2, 2) PVD(oa3, 3)
            #undef PVD
        }
        if (dh == 0 && tt < 64) {
            const char* kb = lds + (tt & 1) * 32768 + kh * 16384;
            f32x16 s0{}, s1{}, s2{}, s3{};
            #pragma unroll
            for (int ks = 0; ks < 16; ks += 4) {
                bf16x8 k0 = *(const bf16x8*)(kb + lr * 512 + (((2 * ks     + lh) ^ lr) << 4));
                bf16x8 k1 = *(const bf16x8*)(kb + lr * 512 + (((2 * ks + 2 + lh) ^ lr) << 4));
                bf16x8 k2 = *(const bf16x8*)(kb + lr * 512 + (((2 * ks + 4 + lh) ^ lr) << 4));
                bf16x8 k3 = *(const bf16x8*)(kb + lr * 512 + (((2 * ks + 6 + lh) ^ lr) << 4));
                s0 = __builtin_amdgcn_mfma_f32_32x32x16_bf16(k0, qf[ks],     s0, 0, 0, 0);
                s1 = __builtin_amdgcn_mfma_f32_32x32x16_bf16(k1, qf[ks + 1], s1, 0, 0, 0);
                s2 = __builtin_amdgcn_mfma_f32_32x32x16_bf16(k2, qf[ks + 2], s2, 0, 0, 0);
                s3 = __builtin_amdgcn_mfma_f32_32x32x16_bf16(k3, qf[ks + 3], s3, 0, 0, 0);
            }
            f32x16 s = (s0 + s1) + (s2 + s3);
            #define PKR(A, B) ((unsigned)f2bf(fmaxf((A), 0.f)) | ((unsigned)f2bf(fmaxf((B), 0.f)) << 16))
            unsigned p01 = PKR(s[0],  s[1]),  p23 = PKR(s[2],  s[3]);
            unsigned p45 = PKR(s[4],  s[5]),  p67 = PKR(s[6],  s[7]);
            unsigned p89 = PKR(s[8],  s[9]),  pAB = PKR(s[10], s[11]);
            unsigned pCD = PKR(s[12], s[13]), pEF = PKR(s[14], s[15]);
            #undef PKR
            unsigned e1a = lh ? p01 : p45,  e2a = lh ? p23 : p67;
            unsigned e1b = lh ? p89 : pCD,  e2b = lh ? pAB : pEF;
            unsigned f1a = (unsigned)__shfl_xor((int)e1a, 32, 64);
            unsigned f2a = (unsigned)__shfl_xor((int)e2a, 32, 64);
            unsigned f1b = (unsigned)__shfl_xor((int)e1b, 32, 64);
            unsigned f2b = (unsigned)__shfl_xor((int)e2b, 32, 64);
            U4 a0, a1;
            a0.u[0] = lh ? f1a : p01;  a0.u[1] = lh ? f2a : p23;
            a0.u[2] = lh ? p45 : f1a;  a0.u[3] = lh ? p67 : f2a;
            a1.u[0] = lh ? f1b : p89;  a1.u[1] = lh ? f2b : pAB;
            a1.u[2] = lh ? pCD : f1b;  a1.u[3] = lh ? pEF : f2b;
            pf0 = a0.v; pf1 = a1.v;
            unsigned* pw = (unsigned*)(lds + 131072 + (tt & 1) * 8192 + (qg * 2 + kh) * 2048);
            #pragma unroll
            for (int wd = 0; wd < 4; ++wd) {
                pw[wd * 64 + l]       = a0.u[wd];
                pw[(4 + wd) * 64 + l] = a1.u[wd];
            }
        }
        if (tt < 64) __syncthreads();
    }
    #undef STAGE_K
    #undef STAGE_V
    float* red = (float*)lds;
    const int rowbase = ((qg * 2 + dh) * 32 + lr) * 132;
    if (kh == 1) {
        #define REDW(OA, DB) _Pragma("unroll") \
            for (int r = 0; r < 16; r += 2) { \
                const int d_ = (DB) * 32 + (r & 3) + 8 * (r >> 2) + 4 * lh; \
                *(float2*)&red[rowbase + d_] = make_float2((OA)[r], (OA)[r + 1]); }
        REDW(oa0, 0) REDW(oa1, 1) REDW(oa2, 2) REDW(oa3, 3)
        #undef REDW
    }
    __syncthreads();
    if (kh == 0) {
        ushort* Xb = X + ((size_t)b * 4096 + q0 + qg * 32 + lr) * 256 + dh * 128;
        #define OUTD(OA, DB) _Pragma("unroll") \
            for (int r = 0; r < 16; r += 2) { \
                const int d_ = (DB) * 32 + (r & 3) + 8 * (r >> 2) + 4 * lh; \
                float2 p = *(float2*)&red[rowbase + d_]; \
                ushort2 u_; u_.x = f2bf((OA)[r] + p.x); u_.y = f2bf((OA)[r + 1] + p.y); \
                *(ushort2*)(Xb + d_) = u_; }
        OUTD(oa0, 0) OUTD(oa1, 1) OUTD(oa2, 2) OUTD(oa3, 3)
        #undef OUTD
    }
}

// ------------------------------- conv3x3 + BN + SiLU as 9 shifted MFMA GEMMs
__global__ __launch_bounds__(256, 2) void k_conv3_mfma(
    const ushort* __restrict__ X, const ushort* __restrict__ w9p,
    const float* __restrict__ bn_g, const float* __restrict__ bn_b,
    const float* __restrict__ bn_m, const float* __restrict__ bn_v,
    ushort* __restrict__ Y)
{
    __shared__ __align__(16) char smem[67584];   // 2x32KB bufs + 2KB bn (tr aliases bufs)
    float* bnv = (float*)(smem + 65536);
    const int t = threadIdx.x, w = t >> 6, l = t & 63, lr = l & 31, lh = l >> 5;
    {
        float inv = bn_g[t] * rsqrtf(bn_v[t] + 1e-3f);
        bnv[t]       = inv;
        bnv[256 + t] = bn_b[t] - bn_m[t] * inv;
    }
    const int bid = blockIdx.x;                  // 4b x 4ct x 32pt
    const int b = bid >> 7, ct = (bid >> 5) & 3, pt = bid & 31;
    const int co0 = ct * 64, p0 = pt * 128;
    const int wc = w >> 1, wp = w & 1;
    const int h0 = pt * 2 + wp;
    const int cb = ct * 2 + wc;
    const char* Xbytes = (const char*)(X + (size_t)b * 4096 * 256);
    const bf16x8 bz = {};
    f32x16 o0{}, o1{};

    #define CSTAGE(bufb, st_) do { \
        const char* src_ = Xbytes + (ptrdiff_t)(p0 + 64 * ((st_) >> 1) - 64) * 512 \
                         + ((st_) & 1) * 256; \
        char* dst_ = smem + (bufb) * 32768; \
        _Pragma("unroll") \
        for (int i_ = 0; i_ < 8; ++i_) { \
            const int di_ = i_ * 256 + t; \
            const int R_ = di_ >> 4, sl_ = di_ & 15; \
            __builtin_amdgcn_global_load_lds( \
                (const __attribute__((address_space(1))) unsigned*)(src_ + (ptrdiff_t)R_ * 512 + ((sl_ ^ (R_ & 15)) << 4)), \
                (__attribute__((address_space(3))) unsigned*)(dst_ + di_ * 16), 16, 0, 0); \
        } } while (0)

    CSTAGE(0, 0);
    __syncthreads();
    for (int st = 0; st < 6; ++st) {
        if (st < 5) CSTAGE((st + 1) & 1, st + 1);
        if (st < 5) asm volatile("s_waitcnt vmcnt(8)" ::: "memory");
        else        asm volatile("s_waitcnt vmcnt(0)" ::: "memory");
        __builtin_amdgcn_s_barrier();
        const char* xb = smem + (st & 1) * 32768;
        const int dyi = st >> 1, cih = st & 1;
        const int hh = h0 + dyi - 1;
        if (hh >= 0 && hh <= 63) {
            __builtin_amdgcn_s_setprio(1);
            #pragma unroll
            for (int dxi = 0; dxi < 3; ++dxi) {
                const int dx = dxi - 1;
                const int s = dyi * 3 + dxi;
                const bool mA = (dxi == 0) && (lr == 0);
                const bool mB = (dxi == 2) && (lr == 31);
                const int R0 = mA ? 0 : (wp * 64 + lr + dx);
                const int R1 = mB ? 0 : (wp * 64 + lr + dx + 32);
                const ushort* wb = w9p + ((size_t)(s * 8 + cb) * 16 + cih * 8) * 512 + l * 8;
                #pragma unroll
                for (int k8 = 0; k8 < 8; ++k8) {
                    bf16x8 af = *(const bf16x8*)(wb + k8 * 512);
                    bf16x8 b0 = *(const bf16x8*)(xb + R0 * 256 + (((k8 * 2 + lh) ^ (R0 & 15)) << 4));
                    bf16x8 b1 = *(const bf16x8*)(xb + R1 * 256 + (((k8 * 2 + lh) ^ (R1 & 15)) << 4));
                    if (mA) b0 = bz;
                    if (mB) b1 = bz;
                    o0 = __builtin_amdgcn_mfma_f32_32x32x16_bf16(af, b0, o0, 0, 0, 0);
                    o1 = __builtin_amdgcn_mfma_f32_32x32x16_bf16(af, b1, o1, 0, 0, 0);
                }
            }
            __builtin_amdgcn_s_setprio(0);
        }
        __builtin_amdgcn_s_barrier();
    }
    #undef CSTAGE
    ushort (*tr)[72] = (ushort(*)[72])smem;
    #pragma unroll
    for (int r = 0; r < 16; ++r) {
        const int co_l = wc * 32 + (r & 3) + 8 * (r >> 2) + 4 * lh;
        const int co = co0 + co_l;
        const float inv = bnv[co], add = bnv[256 + co];
        float x0 = o0[r] * inv + add;
        float x1 = o1[r] * inv + add;
        x0 = x0 / (1.f + expf(-x0));
        x1 = x1 / (1.f + expf(-x1));
        tr[wp * 64 + lr][co_l]      = f2bf(x0);
        tr[wp * 64 + 32 + lr][co_l] = f2bf(x1);
    }
    __syncthreads();
    const int pp = t >> 1, half = t & 1;
    uint4 u0 = *(uint4*)&tr[pp][half * 32];
    uint4 u1 = *(uint4*)&tr[pp][half * 32 + 8];
    uint4 u2 = *(uint4*)&tr[pp][half * 32 + 16];
    uint4 u3 = *(uint4*)&tr[pp][half * 32 + 24];
    ushort* yb = Y + ((size_t)b * 4096 + p0 + pp) * 256 + co0 + half * 32;
    *(uint4*)yb        = u0; *(uint4*)(yb + 8)  = u1;
    *(uint4*)(yb + 16) = u2; *(uint4*)(yb + 24) = u3;
}

// ------------------------- conv1x1 + bias + residual (LDS-staged GEMM form)
// out[b][co][p] = q + Y @ W2^T + b2. Block: 128co x 128p, 8 waves (2co x 4p).
__global__ __launch_bounds__(512, 1) void k_conv1x1_mfma(
    const ushort* __restrict__ Y, const ushort* __restrict__ W2,
    const float* __restrict__ bias2, const float* __restrict__ query,
    float* __restrict__ out)
{
    __shared__ __align__(16) char lds[131072];   // Y 64K | W2 64K
    const int t = threadIdx.x, w = t >> 6, l = t & 63, lr = l & 31, lh = l >> 5;
    const int wc = w >> 2, wp = w & 3;
    const int bid = blockIdx.x;                  // b(4) x pt(32) x ct(2)
    const int b = bid >> 6, pt = (bid >> 1) & 31, ct = bid & 1;
    const int p0 = pt * 128, co0 = ct * 128;
    const char* Yb = (const char*)Y + ((size_t)b * 4096 + p0) * 512;
    const char* Wb = (const char*)W2 + (size_t)co0 * 512;
    #pragma unroll
    for (int i = 0; i < 8; ++i) {
        const int p = i * 512 + t;
        const int R = p >> 5, sl = p & 31;
        const int so = R * 512 + ((sl ^ (R & 31)) << 4);
        __builtin_amdgcn_global_load_lds(
            (const __attribute__((address_space(1))) unsigned*)(Yb + so),
            (__attribute__((address_space(3))) unsigned*)(lds + p * 16), 16, 0, 0);
        __builtin_amdgcn_global_load_lds(
            (const __attribute__((address_space(1))) unsigned*)(Wb + so),
            (__attribute__((address_space(3))) unsigned*)(lds + 65536 + p * 16), 16, 0, 0);
    }
    __syncthreads();
    const char* Ybuf = lds;
    const char* Wbuf = lds + 65536;
    const int cr0 = wc * 64 + lr, cr1 = cr0 + 32;
    const int yr  = wp * 32 + lr;
    f32x16 o0{}, o1{};
    #pragma unroll
    for (int ks = 0; ks < 16; ++ks) {
        const int j = 2 * ks + lh;
        bf16x8 w0 = *(const bf16x8*)(Wbuf + cr0 * 512 + ((j ^ lr) << 4));
        bf16x8 w1 = *(const bf16x8*)(Wbuf + cr1 * 512 + ((j ^ lr) << 4));
        bf16x8 yf = *(const bf16x8*)(Ybuf + yr  * 512 + ((j ^ lr) << 4));
        o0 = __builtin_amdgcn_mfma_f32_32x32x16_bf16(w0, yf, o0, 0, 0, 0);
        o1 = __builtin_amdgcn_mfma_f32_32x32x16_bf16(w1, yf, o1, 0, 0, 0);
    }
    const int p = p0 + wp * 32 + lr;
    #pragma unroll
    for (int r = 0; r < 16; ++r) {
        const int crow = (r & 3) + 8 * (r >> 2) + 4 * lh;
        const int coA = co0 + wc * 64 + crow;
        const int coB = coA + 32;
        const size_t baseA = ((size_t)b * 256 + coA) * 4096 + p;
        const size_t baseB = ((size_t)b * 256 + coB) * 4096 + p;
        out[baseA] = o0[r] + bias2[coA] + query[baseA];
        out[baseB] = o1[r] + bias2[coB] + query[baseB];
    }
}

// ---------------------------------------------------------------- launch
extern "C" void kernel_launch(void* const* d_in, const int* in_sizes, int n_in,
                              void* d_out, int out_size, void* d_ws, size_t ws_size,
                              hipStream_t stream) {
    const float* query   = (const float*)d_in[0];
    const float* v_in    = (const float*)d_in[1];
    const float* qpos    = (const float*)d_in[2];
    const float* kpos    = (const float*)d_in[3];
    const float* otherW  = (const float*)d_in[4];
    const float* w_vs    = (const float*)d_in[5];
    const float* mlp_w1  = (const float*)d_in[6];
    const float* mlp_b1  = (const float*)d_in[7];
    const float* mlp_w2  = (const float*)d_in[8];
    const float* mlp_b2  = (const float*)d_in[9];
    const float* conv1_w = (const float*)d_in[10];
    const float* bn_g    = (const float*)d_in[11];
    const float* bn_b    = (const float*)d_in[12];
    const float* bn_m    = (const float*)d_in[13];
    const float* bn_v    = (const float*)d_in[14];
    const float* conv2_w = (const float*)d_in[15];
    const float* conv2_b = (const float*)d_in[16];
    float* out = (float*)d_out;
    char* base = (char*)d_ws;

    constexpr size_t MB = 1u << 20;
    ushort* v_bf    = (ushort*)(base);             // 8MB   (dead after vproj)
    ushort* qpos_bf = (ushort*)(base + 8 * MB);    // 8MB   (dead after mlp1)
    float*  qp_f32  = (float*) (base);             // 16MB  (aliases v_bf+qpos_bf)
    ushort* qhid_bf = (ushort*)(base + 16 * MB);   // 8MB   (dead after mlp2)
    ushort* X_bf    = (ushort*)(base + 16 * MB);   // 8MB   (attn out, aliases qhid)
    ushort* qn_bf   = (ushort*)(base + 24 * MB);   // 8MB   (dead after attn)
    ushort* Y_bf    = (ushort*)(base + 24 * MB);   // 8MB   (conv3 out, aliases qn)
    ushort* kn_bf   = (ushort*)(base + 32 * MB);   // 8MB
    ushort* vT_bf   = (ushort*)(base + 40 * MB);   // 8MB  (w-scaled V'^T, k-tiled)
    ushort* wvs_bf  = (ushort*)(base + 48 * MB);
    ushort* w1e_bf  = (ushort*)(base + 48 * MB + 128 * 1024);
    ushort* w2_bf   = (ushort*)(base + 48 * MB + 256 * 1024);
    ushort* c2_bf   = (ushort*)(base + 48 * MB + 384 * 1024);
    ushort* w9p_bf  = (ushort*)(base + 48 * MB + 512 * 1024);   // 1.125MB packed

    k_prep<<<15040, 256, 0, stream>>>(v_in, otherW, v_bf, qpos, qpos_bf,
                                      kpos, kn_bf, conv1_w, w9p_bf,
                                      w_vs, wvs_bf, mlp_w2, w2_bf,
                                      conv2_w, c2_bf, mlp_w1, w1e_bf);
    k_gemm_mfma<2, 0><<<256, 512, 0, stream>>>(v_bf, wvs_bf, nullptr, vT_bf);
    k_gemm_mfma<1, 1><<<256, 512, 0, stream>>>(qpos_bf, w1e_bf, mlp_b1, qhid_bf);
    k_gemm_mfma<0, 0><<<256, 512, 0, stream>>>(qhid_bf, w2_bf, mlp_b2, qp_f32);
    k_l2norm_bf16<<<4096, 256, 0, stream>>>(qp_f32, qn_bf);
    k_attn_mfma<<<256, 512, 0, stream>>>(qn_bf, kn_bf, vT_bf, X_bf);
    k_conv3_mfma<<<512, 256, 0, stream>>>(X_bf, w9p_bf, bn_g, bn_b, bn_m, bn_v, Y_bf);
    k_conv1x1_mfma<<<256, 512, 0, stream>>>(Y_bf, c2_bf, conv2_b, query, out);
}

// Round 13
// 180.378 us; speedup vs baseline: 3.5116x; 1.0183x over previous
//
#include <hip/hip_runtime.h>
#include <math.h>

// Fixed problem dims
constexpr int kB  = 4;
constexpr int kD  = 256;
constexpr int kNQ = 4096;
constexpr int kNK = 4096;
constexpr int kHW = 4096;   // 64*64

typedef __bf16 bf16x8 __attribute__((ext_vector_type(8)));
typedef float  f32x16 __attribute__((ext_vector_type(16)));

__device__ __forceinline__ unsigned short f2bf(float x) {
    unsigned int u = __builtin_bit_cast(unsigned int, x);
    u = (u + 0x7fffu + ((u >> 16) & 1u)) >> 16;
    return (unsigned short)u;
}

// =============================================== fused prep (1 launch, 15040 blocks)
__global__ __launch_bounds__(256) void k_prep(
    const float* __restrict__ v_in, const float* __restrict__ ow, ushort* __restrict__ v_bf,
    const float* __restrict__ qpos, ushort* __restrict__ qpos_bf,
    const float* __restrict__ kpos, ushort* __restrict__ kn_bf,
    const float* __restrict__ conv1_w, ushort* __restrict__ w9p,
    const float* __restrict__ w_vs, ushort* __restrict__ wvs_bf,
    const float* __restrict__ mlp_w2, ushort* __restrict__ w2_bf,
    const float* __restrict__ conv2_w, ushort* __restrict__ c2_bf,
    const float* __restrict__ mlp_w1, ushort* __restrict__ w1e_bf)
{
    const int bid = blockIdx.x, t = threadIdx.x;
    if (bid < 4096) {
        const int i = bid * 256 + t;
        float4 v = ((const float4*)v_in)[i];
        const float wsc = ow[i >> 6];
        ushort4 o;
        o.x = f2bf(v.x * wsc); o.y = f2bf(v.y * wsc);
        o.z = f2bf(v.z * wsc); o.w = f2bf(v.w * wsc);
        ((ushort4*)v_bf)[i] = o;
    } else if (bid < 8192) {
        const int i = (bid - 4096) * 256 + t;
        float4 v = ((const float4*)qpos)[i];
        ushort4 o;
        o.x = f2bf(v.x); o.y = f2bf(v.y); o.z = f2bf(v.z); o.w = f2bf(v.w);
        ((ushort4*)qpos_bf)[i] = o;
    } else if (bid < 12288) {
        const int row  = (bid - 8192) * 4 + (t >> 6);
        const int lane = t & 63;
        float4 v = ((const float4*)(kpos + (size_t)row * 256))[lane];
        float ss = v.x * v.x + v.y * v.y + v.z * v.z + v.w * v.w;
        #pragma unroll
        for (int off = 32; off; off >>= 1) ss += __shfl_xor(ss, off, 64);
        const float rn = 1.0f / sqrtf(ss);
        ushort4 o;
        o.x = f2bf(v.x * rn); o.y = f2bf(v.y * rn);
        o.z = f2bf(v.z * rn); o.w = f2bf(v.w * rn);
        ((ushort4*)(kn_bf + (size_t)row * 256))[lane] = o;
    } else if (bid < 14592) {
        const int idx = bid - 12288;
        const int s = idx >> 8, co = idx & 255, ci = t;
        const int oidx = ((s * 8 + (co >> 5)) * 16 + (ci >> 4)) * 512
                       + ((ci >> 3) & 1) * 256 + (co & 31) * 8 + (ci & 7);
        w9p[oidx] = f2bf(conv1_w[((size_t)co * 256 + ci) * 9 + s]);
    } else if (bid < 14784) {
        const float* src = (bid < 14656) ? w_vs : (bid < 14720) ? mlp_w2 : conv2_w;
        ushort* dst = (bid < 14656) ? wvs_bf : (bid < 14720) ? w2_bf : c2_bf;
        const int i = ((bid - 14592) & 63) * 256 + t;
        float4 v = ((const float4*)src)[i];
        ushort4 o;
        o.x = f2bf(v.x); o.y = f2bf(v.y); o.z = f2bf(v.z); o.w = f2bf(v.w);
        ((ushort4*)dst)[i] = o;
    } else {
        const int h = bid - 14784;
        w1e_bf[h * 256 + t] = f2bf(mlp_w1[h * 512 + t] + mlp_w1[h * 512 + 256 + t]);
    }
}

// ----------------------------------------------- staged MFMA GEMM  C = A @ W^T
// A [M,256] bf16, W [256,256] bf16 ([n][k]). Block: 128m x 128n, 8 waves (2m x 4n).
// EPI: 0 = f32 [m][256]; 1 = bf16 [m][256];
// EPI 2 = bf16 K-TILED transpose: [b][kt=m/32][n(256)][m%32] (16KB contiguous tiles)
template<int EPI, int RELU>
__global__ __launch_bounds__(512, 1) void k_gemm_mfma(
    const ushort* __restrict__ A, const ushort* __restrict__ W,
    const float* __restrict__ bias, void* __restrict__ outp)
{
    __shared__ __align__(16) char lds[131072];   // A 64K | W 64K (tr aliases A)
    const int t = threadIdx.x, w = t >> 6, l = t & 63, lr = l & 31, lh = l >> 5;
    const int wm = w >> 2, wn = w & 3;
    const int m0 = (blockIdx.x >> 1) * 128;
    const int n0 = (blockIdx.x & 1) * 128;
    const char* Ab = (const char*)A + (size_t)m0 * 512;
    const char* Wb = (const char*)W + (size_t)n0 * 512;
    #pragma unroll
    for (int i = 0; i < 8; ++i) {
        const int p = i * 512 + t;
        const int R = p >> 5, sl = p & 31;
        const int so = R * 512 + ((sl ^ (R & 31)) << 4);
        __builtin_amdgcn_global_load_lds(
            (const __attribute__((address_space(1))) unsigned*)(Ab + so),
            (__attribute__((address_space(3))) unsigned*)(lds + p * 16), 16, 0, 0);
        __builtin_amdgcn_global_load_lds(
            (const __attribute__((address_space(1))) unsigned*)(Wb + so),
            (__attribute__((address_space(3))) unsigned*)(lds + 65536 + p * 16), 16, 0, 0);
    }
    __syncthreads();
    const char* Abuf = lds;
    const char* Wbuf = lds + 65536;
    const int ar0 = wm * 64 + lr, ar1 = ar0 + 32;
    const int wrr = wn * 32 + lr;
    f32x16 c0{}, c1{};
    #pragma unroll
    for (int ks = 0; ks < 16; ++ks) {
        const int j = 2 * ks + lh;
        bf16x8 a0 = *(const bf16x8*)(Abuf + ar0 * 512 + ((j ^ lr) << 4));
        bf16x8 a1 = *(const bf16x8*)(Abuf + ar1 * 512 + ((j ^ lr) << 4));
        bf16x8 wf = *(const bf16x8*)(Wbuf + wrr * 512 + ((j ^ lr) << 4));
        c0 = __builtin_amdgcn_mfma_f32_32x32x16_bf16(a0, wf, c0, 0, 0, 0);
        c1 = __builtin_amdgcn_mfma_f32_32x32x16_bf16(a1, wf, c1, 0, 0, 0);
    }
    const int n = n0 + wn * 32 + lr;
    float bb = bias ? bias[n] : 0.f;
    if constexpr (EPI == 2) {
        __syncthreads();                         // all frag reads done before alias
        ushort (*tr)[136] = (ushort(*)[136])lds; // [n_local 128][m_local 128+pad]
        #pragma unroll
        for (int r = 0; r < 16; ++r) {
            const int ml = wm * 64 + (r & 3) + 8 * (r >> 2) + 4 * lh;
            float v0 = c0[r], v1 = c1[r];
            if (RELU) { v0 = fmaxf(v0, 0.f); v1 = fmaxf(v1, 0.f); }
            tr[wn * 32 + lr][ml]      = f2bf(v0);
            tr[wn * 32 + lr][ml + 32] = f2bf(v1);
        }
        __syncthreads();
        ushort* out = (ushort*)outp;
        const int b = m0 >> 12, mm = m0 & 4095;
        const int row = t >> 2, seg = t & 3;     // 128 rows x 4 segs of 32 m
        uint4 u0 = *(uint4*)&tr[row][seg * 32];
        uint4 u1 = *(uint4*)&tr[row][seg * 32 + 8];
        uint4 u2 = *(uint4*)&tr[row][seg * 32 + 16];
        uint4 u3 = *(uint4*)&tr[row][seg * 32 + 24];
        ushort* ob = out + ((size_t)(b * 128 + (mm >> 5) + seg) * 256 + n0 + row) * 32;
        *(uint4*)ob        = u0; *(uint4*)(ob + 8)  = u1;
        *(uint4*)(ob + 16) = u2; *(uint4*)(ob + 24) = u3;
    } else {
        #pragma unroll
        for (int r = 0; r < 16; ++r) {
            const int m = m0 + wm * 64 + (r & 3) + 8 * (r >> 2) + 4 * lh;
            float v0 = c0[r] + bb, v1 = c1[r] + bb;
            if (RELU) { v0 = fmaxf(v0, 0.f); v1 = fmaxf(v1, 0.f); }
            if constexpr (EPI == 0) {
                float* out = (float*)outp;
                out[(size_t)m * 256 + n]      = v0;
                out[(size_t)(m + 32) * 256 + n] = v1;
            } else {
                ushort* out = (ushort*)outp;
                out[(size_t)m * 256 + n]      = f2bf(v0);
                out[(size_t)(m + 32) * 256 + n] = f2bf(v1);
            }
        }
    }
}

// ---------------------------------------------------------------- MFMA attention
// X[b][q][d] (bf16) = sum_k relu((qp/|qp|).kn) * vT'[d][k]  (w folded in V')
// Q L2-norm FUSED: dh=0 loads qp f32, computes rn = rsqrt(sum qp^2) per row;
// rn>0 commutes with relu, and in swapped-S^T layout q = lane&31, so rn folds
// into the pack multiply. Cross-tile pipelined QK dedup (r11) + T5 setprio.
__global__ __launch_bounds__(512, 2) void k_attn_mfma(
    const float* __restrict__ qpf, const ushort* __restrict__ kn,
    const ushort* __restrict__ vpT, ushort* __restrict__ X)
{
    __shared__ __align__(16) char lds[147456];   // K 2x32K | V 2x32K | P 2x8K
    const int t = threadIdx.x, w = t >> 6, l = t & 63, lr = l & 31, lh = l >> 5;
    const int dh = w >> 2, qg = (w >> 1) & 1, kh = w & 1;
    const int bid0 = blockIdx.x;
    const int L = (bid0 & 7) * 32 + (bid0 >> 3);    // XCD clustering (256 = 8*32)
    const int b = L >> 6, qt = L & 63;
    const int q0 = qt << 6;
    union U4 { unsigned u[4]; bf16x8 v; };

    int koff[4], voff[4];
    #pragma unroll
    for (int i = 0; i < 4; ++i) {
        const int p = i * 512 + t;
        {
            const int R = p >> 5, sl = p & 31;
            koff[i] = R * 512 + ((sl ^ (R & 31)) << 4);
        }
        {
            const int sub = p >> 10, q = p & 1023;
            const int R = q >> 4, ch = (q & 15) ^ (R & 15);
            voff[i] = sub * 16384 + ((ch >> 2) * 64 + R) * 64 + ((ch & 3) << 4);
        }
    }
    const char* kgb = (const char*)(kn + (size_t)b * 4096 * 256);
    const char* vgb = (const char*)vpT + (size_t)b * 128 * 16384;

    #define STAGE_K(bb, tc) do { \
        const char* ks_ = kgb + (size_t)(tc) * 32768; \
        char* kd_ = lds + (bb) * 32768; \
        _Pragma("unroll") \
        for (int i_ = 0; i_ < 4; ++i_) \
            __builtin_amdgcn_global_load_lds( \
                (const __attribute__((address_space(1))) unsigned*)(ks_ + koff[i_]), \
                (__attribute__((address_space(3))) unsigned*)(kd_ + (i_ * 512 + w * 64) * 16), 16, 0, 0); \
        } while (0)
    #define STAGE_V(bb, tc) do { \
        const char* vs_ = vgb + (size_t)(tc) * 32768; \
        char* vd_ = lds + 65536 + (bb) * 32768; \
        _Pragma("unroll") \
        for (int i_ = 0; i_ < 4; ++i_) \
            __builtin_amdgcn_global_load_lds( \
                (const __attribute__((address_space(1))) unsigned*)(vs_ + voff[i_]), \
                (__attribute__((address_space(3))) unsigned*)(vd_ + (i_ * 512 + w * 64) * 16), 16, 0, 0); \
        } while (0)

    // Q load (dh=0 only): f32 -> bf16 frags + row sum-of-squares -> rn
    bf16x8 qf[16];
    float rn = 0.f;
    if (dh == 0) {
        const float* qrow = qpf + ((size_t)b * 4096 + q0 + qg * 32 + lr) * 256 + lh * 8;
        float ss = 0.f;
        #pragma unroll
        for (int ks = 0; ks < 16; ++ks) {
            float4 a = *(const float4*)(qrow + ks * 16);
            float4 c = *(const float4*)(qrow + ks * 16 + 4);
            ss += a.x * a.x + a.y * a.y + a.z * a.z + a.w * a.w
                + c.x * c.x + c.y * c.y + c.z * c.z + c.w * c.w;
            U4 q8a;
            q8a.u[0] = (unsigned)f2bf(a.x) | ((unsigned)f2bf(a.y) << 16);
            q8a.u[1] = (unsigned)f2bf(a.z) | ((unsigned)f2bf(a.w) << 16);
            q8a.u[2] = (unsigned)f2bf(c.x) | ((unsigned)f2bf(c.y) << 16);
            q8a.u[3] = (unsigned)f2bf(c.z) | ((unsigned)f2bf(c.w) << 16);
            qf[ks] = q8a.v;
        }
        ss += __shfl_xor(ss, 32, 64);
        rn = rsqrtf(ss);
    }

    f32x16 oa0{}, oa1{}, oa2{}, oa3{};
    bf16x8 pf0{}, pf1{};

    STAGE_K(0, 0);
    __syncthreads();
    for (int tt = 0; tt <= 64; ++tt) {
        if (tt < 64) {
            if (tt + 1 < 64) STAGE_K((tt + 1) & 1, tt + 1);
            STAGE_V(tt & 1, tt);
        }
        if (tt > 0) {
            const char* vb = lds + 65536 + ((tt - 1) & 1) * 32768 + kh * 16384;
            bf16x8 qp0, qp1;
            if (dh == 0) { qp0 = pf0; qp1 = pf1; }
            else {
                const unsigned* pr = (const unsigned*)(lds + 131072
                                   + ((tt - 1) & 1) * 8192 + (qg * 2 + kh) * 2048);
                U4 a0, a1;
                #pragma unroll
                for (int wd = 0; wd < 4; ++wd) {
                    a0.u[wd] = pr[wd * 64 + l];
                    a1.u[wd] = pr[(4 + wd) * 64 + l];
                }
                qp0 = a0.v; qp1 = a1.v;
            }
            __builtin_amdgcn_s_setprio(1);
            #define PVD(OA, DB) { \
                const int R_  = (((DB) & 1)) * 32 + lr; \
                const int sg_ = dh * 2 + ((DB) >> 1); \
                bf16x8 v0_ = *(const bf16x8*)(vb + R_ * 256 + ((((sg_ << 2) + lh)     ^ (lr & 15)) << 4)); \
                bf16x8 v1_ = *(const bf16x8*)(vb + R_ * 256 + ((((sg_ << 2) + 2 + lh) ^ (lr & 15)) << 4)); \
                OA = __builtin_amdgcn_mfma_f32_32x32x16_bf16(v0_, qp0, OA, 0, 0, 0); \
                OA = __builtin_amdgcn_mfma_f32_32x32x16_bf16(v1_, qp1, OA, 0, 0, 0); }
            PVD(oa0, 0) PVD(oa1, 1) PVD(oa2, 2) PVD(oa3, 3)
            #undef PVD
            __builtin_amdgcn_s_setprio(0);
        }
        if (dh == 0 && tt < 64) {
            const char* kb = lds + (tt & 1) * 32768 + kh * 16384;
            f32x16 s0{}, s1{}, s2{}, s3{};
            __builtin_amdgcn_s_setprio(1);
            #pragma unroll
            for (int ks = 0; ks < 16; ks += 4) {
                bf16x8 k0 = *(const bf16x8*)(kb + lr * 512 + (((2 * ks     + lh) ^ lr) << 4));
                bf16x8 k1 = *(const bf16x8*)(kb + lr * 512 + (((2 * ks + 2 + lh) ^ lr) << 4));
                bf16x8 k2 = *(const bf16x8*)(kb + lr * 512 + (((2 * ks + 4 + lh) ^ lr) << 4));
                bf16x8 k3 = *(const bf16x8*)(kb + lr * 512 + (((2 * ks + 6 + lh) ^ lr) << 4));
                s0 = __builtin_amdgcn_mfma_f32_32x32x16_bf16(k0, qf[ks],     s0, 0, 0, 0);
                s1 = __builtin_amdgcn_mfma_f32_32x32x16_bf16(k1, qf[ks + 1], s1, 0, 0, 0);
                s2 = __builtin_amdgcn_mfma_f32_32x32x16_bf16(k2, qf[ks + 2], s2, 0, 0, 0);
                s3 = __builtin_amdgcn_mfma_f32_32x32x16_bf16(k3, qf[ks + 3], s3, 0, 0, 0);
            }
            __builtin_amdgcn_s_setprio(0);
            f32x16 s = (s0 + s1) + (s2 + s3);
            #define PKR(A, B) ((unsigned)f2bf(fmaxf((A), 0.f) * rn) | ((unsigned)f2bf(fmaxf((B), 0.f) * rn) << 16))
            unsigned p01 = PKR(s[0],  s[1]),  p23 = PKR(s[2],  s[3]);
            unsigned p45 = PKR(s[4],  s[5]),  p67 = PKR(s[6],  s[7]);
            unsigned p89 = PKR(s[8],  s[9]),  pAB = PKR(s[10], s[11]);
            unsigned pCD = PKR(s[12], s[13]), pEF = PKR(s[14], s[15]);
            #undef PKR
            unsigned e1a = lh ? p01 : p45,  e2a = lh ? p23 : p67;
            unsigned e1b = lh ? p89 : pCD,  e2b = lh ? pAB : pEF;
            unsigned f1a = (unsigned)__shfl_xor((int)e1a, 32, 64);
            unsigned f2a = (unsigned)__shfl_xor((int)e2a, 32, 64);
            unsigned f1b = (unsigned)__shfl_xor((int)e1b, 32, 64);
            unsigned f2b = (unsigned)__shfl_xor((int)e2b, 32, 64);
            U4 a0, a1;
            a0.u[0] = lh ? f1a : p01;  a0.u[1] = lh ? f2a : p23;
            a0.u[2] = lh ? p45 : f1a;  a0.u[3] = lh ? p67 : f2a;
            a1.u[0] = lh ? f1b : p89;  a1.u[1] = lh ? f2b : pAB;
            a1.u[2] = lh ? pCD : f1b;  a1.u[3] = lh ? pEF : f2b;
            pf0 = a0.v; pf1 = a1.v;
            unsigned* pw = (unsigned*)(lds + 131072 + (tt & 1) * 8192 + (qg * 2 + kh) * 2048);
            #pragma unroll
            for (int wd = 0; wd < 4; ++wd) {
                pw[wd * 64 + l]       = a0.u[wd];
                pw[(4 + wd) * 64 + l] = a1.u[wd];
            }
        }
        if (tt < 64) __syncthreads();
    }
    #undef STAGE_K
    #undef STAGE_V
    float* red = (float*)lds;
    const int rowbase = ((qg * 2 + dh) * 32 + lr) * 132;
    if (kh == 1) {
        #define REDW(OA, DB) _Pragma("unroll") \
            for (int r = 0; r < 16; r += 2) { \
                const int d_ = (DB) * 32 + (r & 3) + 8 * (r >> 2) + 4 * lh; \
                *(float2*)&red[rowbase + d_] = make_float2((OA)[r], (OA)[r + 1]); }
        REDW(oa0, 0) REDW(oa1, 1) REDW(oa2, 2) REDW(oa3, 3)
        #undef REDW
    }
    __syncthreads();
    if (kh == 0) {
        ushort* Xb = X + ((size_t)b * 4096 + q0 + qg * 32 + lr) * 256 + dh * 128;
        #define OUTD(OA, DB) _Pragma("unroll") \
            for (int r = 0; r < 16; r += 2) { \
                const int d_ = (DB) * 32 + (r & 3) + 8 * (r >> 2) + 4 * lh; \
                float2 p = *(float2*)&red[rowbase + d_]; \
                ushort2 u_; u_.x = f2bf((OA)[r] + p.x); u_.y = f2bf((OA)[r + 1] + p.y); \
                *(ushort2*)(Xb + d_) = u_; }
        OUTD(oa0, 0) OUTD(oa1, 1) OUTD(oa2, 2) OUTD(oa3, 3)
        #undef OUTD
    }
}

// ------------------------------- conv3x3 + BN + SiLU as 9 shifted MFMA GEMMs
__global__ __launch_bounds__(256, 2) void k_conv3_mfma(
    const ushort* __restrict__ X, const ushort* __restrict__ w9p,
    const float* __restrict__ bn_g, const float* __restrict__ bn_b,
    const float* __restrict__ bn_m, const float* __restrict__ bn_v,
    ushort* __restrict__ Y)
{
    __shared__ __align__(16) char smem[67584];   // 2x32KB bufs + 2KB bn (tr aliases bufs)
    float* bnv = (float*)(smem + 65536);
    const int t = threadIdx.x, w = t >> 6, l = t & 63, lr = l & 31, lh = l >> 5;
    {
        float inv = bn_g[t] * rsqrtf(bn_v[t] + 1e-3f);
        bnv[t]       = inv;
        bnv[256 + t] = bn_b[t] - bn_m[t] * inv;
    }
    const int bid = blockIdx.x;                  // 4b x 4ct x 32pt
    const int b = bid >> 7, ct = (bid >> 5) & 3, pt = bid & 31;
    const int co0 = ct * 64, p0 = pt * 128;
    const int wc = w >> 1, wp = w & 1;
    const int h0 = pt * 2 + wp;
    const int cb = ct * 2 + wc;
    const char* Xbytes = (const char*)(X + (size_t)b * 4096 * 256);
    const bf16x8 bz = {};
    f32x16 o0{}, o1{};

    #define CSTAGE(bufb, st_) do { \
        const char* src_ = Xbytes + (ptrdiff_t)(p0 + 64 * ((st_) >> 1) - 64) * 512 \
                         + ((st_) & 1) * 256; \
        char* dst_ = smem + (bufb) * 32768; \
        _Pragma("unroll") \
        for (int i_ = 0; i_ < 8; ++i_) { \
            const int di_ = i_ * 256 + t; \
            const int R_ = di_ >> 4, sl_ = di_ & 15; \
            __builtin_amdgcn_global_load_lds( \
                (const __attribute__((address_space(1))) unsigned*)(src_ + (ptrdiff_t)R_ * 512 + ((sl_ ^ (R_ & 15)) << 4)), \
                (__attribute__((address_space(3))) unsigned*)(dst_ + di_ * 16), 16, 0, 0); \
        } } while (0)

    CSTAGE(0, 0);
    __syncthreads();
    for (int st = 0; st < 6; ++st) {
        if (st < 5) CSTAGE((st + 1) & 1, st + 1);
        if (st < 5) asm volatile("s_waitcnt vmcnt(8)" ::: "memory");
        else        asm volatile("s_waitcnt vmcnt(0)" ::: "memory");
        __builtin_amdgcn_s_barrier();
        const char* xb = smem + (st & 1) * 32768;
        const int dyi = st >> 1, cih = st & 1;
        const int hh = h0 + dyi - 1;
        if (hh >= 0 && hh <= 63) {
            __builtin_amdgcn_s_setprio(1);
            #pragma unroll
            for (int dxi = 0; dxi < 3; ++dxi) {
                const int dx = dxi - 1;
                const int s = dyi * 3 + dxi;
                const bool mA = (dxi == 0) && (lr == 0);
                const bool mB = (dxi == 2) && (lr == 31);
                const int R0 = mA ? 0 : (wp * 64 + lr + dx);
                const int R1 = mB ? 0 : (wp * 64 + lr + dx + 32);
                const ushort* wb = w9p + ((size_t)(s * 8 + cb) * 16 + cih * 8) * 512 + l * 8;
                #pragma unroll
                for (int k8 = 0; k8 < 8; ++k8) {
                    bf16x8 af = *(const bf16x8*)(wb + k8 * 512);
                    bf16x8 b0 = *(const bf16x8*)(xb + R0 * 256 + (((k8 * 2 + lh) ^ (R0 & 15)) << 4));
                    bf16x8 b1 = *(const bf16x8*)(xb + R1 * 256 + (((k8 * 2 + lh) ^ (R1 & 15)) << 4));
                    if (mA) b0 = bz;
                    if (mB) b1 = bz;
                    o0 = __builtin_amdgcn_mfma_f32_32x32x16_bf16(af, b0, o0, 0, 0, 0);
                    o1 = __builtin_amdgcn_mfma_f32_32x32x16_bf16(af, b1, o1, 0, 0, 0);
                }
            }
            __builtin_amdgcn_s_setprio(0);
        }
        __builtin_amdgcn_s_barrier();
    }
    #undef CSTAGE
    ushort (*tr)[72] = (ushort(*)[72])smem;
    #pragma unroll
    for (int r = 0; r < 16; ++r) {
        const int co_l = wc * 32 + (r & 3) + 8 * (r >> 2) + 4 * lh;
        const int co = co0 + co_l;
        const float inv = bnv[co], add = bnv[256 + co];
        float x0 = o0[r] * inv + add;
        float x1 = o1[r] * inv + add;
        x0 = x0 / (1.f + expf(-x0));
        x1 = x1 / (1.f + expf(-x1));
        tr[wp * 64 + lr][co_l]      = f2bf(x0);
        tr[wp * 64 + 32 + lr][co_l] = f2bf(x1);
    }
    __syncthreads();
    const int pp = t >> 1, half = t & 1;
    uint4 u0 = *(uint4*)&tr[pp][half * 32];
    uint4 u1 = *(uint4*)&tr[pp][half * 32 + 8];
    uint4 u2 = *(uint4*)&tr[pp][half * 32 + 16];
    uint4 u3 = *(uint4*)&tr[pp][half * 32 + 24];
    ushort* yb = Y + ((size_t)b * 4096 + p0 + pp) * 256 + co0 + half * 32;
    *(uint4*)yb        = u0; *(uint4*)(yb + 8)  = u1;
    *(uint4*)(yb + 16) = u2; *(uint4*)(yb + 24) = u3;
}

// ------------------------- conv1x1 + bias + residual (LDS-staged GEMM form)
__global__ __launch_bounds__(512, 1) void k_conv1x1_mfma(
    const ushort* __restrict__ Y, const ushort* __restrict__ W2,
    const float* __restrict__ bias2, const float* __restrict__ query,
    float* __restrict__ out)
{
    __shared__ __align__(16) char lds[131072];   // Y 64K | W2 64K
    const int t = threadIdx.x, w = t >> 6, l = t & 63, lr = l & 31, lh = l >> 5;
    const int wc = w >> 2, wp = w & 3;
    const int bid = blockIdx.x;                  // b(4) x pt(32) x ct(2)
    const int b = bid >> 6, pt = (bid >> 1) & 31, ct = bid & 1;
    const int p0 = pt * 128, co0 = ct * 128;
    const char* Yb = (const char*)Y + ((size_t)b * 4096 + p0) * 512;
    const char* Wb = (const char*)W2 + (size_t)co0 * 512;
    #pragma unroll
    for (int i = 0; i < 8; ++i) {
        const int p = i * 512 + t;
        const int R = p >> 5, sl = p & 31;
        const int so = R * 512 + ((sl ^ (R & 31)) << 4);
        __builtin_amdgcn_global_load_lds(
            (const __attribute__((address_space(1))) unsigned*)(Yb + so),
            (__attribute__((address_space(3))) unsigned*)(lds + p * 16), 16, 0, 0);
        __builtin_amdgcn_global_load_lds(
            (const __attribute__((address_space(1))) unsigned*)(Wb + so),
            (__attribute__((address_space(3))) unsigned*)(lds + 65536 + p * 16), 16, 0, 0);
    }
    __syncthreads();
    const char* Ybuf = lds;
    const char* Wbuf = lds + 65536;
    const int cr0 = wc * 64 + lr, cr1 = cr0 + 32;
    const int yr  = wp * 32 + lr;
    f32x16 o0{}, o1{};
    #pragma unroll
    for (int ks = 0; ks < 16; ++ks) {
        const int j = 2 * ks + lh;
        bf16x8 w0 = *(const bf16x8*)(Wbuf + cr0 * 512 + ((j ^ lr) << 4));
        bf16x8 w1 = *(const bf16x8*)(Wbuf + cr1 * 512 + ((j ^ lr) << 4));
        bf16x8 yf = *(const bf16x8*)(Ybuf + yr  * 512 + ((j ^ lr) << 4));
        o0 = __builtin_amdgcn_mfma_f32_32x32x16_bf16(w0, yf, o0, 0, 0, 0);
        o1 = __builtin_amdgcn_mfma_f32_32x32x16_bf16(w1, yf, o1, 0, 0, 0);
    }
    const int p = p0 + wp * 32 + lr;
    #pragma unroll
    for (int r = 0; r < 16; ++r) {
        const int crow = (r & 3) + 8 * (r >> 2) + 4 * lh;
        const int coA = co0 + wc * 64 + crow;
        const int coB = coA + 32;
        const size_t baseA = ((size_t)b * 256 + coA) * 4096 + p;
        const size_t baseB = ((size_t)b * 256 + coB) * 4096 + p;
        out[baseA] = o0[r] + bias2[coA] + query[baseA];
        out[baseB] = o1[r] + bias2[coB] + query[baseB];
    }
}

// ---------------------------------------------------------------- launch
extern "C" void kernel_launch(void* const* d_in, const int* in_sizes, int n_in,
                              void* d_out, int out_size, void* d_ws, size_t ws_size,
                              hipStream_t stream) {
    const float* query   = (const float*)d_in[0];
    const float* v_in    = (const float*)d_in[1];
    const float* qpos    = (const float*)d_in[2];
    const float* kpos    = (const float*)d_in[3];
    const float* otherW  = (const float*)d_in[4];
    const float* w_vs    = (const float*)d_in[5];
    const float* mlp_w1  = (const float*)d_in[6];
    const float* mlp_b1  = (const float*)d_in[7];
    const float* mlp_w2  = (const float*)d_in[8];
    const float* mlp_b2  = (const float*)d_in[9];
    const float* conv1_w = (const float*)d_in[10];
    const float* bn_g    = (const float*)d_in[11];
    const float* bn_b    = (const float*)d_in[12];
    const float* bn_m    = (const float*)d_in[13];
    const float* bn_v    = (const float*)d_in[14];
    const float* conv2_w = (const float*)d_in[15];
    const float* conv2_b = (const float*)d_in[16];
    float* out = (float*)d_out;
    char* base = (char*)d_ws;

    constexpr size_t MB = 1u << 20;
    ushort* v_bf    = (ushort*)(base);             // 8MB   (dead after vproj)
    ushort* qpos_bf = (ushort*)(base + 8 * MB);    // 8MB   (dead after mlp1)
    float*  qp_f32  = (float*) (base);             // 16MB  (aliases v_bf+qpos_bf)
    ushort* qhid_bf = (ushort*)(base + 16 * MB);   // 8MB   (dead after mlp2)
    ushort* X_bf    = (ushort*)(base + 16 * MB);   // 8MB   (attn out, aliases qhid)
    ushort* Y_bf    = (ushort*)(base + 24 * MB);   // 8MB   (conv3 out)
    ushort* kn_bf   = (ushort*)(base + 32 * MB);   // 8MB
    ushort* vT_bf   = (ushort*)(base + 40 * MB);   // 8MB  (w-scaled V'^T, k-tiled)
    ushort* wvs_bf  = (ushort*)(base + 48 * MB);
    ushort* w1e_bf  = (ushort*)(base + 48 * MB + 128 * 1024);
    ushort* w2_bf   = (ushort*)(base + 48 * MB + 256 * 1024);
    ushort* c2_bf   = (ushort*)(base + 48 * MB + 384 * 1024);
    ushort* w9p_bf  = (ushort*)(base + 48 * MB + 512 * 1024);   // 1.125MB packed

    k_prep<<<15040, 256, 0, stream>>>(v_in, otherW, v_bf, qpos, qpos_bf,
                                      kpos, kn_bf, conv1_w, w9p_bf,
                                      w_vs, wvs_bf, mlp_w2, w2_bf,
                                      conv2_w, c2_bf, mlp_w1, w1e_bf);
    k_gemm_mfma<2, 0><<<256, 512, 0, stream>>>(v_bf, wvs_bf, nullptr, vT_bf);
    k_gemm_mfma<1, 1><<<256, 512, 0, stream>>>(qpos_bf, w1e_bf, mlp_b1, qhid_bf);
    k_gemm_mfma<0, 0><<<256, 512, 0, stream>>>(qhid_bf, w2_bf, mlp_b2, qp_f32);
    k_attn_mfma<<<256, 512, 0, stream>>>(qp_f32, kn_bf, vT_bf, X_bf);
    k_conv3_mfma<<<512, 256, 0, stream>>>(X_bf, w9p_bf, bn_g, bn_b, bn_m, bn_v, Y_bf);
    k_conv1x1_mfma<<<256, 512, 0, stream>>>(Y_bf, c2_bf, conv2_b, query, out);
}